// Round 13
// baseline (6105.165 us; speedup 1.0000x reference)
//
#include <hip/hip_runtime.h>
#include <cstdint>

// ---------------------------------------------------------------------------
// VQVAE forward — MFMA implicit-GEMM convolutions, channels-last.
//
// Encoder: activations stored as EXACT 3-way bf16 split planes (h+m+l ==
//   fp32 bit-exact), split ONCE at producer epilogue; consumers stage with
//   plain ushort4 copies. 6-MFMA products => fp32-class => VQ argmin safe.
// Decoder: split-2 bf16 (hi/lo) storage, 3-pass MFMA (unchanged).
//
// Round-13: fixes round-12's plane-size bug (64^3 split-3 plane = 67MB for
// B=2, not 33.5MB => 384MB live, impossible). The 64^3 encoder stages now
// run PER BATCH (batch dim independent; stream-serialized), making each
// plane 33.5MB: A(100.6) + H(100.6) + E1(50) = 251.6MB <= 256MiB.
// Retained: producer-side split-3, fragment-major weights, T14 async-STAGE,
// T1 XCD swizzle (grids 4096/4096/1024, all %8==0), LDS XOR swizzle,
// MFMA ec0, wave-level du1.
//
// C layout: col = lane&31, row = (reg&3) + 8*(reg>>2) + 4*(lane>>5)
// ---------------------------------------------------------------------------

typedef unsigned short bf16_t;
typedef __attribute__((ext_vector_type(8)))  short s8b;     // 8 x bf16 frag
typedef __attribute__((ext_vector_type(16))) float f32x16;  // 32x32 acc

__device__ __forceinline__ float b2f(bf16_t u) { return __uint_as_float((unsigned)u << 16); }
__device__ __forceinline__ bf16_t f2b(float f) {
    unsigned x = __float_as_uint(f);
    return (bf16_t)((x + 0x7FFFu + ((x >> 16) & 1u)) >> 16);
}

// exact: v == h+m+l (truncation split; last residue fits bf16 exactly)
__device__ __forceinline__ void split3s(float v, unsigned short& h,
                                        unsigned short& m, unsigned short& l)
{
    const unsigned uv = __float_as_uint(v);
    const float fh = __uint_as_float(uv & 0xFFFF0000u);
    const float r1 = v - fh;
    const unsigned u1 = __float_as_uint(r1);
    const float fm = __uint_as_float(u1 & 0xFFFF0000u);
    const float r2 = r1 - fm;
    h = (unsigned short)(uv >> 16);
    m = (unsigned short)(u1 >> 16);
    l = (unsigned short)(__float_as_uint(r2) >> 16);
}

// ------------------------- weight prep ------------------------------------
// src [tap][ci][co] fp32 -> dst fragment-major [tap][ks][half][co][8k]
__device__ __forceinline__ int wdst(int tap, int ci_, int co_, int ci, int co)
{
    const int ks = ci_ >> 4, half = (ci_ >> 3) & 1, j = ci_ & 7;
    return (((tap * (ci >> 4) + ks) * 2 + half) * co + co_) * 8 + j;
}

__global__ __launch_bounds__(256)
void wprep3(const float* __restrict__ w, bf16_t* __restrict__ h,
            bf16_t* __restrict__ m, bf16_t* __restrict__ l,
            int ci, int co, int n)
{
    const int i = blockIdx.x * 256 + threadIdx.x;
    if (i >= n) return;
    const int co_ = i % co;
    const int ci_ = (i / co) % ci;
    const int tap = i / (co * ci);
    const int dst = wdst(tap, ci_, co_, ci, co);
    unsigned short hh, mm, ll2;
    split3s(w[i], hh, mm, ll2);
    h[dst] = hh; m[dst] = mm; l[dst] = ll2;
}

__global__ __launch_bounds__(256)
void wprep_split(const float* __restrict__ w, bf16_t* __restrict__ hi,
                 bf16_t* __restrict__ lo, int ci, int co, int n)
{
    const int i = blockIdx.x * 256 + threadIdx.x;
    if (i >= n) return;
    const int co_ = i % co;
    const int ci_ = (i / co) % ci;
    const int tap = i / (co * ci);
    const float v = w[i];
    const int dst = wdst(tap, ci_, co_, ci, co);
    const bf16_t h = f2b(v);
    hi[dst] = h;
    lo[dst] = f2b(v - b2f(h));
}

// ---------------- encoder 3x3x3 conv: split-3 in/out, T14-staged ------------
// EPI: 0=ReLU 1=swish 2=PReLU 3=BN+PReLU+skip+ReLU
// OM:  0 = split-3 bf16 out, 1 = fp32 out (eo -> Zf)
// NB: launched with grid covering NB batches (b = bid/(SD*SD) in [0,NB)).
template<int CIN, int COUT, int SD, int NW, int EPI, int OM>
__global__ __launch_bounds__((SD / 32) * NW * 64)
void conv3e(const bf16_t* __restrict__ xh, const bf16_t* __restrict__ xm,
            const bf16_t* __restrict__ xl,
            const bf16_t* __restrict__ wh, const bf16_t* __restrict__ wm,
            const bf16_t* __restrict__ wl,
            const float* __restrict__ bias,
            const float* __restrict__ g, const float* __restrict__ be,
            const float* __restrict__ mn, const float* __restrict__ vr,
            const float* __restrict__ al,
            const bf16_t* sh, const bf16_t* sm, const bf16_t* sl,
            bf16_t* oh, bf16_t* om_, bf16_t* ol_, float* of)
{
    constexpr int NT = (SD / 32) * NW * 64;
    constexpr int LP = (SD * CIN) / (4 * NT);
    constexpr int KS = CIN / 16;
    __shared__ bf16_t lh[SD * CIN], lm[SD * CIN], ll[SD * CIN];

    const int tid  = threadIdx.x;
    const int lane = tid & 63;
    const int wid  = tid >> 6;
    const int wn   = wid % NW, wm2 = wid / NW;
    const int half = lane >> 5, ln = lane & 31;
    const int w    = wm2 * 32 + ln;
    const int nwg  = gridDim.x;
    const int bid  = (blockIdx.x & 7) * (nwg >> 3) + (blockIdx.x >> 3);
    const int h    = bid % SD;
    const int d    = (bid / SD) % SD;
    const int b    = bid / (SD * SD);
    const int cout0 = wn * 64 + ln;

    int pz[9], py[9], pt[9], np = 0;
    for (int kd = 0; kd < 3; ++kd) {
        const int iz = d + kd - 1;
        if ((unsigned)iz >= (unsigned)SD) continue;
        for (int kh = 0; kh < 3; ++kh) {
            const int iy = h + kh - 1;
            if ((unsigned)iy >= (unsigned)SD) continue;
            pz[np] = iz; py[np] = iy; pt[np] = (kd * 3 + kh) * 3; ++np;
        }
    }

    f32x16 accA[2], accB[2];
#pragma unroll
    for (int i = 0; i < 16; ++i) {
        accA[0][i] = 0.f; accA[1][i] = 0.f;
        accB[0][i] = 0.f; accB[1][i] = 0.f;
    }

    ushort4 rh[LP], rm[LP], rl[LP];
    auto loadrow = [&](int iz, int iy) {
        const size_t rb = ((size_t)((b * SD + iz) * SD + iy)) * SD * CIN;
#pragma unroll
        for (int j = 0; j < LP; ++j) {
            const int idx = (tid + j * NT) * 4;
            rh[j] = *reinterpret_cast<const ushort4*>(xh + rb + idx);
            rm[j] = *reinterpret_cast<const ushort4*>(xm + rb + idx);
            rl[j] = *reinterpret_cast<const ushort4*>(xl + rb + idx);
        }
    };
    auto writerow = [&]() {
#pragma unroll
        for (int j = 0; j < LP; ++j) {
            const int idx = (tid + j * NT) * 4;
            const int vox = idx / CIN, ch = idx % CIN;
            const int bo = ((vox * CIN + ch) * 2) ^ ((vox & 7) << 4);
            *reinterpret_cast<ushort4*>((char*)&lh[0] + bo) = rh[j];
            *reinterpret_cast<ushort4*>((char*)&lm[0] + bo) = rm[j];
            *reinterpret_cast<ushort4*>((char*)&ll[0] + bo) = rl[j];
        }
    };

    loadrow(pz[0], py[0]);
    writerow();
    __syncthreads();
#pragma unroll 1
    for (int i = 0; i < np; ++i) {
        if (i + 1 < np) loadrow(pz[i + 1], py[i + 1]);   // issue early (T14)
#pragma unroll
        for (int kw = 0; kw < 3; ++kw) {
            const int tap = pt[i] + kw;
            const int iw = w + kw - 1;
            const bool edge = (unsigned)iw >= (unsigned)SD;
            const int wcl = edge ? w : iw;
            const s8b zz = {};
#pragma unroll
            for (int ks = 0; ks < KS; ++ks) {
                const int bo = ((wcl * CIN + half * 8 + ks * 16) * 2) ^ ((wcl & 7) << 4);
                s8b ah  = *reinterpret_cast<const s8b*>((const char*)&lh[0] + bo);
                s8b am  = *reinterpret_cast<const s8b*>((const char*)&lm[0] + bo);
                s8b al3 = *reinterpret_cast<const s8b*>((const char*)&ll[0] + bo);
                if (edge) { ah = zz; am = zz; al3 = zz; }
                const size_t wb0 = ((size_t)((tap * KS + ks) * 2 + half) * COUT + cout0) * 8;
#pragma unroll
                for (int n2 = 0; n2 < 2; ++n2) {
                    const size_t wb = wb0 + n2 * 256;   // cout += 32
                    const s8b bh = *reinterpret_cast<const s8b*>(wh + wb);
                    const s8b bm = *reinterpret_cast<const s8b*>(wm + wb);
                    const s8b bl = *reinterpret_cast<const s8b*>(wl + wb);
                    accA[n2] = __builtin_amdgcn_mfma_f32_32x32x16_bf16(ah, bh, accA[n2], 0, 0, 0);
                    accB[n2] = __builtin_amdgcn_mfma_f32_32x32x16_bf16(ah, bm, accB[n2], 0, 0, 0);
                    accA[n2] = __builtin_amdgcn_mfma_f32_32x32x16_bf16(am, bh, accA[n2], 0, 0, 0);
                    accB[n2] = __builtin_amdgcn_mfma_f32_32x32x16_bf16(am, bm, accB[n2], 0, 0, 0);
                    accA[n2] = __builtin_amdgcn_mfma_f32_32x32x16_bf16(al3, bh, accA[n2], 0, 0, 0);
                    accB[n2] = __builtin_amdgcn_mfma_f32_32x32x16_bf16(ah, bl, accB[n2], 0, 0, 0);
                }
            }
        }
        if (i + 1 < np) {
            __syncthreads();          // all waves done reading LDS
            writerow();               // implicit vmcnt wait on regs here
            __syncthreads();          // LDS ready
        }
    }

    const size_t outrow = ((size_t)((b * SD + d) * SD + h)) * SD;
#pragma unroll
    for (int n2 = 0; n2 < 2; ++n2) {
        const int cout = wn * 64 + n2 * 32 + ln;
        const float bv = bias[cout];
        float sc = 0.f, mm = 0.f, bb2 = 0.f, aa = 0.f;
        if constexpr (EPI == 3) {
            sc = g[cout] * (1.0f / sqrtf(vr[cout] + 1e-3f));
            mm = mn[cout]; bb2 = be[cout]; aa = al[cout];
        }
        if constexpr (EPI == 2) aa = al[cout];
#pragma unroll
        for (int r = 0; r < 16; ++r) {
            const int rl2 = (r & 3) + 8 * (r >> 2) + 4 * half;
            const size_t oe = (outrow + wm2 * 32 + rl2) * COUT + cout;
            float y = accA[n2][r] + accB[n2][r] + bv;
            if constexpr (EPI == 0) y = fmaxf(y, 0.f);
            else if constexpr (EPI == 1) y = y / (1.f + expf(-y));
            else if constexpr (EPI == 2) y = y > 0.f ? y : aa * y;
            else {
                float t2 = (y - mm) * sc + bb2;
                t2 = t2 > 0.f ? t2 : aa * t2;
                const float sv = b2f(sh[oe]) + b2f(sm[oe]) + b2f(sl[oe]);
                y = fmaxf(sv + t2, 0.f);
            }
            if constexpr (OM == 1) {
                of[oe] = y;
            } else {
                unsigned short yh, ym, yl;
                split3s(y, yh, ym, yl);
                oh[oe] = yh; om_[oe] = ym; ol_[oe] = yl;
            }
        }
    }
}

// ---------------- ec1: stride-2 k=4, split-3 in/out, T14-staged -------------
// Per-batch launch: grid 1024, pointers pre-offset to the batch.
__global__ __launch_bounds__(128)
void convs2e(const bf16_t* __restrict__ xh, const bf16_t* __restrict__ xm,
             const bf16_t* __restrict__ xl,
             const bf16_t* __restrict__ wh, const bf16_t* __restrict__ wm,
             const bf16_t* __restrict__ wl,
             const float* __restrict__ bias,
             bf16_t* __restrict__ oh, bf16_t* __restrict__ om_,
             bf16_t* __restrict__ ol_)
{
    constexpr int NT = 128, LP = (64 * 64) / (4 * NT);
    __shared__ bf16_t lh[64 * 64], lm[64 * 64], ll[64 * 64];

    const int tid  = threadIdx.x;
    const int lane = tid & 63;
    const int wn   = tid >> 6;
    const int half = lane >> 5, ln = lane & 31;
    const int nwg  = gridDim.x;
    const int bid  = (blockIdx.x & 7) * (nwg >> 3) + (blockIdx.x >> 3);
    const int h    = bid % 32;
    const int d    = (bid / 32) % 32;
    const int b    = bid / 1024;      // 0 for per-batch launch
    const int cout0 = wn * 64 + ln;

    int pz[16], py[16], pt[16], np = 0;
    for (int kd = 0; kd < 4; ++kd) {
        const int iz = 2 * d + kd - 1;
        if ((unsigned)iz >= 64u) continue;
        for (int kh = 0; kh < 4; ++kh) {
            const int iy = 2 * h + kh - 1;
            if ((unsigned)iy >= 64u) continue;
            pz[np] = iz; py[np] = iy; pt[np] = (kd * 4 + kh) * 4; ++np;
        }
    }

    f32x16 accA[2], accB[2];
#pragma unroll
    for (int i = 0; i < 16; ++i) {
        accA[0][i] = 0.f; accA[1][i] = 0.f;
        accB[0][i] = 0.f; accB[1][i] = 0.f;
    }

    ushort4 rh[LP], rm[LP], rl[LP];
    auto loadrow = [&](int iz, int iy) {
        const size_t rb = ((size_t)((b * 64 + iz) * 64 + iy)) * 64 * 64;
#pragma unroll
        for (int j = 0; j < LP; ++j) {
            const int idx = (tid + j * NT) * 4;
            rh[j] = *reinterpret_cast<const ushort4*>(xh + rb + idx);
            rm[j] = *reinterpret_cast<const ushort4*>(xm + rb + idx);
            rl[j] = *reinterpret_cast<const ushort4*>(xl + rb + idx);
        }
    };
    auto writerow = [&]() {
#pragma unroll
        for (int j = 0; j < LP; ++j) {
            const int idx = (tid + j * NT) * 4;
            const int vox = idx / 64, ch = idx % 64;
            const int bo = ((vox * 64 + ch) * 2) ^ ((vox & 7) << 4);
            *reinterpret_cast<ushort4*>((char*)&lh[0] + bo) = rh[j];
            *reinterpret_cast<ushort4*>((char*)&lm[0] + bo) = rm[j];
            *reinterpret_cast<ushort4*>((char*)&ll[0] + bo) = rl[j];
        }
    };

    loadrow(pz[0], py[0]);
    writerow();
    __syncthreads();
#pragma unroll 1
    for (int i = 0; i < np; ++i) {
        if (i + 1 < np) loadrow(pz[i + 1], py[i + 1]);
#pragma unroll
        for (int kw = 0; kw < 4; ++kw) {
            const int tap = pt[i] + kw;
            const int iw = 2 * ln + kw - 1;
            const bool edge = (unsigned)iw >= 64u;
            const int wcl = edge ? 2 * ln : iw;
            const s8b zz = {};
#pragma unroll
            for (int ks = 0; ks < 4; ++ks) {
                const int bo = ((wcl * 64 + half * 8 + ks * 16) * 2) ^ ((wcl & 7) << 4);
                s8b ah  = *reinterpret_cast<const s8b*>((const char*)&lh[0] + bo);
                s8b am  = *reinterpret_cast<const s8b*>((const char*)&lm[0] + bo);
                s8b al3 = *reinterpret_cast<const s8b*>((const char*)&ll[0] + bo);
                if (edge) { ah = zz; am = zz; al3 = zz; }
                const size_t wb0 = ((size_t)((tap * 4 + ks) * 2 + half) * 128 + cout0) * 8;
#pragma unroll
                for (int n2 = 0; n2 < 2; ++n2) {
                    const size_t wb = wb0 + n2 * 256;
                    const s8b bh = *reinterpret_cast<const s8b*>(wh + wb);
                    const s8b bm = *reinterpret_cast<const s8b*>(wm + wb);
                    const s8b bl = *reinterpret_cast<const s8b*>(wl + wb);
                    accA[n2] = __builtin_amdgcn_mfma_f32_32x32x16_bf16(ah, bh, accA[n2], 0, 0, 0);
                    accB[n2] = __builtin_amdgcn_mfma_f32_32x32x16_bf16(ah, bm, accB[n2], 0, 0, 0);
                    accA[n2] = __builtin_amdgcn_mfma_f32_32x32x16_bf16(am, bh, accA[n2], 0, 0, 0);
                    accB[n2] = __builtin_amdgcn_mfma_f32_32x32x16_bf16(am, bm, accB[n2], 0, 0, 0);
                    accA[n2] = __builtin_amdgcn_mfma_f32_32x32x16_bf16(al3, bh, accA[n2], 0, 0, 0);
                    accB[n2] = __builtin_amdgcn_mfma_f32_32x32x16_bf16(ah, bl, accB[n2], 0, 0, 0);
                }
            }
        }
        if (i + 1 < np) {
            __syncthreads();
            writerow();
            __syncthreads();
        }
    }

    const size_t outrow = ((size_t)((b * 32 + d) * 32 + h)) * 32;
#pragma unroll
    for (int n2 = 0; n2 < 2; ++n2) {
        const int cout = wn * 64 + n2 * 32 + ln;
        const float bv = bias[cout];
#pragma unroll
        for (int r = 0; r < 16; ++r) {
            const int rl2 = (r & 3) + 8 * (r >> 2) + 4 * half;
            const size_t oe = (outrow + rl2) * 128 + cout;
            const float y = fmaxf(accA[n2][r] + accB[n2][r] + bv, 0.f);
            unsigned short yh, ym, yl;
            split3s(y, yh, ym, yl);
            oh[oe] = yh; om_[oe] = ym; ol_[oe] = yl;
        }
    }
}

// ---------------- decoder 3x3x3 conv: split-2 bf16, T14-staged --------------
template<int CIN, int COUT, int SD, int NW, int EPI>
__global__ __launch_bounds__((SD / 32) * NW * 64)
void conv3d(const bf16_t* __restrict__ xh, const bf16_t* __restrict__ xl,
            const bf16_t* __restrict__ wh, const bf16_t* __restrict__ wl,
            const float* __restrict__ bias,
            const float* __restrict__ g, const float* __restrict__ be,
            const float* __restrict__ mn, const float* __restrict__ vr,
            const float* __restrict__ al,
            const bf16_t* skh, const bf16_t* skl,
            bf16_t* oh, bf16_t* ol)
{
    constexpr int NT = (SD / 32) * NW * 64;
    constexpr int LP = (SD * CIN) / (4 * NT);
    constexpr int KS = CIN / 16;
    __shared__ bf16_t lh[SD * CIN], ll[SD * CIN];

    const int tid  = threadIdx.x;
    const int lane = tid & 63;
    const int wid  = tid >> 6;
    const int wn   = wid % NW, wm2 = wid / NW;
    const int half = lane >> 5, ln = lane & 31;
    const int w    = wm2 * 32 + ln;
    const int nwg  = gridDim.x;
    const int bid  = (blockIdx.x & 7) * (nwg >> 3) + (blockIdx.x >> 3);
    const int h    = bid % SD;
    const int d    = (bid / SD) % SD;
    const int b    = bid / (SD * SD);
    const int cout0 = wn * 64 + ln;

    int pz[9], py[9], pt[9], np = 0;
    for (int kd = 0; kd < 3; ++kd) {
        const int iz = d + kd - 1;
        if ((unsigned)iz >= (unsigned)SD) continue;
        for (int kh = 0; kh < 3; ++kh) {
            const int iy = h + kh - 1;
            if ((unsigned)iy >= (unsigned)SD) continue;
            pz[np] = iz; py[np] = iy; pt[np] = (kd * 3 + kh) * 3; ++np;
        }
    }

    f32x16 accA[2], accB[2];
#pragma unroll
    for (int i = 0; i < 16; ++i) {
        accA[0][i] = 0.f; accA[1][i] = 0.f;
        accB[0][i] = 0.f; accB[1][i] = 0.f;
    }

    ushort4 rh[LP], rl2a[LP];
    auto loadrow = [&](int iz, int iy) {
        const size_t rb = ((size_t)((b * SD + iz) * SD + iy)) * SD * CIN;
#pragma unroll
        for (int j = 0; j < LP; ++j) {
            const int idx = (tid + j * NT) * 4;
            rh[j]   = *reinterpret_cast<const ushort4*>(xh + rb + idx);
            rl2a[j] = *reinterpret_cast<const ushort4*>(xl + rb + idx);
        }
    };
    auto writerow = [&]() {
#pragma unroll
        for (int j = 0; j < LP; ++j) {
            const int idx = (tid + j * NT) * 4;
            const int vox = idx / CIN, ch = idx % CIN;
            const int bo = ((vox * CIN + ch) * 2) ^ ((vox & 7) << 4);
            *reinterpret_cast<ushort4*>((char*)&lh[0] + bo) = rh[j];
            *reinterpret_cast<ushort4*>((char*)&ll[0] + bo) = rl2a[j];
        }
    };

    loadrow(pz[0], py[0]);
    writerow();
    __syncthreads();
#pragma unroll 1
    for (int i = 0; i < np; ++i) {
        if (i + 1 < np) loadrow(pz[i + 1], py[i + 1]);
#pragma unroll
        for (int kw = 0; kw < 3; ++kw) {
            const int tap = pt[i] + kw;
            const int iw = w + kw - 1;
            const bool edge = (unsigned)iw >= (unsigned)SD;
            const int wcl = edge ? w : iw;
            const s8b zz = {};
#pragma unroll
            for (int ks = 0; ks < KS; ++ks) {
                const int bo = ((wcl * CIN + half * 8 + ks * 16) * 2) ^ ((wcl & 7) << 4);
                s8b ah  = *reinterpret_cast<const s8b*>((const char*)&lh[0] + bo);
                s8b al2 = *reinterpret_cast<const s8b*>((const char*)&ll[0] + bo);
                if (edge) { ah = zz; al2 = zz; }
                const size_t wb0 = ((size_t)((tap * KS + ks) * 2 + half) * COUT + cout0) * 8;
#pragma unroll
                for (int n2 = 0; n2 < 2; ++n2) {
                    const size_t wb = wb0 + n2 * 256;
                    const s8b bh = *reinterpret_cast<const s8b*>(wh + wb);
                    const s8b bl = *reinterpret_cast<const s8b*>(wl + wb);
                    accA[n2] = __builtin_amdgcn_mfma_f32_32x32x16_bf16(ah, bh, accA[n2], 0, 0, 0);
                    accB[n2] = __builtin_amdgcn_mfma_f32_32x32x16_bf16(al2, bh, accB[n2], 0, 0, 0);
                    accB[n2] = __builtin_amdgcn_mfma_f32_32x32x16_bf16(ah, bl, accB[n2], 0, 0, 0);
                }
            }
        }
        if (i + 1 < np) {
            __syncthreads();
            writerow();
            __syncthreads();
        }
    }

    const size_t outrow = ((size_t)((b * SD + d) * SD + h)) * SD;
#pragma unroll
    for (int n2 = 0; n2 < 2; ++n2) {
        const int cout = wn * 64 + n2 * 32 + ln;
        const float bv = bias[cout];
        float sc = 0.f, mm = 0.f, bb2 = 0.f, aa = 0.f;
        if constexpr (EPI == 3) {
            sc = g[cout] * (1.0f / sqrtf(vr[cout] + 1e-3f));
            mm = mn[cout]; bb2 = be[cout]; aa = al[cout];
        }
        if constexpr (EPI == 2) aa = al[cout];
#pragma unroll
        for (int r = 0; r < 16; ++r) {
            const int rl3 = (r & 3) + 8 * (r >> 2) + 4 * half;
            const size_t oe = (outrow + wm2 * 32 + rl3) * COUT + cout;
            float y = accA[n2][r] + accB[n2][r] + bv;
            if constexpr (EPI == 0) y = fmaxf(y, 0.f);
            else if constexpr (EPI == 1) y = y / (1.f + expf(-y));
            else if constexpr (EPI == 2) y = y > 0.f ? y : aa * y;
            else {
                float t2 = (y - mm) * sc + bb2;
                t2 = t2 > 0.f ? t2 : aa * t2;
                float sv = b2f(skh[oe]) + b2f(skl[oe]);
                y = fmaxf(sv + t2, 0.f);
            }
            const bf16_t hh = f2b(y);
            oh[oe] = hh;
            ol[oe] = f2b(y - b2f(hh));
        }
    }
}

// ---------------- convT stride-2 k=4 (du0, split-2, T14-staged) -------------
__global__ __launch_bounds__(256)
void convTm(const bf16_t* __restrict__ xh, const bf16_t* __restrict__ xl,
            const bf16_t* __restrict__ wh, const bf16_t* __restrict__ wl,
            const float* __restrict__ bias,
            bf16_t* __restrict__ oh, bf16_t* __restrict__ ol)
{
    constexpr int NT = 256, LP = (32 * 128) / (4 * NT);
    __shared__ bf16_t lh[32 * 128], ll[32 * 128];

    const int tid  = threadIdx.x;
    const int lane = tid & 63;
    const int wid  = tid >> 6;
    const int wn   = wid & 1, p = wid >> 1;
    const int half = lane >> 5, ln = lane & 31;
    const int nwg  = gridDim.x;
    const int bid  = (blockIdx.x & 7) * (nwg >> 3) + (blockIdx.x >> 3);
    const int ohh  = bid % 64;
    const int od   = (bid / 64) % 64;
    const int b    = bid / 4096;
    const int pd = od & 1, dz = od >> 1;
    const int ph = ohh & 1, hy = ohh >> 1;
    const int cout = wn * 32 + ln;

    int pz[4], py[4], pt[4], np = 0;
    for (int jd = 0; jd < 2; ++jd) {
        const int kd = pd + 2 * jd;
        const int iz = dz + pd - 1 + jd;
        if ((unsigned)iz >= 32u) continue;
        for (int jh = 0; jh < 2; ++jh) {
            const int kh = ph + 2 * jh;
            const int iy = hy + ph - 1 + jh;
            if ((unsigned)iy >= 32u) continue;
            pz[np] = iz; py[np] = iy; pt[np] = (kd * 4 + kh) * 4; ++np;
        }
    }

    f32x16 accA, accB;
#pragma unroll
    for (int i = 0; i < 16; ++i) { accA[i] = 0.0f; accB[i] = 0.0f; }

    ushort4 rh[LP], rl2a[LP];
    auto loadrow = [&](int iz, int iy) {
        const size_t rb = ((size_t)((b * 32 + iz) * 32 + iy)) * 32 * 128;
#pragma unroll
        for (int j = 0; j < LP; ++j) {
            const int idx = (tid + j * NT) * 4;
            rh[j]   = *reinterpret_cast<const ushort4*>(xh + rb + idx);
            rl2a[j] = *reinterpret_cast<const ushort4*>(xl + rb + idx);
        }
    };
    auto writerow = [&]() {
#pragma unroll
        for (int j = 0; j < LP; ++j) {
            const int idx = (tid + j * NT) * 4;
            const int vox = idx / 128, ch = idx % 128;
            const int bo = ((vox * 128 + ch) * 2) ^ ((vox & 7) << 4);
            *reinterpret_cast<ushort4*>((char*)&lh[0] + bo) = rh[j];
            *reinterpret_cast<ushort4*>((char*)&ll[0] + bo) = rl2a[j];
        }
    };

    loadrow(pz[0], py[0]);
    writerow();
    __syncthreads();
#pragma unroll 1
    for (int i = 0; i < np; ++i) {
        if (i + 1 < np) loadrow(pz[i + 1], py[i + 1]);
#pragma unroll
        for (int jw = 0; jw < 2; ++jw) {
            const int kw = p + 2 * jw;
            const int tap = pt[i] + kw;
            const int ix = ln + p - 1 + jw;
            const bool edge = (unsigned)ix >= 32u;
            const int xcl = edge ? ln : ix;
            const s8b zz = {};
#pragma unroll
            for (int ks = 0; ks < 8; ++ks) {
                const int bo = ((xcl * 128 + half * 8 + ks * 16) * 2) ^ ((xcl & 7) << 4);
                s8b a  = *reinterpret_cast<const s8b*>((const char*)&lh[0] + bo);
                s8b a2 = *reinterpret_cast<const s8b*>((const char*)&ll[0] + bo);
                if (edge) { a = zz; a2 = zz; }
                const size_t wb = ((size_t)((tap * 8 + ks) * 2 + half) * 64 + cout) * 8;
                const s8b bb = *reinterpret_cast<const s8b*>(wh + wb);
                const s8b b2 = *reinterpret_cast<const s8b*>(wl + wb);
                accA = __builtin_amdgcn_mfma_f32_32x32x16_bf16(a, bb, accA, 0, 0, 0);
                accB = __builtin_amdgcn_mfma_f32_32x32x16_bf16(a2, bb, accB, 0, 0, 0);
                accB = __builtin_amdgcn_mfma_f32_32x32x16_bf16(a, b2, accB, 0, 0, 0);
            }
        }
        if (i + 1 < np) {
            __syncthreads();
            writerow();
            __syncthreads();
        }
    }

    const float bv = bias[cout];
#pragma unroll
    for (int r = 0; r < 16; ++r) {
        const int rl3 = (r & 3) + 8 * (r >> 2) + 4 * half;
        const int ow = 2 * rl3 + p;
        const size_t oe = (((size_t)((b * 64 + od) * 64 + ohh)) * 64 + ow) * 64 + cout;
        const float y = fmaxf(accA[r] + accB[r] + bv, 0.f);
        const bf16_t hh = f2b(y);
        oh[oe] = hh;
        ol[oe] = f2b(y - b2f(hh));
    }
}

// ---------------- ec0 via MFMA: s2 k=4, CIN=1, K=64 taps, split-3 out -------
// Per-batch launch: grid 4096, x pre-offset, outputs per-batch planes.
__global__ __launch_bounds__(128)
void conv_ec0m(const float* __restrict__ x,
               const bf16_t* __restrict__ wh, const bf16_t* __restrict__ wm,
               const bf16_t* __restrict__ wl,
               const float* __restrict__ bias,
               bf16_t* __restrict__ oh, bf16_t* __restrict__ om_,
               bf16_t* __restrict__ ol_)
{
    __shared__ bf16_t lh[16 * 132], lm[16 * 132], ll[16 * 132];

    const int tid  = threadIdx.x;
    const int lane = tid & 63;
    const int wm2  = tid >> 6;
    const int half = lane >> 5, ln = lane & 31;
    const int w    = wm2 * 32 + ln;
    const int nwg  = gridDim.x;
    const int bid  = (blockIdx.x & 7) * (nwg >> 3) + (blockIdx.x >> 3);
    const int h    = bid % 64;
    const int d    = (bid / 64) % 64;
    const int b    = bid / 4096;      // 0 for per-batch launch

    for (int i = tid; i < 16 * 132; i += 128) {
        const int row = i / 132, col = i % 132;
        const int kd = row >> 2, kh = row & 3;
        const int iz = 2 * d + kd - 1, iy = 2 * h + kh - 1;
        const int ix = col - 1;
        float v = 0.f;
        if ((unsigned)iz < 128u && (unsigned)iy < 128u &&
            (unsigned)ix < 128u && col < 130)
            v = x[(size_t)((b * 128 + iz) * 128 + iy) * 128 + ix];
        unsigned short hh, mm2, ll2;
        split3s(v, hh, mm2, ll2);
        lh[i] = hh; lm[i] = mm2; ll[i] = ll2;
    }
    __syncthreads();

    f32x16 accA[2], accB[2];
#pragma unroll
    for (int i = 0; i < 16; ++i) {
        accA[0][i] = 0.f; accA[1][i] = 0.f;
        accB[0][i] = 0.f; accB[1][i] = 0.f;
    }

#pragma unroll
    for (int ks = 0; ks < 4; ++ks) {
        const int row0 = ks * 4 + 2 * half;
        const int i0 = row0 * 132 + 2 * w;
        const int i1 = i0 + 132;
        s8b ah, am, al3;
        {
            uint* ap = (uint*)&ah;
            ap[0] = *(const uint*)&lh[i0]; ap[1] = *(const uint*)&lh[i0 + 2];
            ap[2] = *(const uint*)&lh[i1]; ap[3] = *(const uint*)&lh[i1 + 2];
        }
        {
            uint* ap = (uint*)&am;
            ap[0] = *(const uint*)&lm[i0]; ap[1] = *(const uint*)&lm[i0 + 2];
            ap[2] = *(const uint*)&lm[i1]; ap[3] = *(const uint*)&lm[i1 + 2];
        }
        {
            uint* ap = (uint*)&al3;
            ap[0] = *(const uint*)&ll[i0]; ap[1] = *(const uint*)&ll[i0 + 2];
            ap[2] = *(const uint*)&ll[i1]; ap[3] = *(const uint*)&ll[i1 + 2];
        }
        const size_t wb0 = ((size_t)(ks * 2 + half) * 64 + ln) * 8;
#pragma unroll
        for (int n2 = 0; n2 < 2; ++n2) {
            const size_t wb = wb0 + n2 * 256;
            const s8b bh = *reinterpret_cast<const s8b*>(wh + wb);
            const s8b bm = *reinterpret_cast<const s8b*>(wm + wb);
            const s8b bl = *reinterpret_cast<const s8b*>(wl + wb);
            accA[n2] = __builtin_amdgcn_mfma_f32_32x32x16_bf16(ah, bh, accA[n2], 0, 0, 0);
            accB[n2] = __builtin_amdgcn_mfma_f32_32x32x16_bf16(ah, bm, accB[n2], 0, 0, 0);
            accA[n2] = __builtin_amdgcn_mfma_f32_32x32x16_bf16(am, bh, accA[n2], 0, 0, 0);
            accB[n2] = __builtin_amdgcn_mfma_f32_32x32x16_bf16(am, bm, accB[n2], 0, 0, 0);
            accA[n2] = __builtin_amdgcn_mfma_f32_32x32x16_bf16(al3, bh, accA[n2], 0, 0, 0);
            accB[n2] = __builtin_amdgcn_mfma_f32_32x32x16_bf16(ah, bl, accB[n2], 0, 0, 0);
        }
    }

    const size_t outrow = ((size_t)((b * 64 + d) * 64 + h)) * 64;
#pragma unroll
    for (int n2 = 0; n2 < 2; ++n2) {
        const int cout = n2 * 32 + ln;
        const float bv = bias[cout];
#pragma unroll
        for (int r = 0; r < 16; ++r) {
            const int rl3 = (r & 3) + 8 * (r >> 2) + 4 * half;
            const size_t oe = (outrow + wm2 * 32 + rl3) * 64 + cout;
            const float y = fmaxf(accA[n2][r] + accB[n2][r] + bv, 0.f);
            unsigned short yh, ym, yl;
            split3s(y, yh, ym, yl);
            oh[oe] = yh; om_[oe] = ym; ol_[oe] = yl;
        }
    }
}

// ---------------- du1: convT s2 k=4, CIN=64, COUT=1 — wave-level ------------
__global__ __launch_bounds__(256)
void convT_du1w(const bf16_t* __restrict__ inh, const bf16_t* __restrict__ inl,
                const float* __restrict__ wt, const float* __restrict__ bias,
                float* __restrict__ out)
{
    const int lane = threadIdx.x & 63;
    const int wv   = blockIdx.x * 4 + (threadIdx.x >> 6);
    const size_t obase = (size_t)wv * 16;
    const int ow0 = (int)(obase % 128);
    size_t rem = obase / 128;
    const int ohh = (int)(rem % 128); rem /= 128;
    const int od  = (int)(rem % 128); rem /= 128;
    const int b   = (int)rem;
    const int pd = od & 1, dz = od >> 1;
    const int ph = ohh & 1, hy = ohh >> 1;
    const int wx0 = ow0 >> 1;

    float acc[16];
#pragma unroll
    for (int o = 0; o < 16; ++o) acc[o] = 0.f;

#pragma unroll
    for (int jd = 0; jd < 2; ++jd) {
        const int kd = pd + 2 * jd;
        const int iz = dz + pd - 1 + jd;
        if ((unsigned)iz >= 64u) continue;
#pragma unroll
        for (int jh = 0; jh < 2; ++jh) {
            const int kh = ph + 2 * jh;
            const int iy = hy + ph - 1 + jh;
            if ((unsigned)iy >= 64u) continue;
            const size_t rbase = ((size_t)((b * 64 + iz) * 64 + iy)) * 64;
            float wv4[4];
#pragma unroll
            for (int kw = 0; kw < 4; ++kw)
                wv4[kw] = wt[(size_t)((kd * 4 + kh) * 4 + kw) * 64 + lane];
            float v[10];
#pragma unroll
            for (int t = 0; t < 10; ++t) {
                const int ix = wx0 - 1 + t;
                if ((unsigned)ix < 64u) {
                    const size_t a = (rbase + ix) * 64 + lane;
                    v[t] = b2f(inh[a]) + b2f(inl[a]);
                } else {
                    v[t] = 0.f;
                }
            }
#pragma unroll
            for (int o = 0; o < 16; ++o) {
                const int pw = o & 1;
                const int t0 = (o >> 1) + pw;
                acc[o] = fmaf(v[t0],     wv4[pw],     acc[o]);
                acc[o] = fmaf(v[t0 + 1], wv4[pw + 2], acc[o]);
            }
        }
    }

    const float b0 = bias[0];
#pragma unroll
    for (int o = 0; o < 16; ++o) {
        float s = acc[o];
        s += __shfl_xor(s, 1);
        s += __shfl_xor(s, 2);
        s += __shfl_xor(s, 4);
        s += __shfl_xor(s, 8);
        s += __shfl_xor(s, 16);
        s += __shfl_xor(s, 32);
        if (lane == 0) out[obase + o] = s + b0;
    }
}

// --------------------------------- VQ ---------------------------------------
__global__ void zero512(float* __restrict__ p) { p[threadIdx.x] = 0.0f; }

__global__ void vq_cnorm(const float* __restrict__ cb, float* __restrict__ cnorm)
{
    const int k = blockIdx.x * 64 + threadIdx.x;
    float s = 0.0f;
    for (int ci = 0; ci < 64; ++ci) { const float c = cb[k * 64 + ci]; s = fmaf(c, c, s); }
    cnorm[k] = s;
}

__global__ __launch_bounds__(256)
void vq_assign(const float* __restrict__ z, const float* __restrict__ cb,
               const float* __restrict__ cnorm, int* __restrict__ idx,
               float* __restrict__ hist, int N)
{
    const int n = blockIdx.x * 256 + threadIdx.x;
    const float4* zp = reinterpret_cast<const float4*>(z + (size_t)n * 64);
    float4 zv[16];
    float z2 = 0.0f;
#pragma unroll
    for (int i = 0; i < 16; ++i) {
        zv[i] = zp[i];
        z2 += zv[i].x * zv[i].x + zv[i].y * zv[i].y + zv[i].z * zv[i].z + zv[i].w * zv[i].w;
    }
    float best = 3.4e38f;
    int bi = 0;
#pragma unroll 1
    for (int k = 0; k < 512; ++k) {
        const float4* cp = reinterpret_cast<const float4*>(cb + (size_t)k * 64);
        float dot = 0.0f;
#pragma unroll
        for (int i = 0; i < 16; ++i) {
            const float4 c = cp[i];
            dot += zv[i].x * c.x + zv[i].y * c.y + zv[i].z * c.z + zv[i].w * c.w;
        }
        const float dist = z2 + cnorm[k] - 2.0f * dot;
        if (dist < best) { best = dist; bi = k; }
    }
    idx[n] = bi;
    atomicAdd(&hist[bi], 1.0f);
}

__global__ __launch_bounds__(256)
void vq_gather_split(const float* __restrict__ cb, const int* __restrict__ idx,
                     bf16_t* __restrict__ zh, bf16_t* __restrict__ zl)
{
    const int gid = blockIdx.x * 256 + threadIdx.x;
    const int n = gid >> 4, c4 = gid & 15;
    const int k = idx[n];
    const float4 c = reinterpret_cast<const float4*>(cb)[k * 16 + c4];
    ushort4 h, l;
    h.x = f2b(c.x); l.x = f2b(c.x - b2f(h.x));
    h.y = f2b(c.y); l.y = f2b(c.y - b2f(h.y));
    h.z = f2b(c.z); l.z = f2b(c.z - b2f(h.z));
    h.w = f2b(c.w); l.w = f2b(c.w - b2f(h.w));
    reinterpret_cast<ushort4*>(zh)[gid] = h;
    reinterpret_cast<ushort4*>(zl)[gid] = l;
}

__global__ __launch_bounds__(512)
void perplexity_k(const float* __restrict__ hist, float* __restrict__ out, float invN)
{
    __shared__ float red[512];
    const int t = threadIdx.x;
    const float p = hist[t] * invN;
    red[t] = p * logf(p + 1e-12f);
    __syncthreads();
    for (int s = 256; s > 0; s >>= 1) {
        if (t < s) red[t] += red[t + s];
        __syncthreads();
    }
    if (t == 0) out[0] = expf(-red[0]);
}

// ---------------------------------------------------------------------------
extern "C" void kernel_launch(void* const* d_in, const int* in_sizes, int n_in,
                              void* d_out, int out_size, void* d_ws, size_t ws_size,
                              hipStream_t stream)
{
    const float* x       = (const float*)d_in[0];
    const float* ec0_w   = (const float*)d_in[1];
    const float* ec0_b   = (const float*)d_in[2];
    const float* er0_c1w = (const float*)d_in[3];
    const float* er0_c1b = (const float*)d_in[4];
    const float* er0_c2w = (const float*)d_in[5];
    const float* er0_c2b = (const float*)d_in[6];
    const float* er0_g   = (const float*)d_in[7];
    const float* er0_be  = (const float*)d_in[8];
    const float* er0_m   = (const float*)d_in[9];
    const float* er0_v   = (const float*)d_in[10];
    const float* er0_a   = (const float*)d_in[11];
    const float* ec1_w   = (const float*)d_in[12];
    const float* ec1_b   = (const float*)d_in[13];
    const float* er1_c1w = (const float*)d_in[14];
    const float* er1_c1b = (const float*)d_in[15];
    const float* er1_c2w = (const float*)d_in[16];
    const float* er1_c2b = (const float*)d_in[17];
    const float* er1_g   = (const float*)d_in[18];
    const float* er1_be  = (const float*)d_in[19];
    const float* er1_m   = (const float*)d_in[20];
    const float* er1_v   = (const float*)d_in[21];
    const float* er1_a   = (const float*)d_in[22];
    const float* eo_w    = (const float*)d_in[23];
    const float* eo_b    = (const float*)d_in[24];
    const float* eo_a    = (const float*)d_in[25];
    const float* cb      = (const float*)d_in[26];
    const float* dc0_w   = (const float*)d_in[27];
    const float* dc0_b   = (const float*)d_in[28];
    const float* dc0_a   = (const float*)d_in[29];
    const float* dr0_c1w = (const float*)d_in[30];
    const float* dr0_c1b = (const float*)d_in[31];
    const float* dr0_c2w = (const float*)d_in[32];
    const float* dr0_c2b = (const float*)d_in[33];
    const float* dr0_g   = (const float*)d_in[34];
    const float* dr0_be  = (const float*)d_in[35];
    const float* dr0_m   = (const float*)d_in[36];
    const float* dr0_v   = (const float*)d_in[37];
    const float* dr0_a   = (const float*)d_in[38];
    const float* du0_w   = (const float*)d_in[39];
    const float* du0_b   = (const float*)d_in[40];
    const float* dr1_c1w = (const float*)d_in[41];
    const float* dr1_c1b = (const float*)d_in[42];
    const float* dr1_c2w = (const float*)d_in[43];
    const float* dr1_c2b = (const float*)d_in[44];
    const float* dr1_g   = (const float*)d_in[45];
    const float* dr1_be  = (const float*)d_in[46];
    const float* dr1_m   = (const float*)d_in[47];
    const float* dr1_v   = (const float*)d_in[48];
    const float* dr1_a   = (const float*)d_in[49];
    const float* du1_w   = (const float*)d_in[50];
    const float* du1_b   = (const float*)d_in[51];

    float* out = (float*)d_out;

    // ---- ws layout (phase-overlaid, peak 251.7 MB <= 256 MiB) ----
    char* W = (char*)d_ws;
    // encoder 64^3 PER-BATCH split-3 planes (64^3 x 64ch bf16 = 33,554,432 B each):
    bf16_t* Ah = (bf16_t*)(W);
    bf16_t* Am = (bf16_t*)(W + 33554432);
    bf16_t* Al = (bf16_t*)(W + 67108864);
    bf16_t* Hh = (bf16_t*)(W + 100663296);
    bf16_t* Hm = (bf16_t*)(W + 134217728);
    bf16_t* Hl = (bf16_t*)(W + 167772160);
    // encoder 32^3 FULL-BATCH split-3 planes (2 x 32^3 x 128 bf16 = 16,777,216 B each):
    bf16_t* E1h = (bf16_t*)(W + 201326592);
    bf16_t* E1m = (bf16_t*)(W + 218103808);
    bf16_t* E1l = (bf16_t*)(W + 234881024);          // ends 251,658,240
    bf16_t* R1h = (bf16_t*)(W + 100663296);          // reuse H region (er1 h)
    bf16_t* R1m = (bf16_t*)(W + 117440512);
    bf16_t* R1l = (bf16_t*)(W + 134217728);
    // VQ (A region dead after batch-1 ec1):
    float*  Zf  = (float*) (W);                      // 16,777,216 B
    int*    IDX = (int*)   (W + 16777216);
    float*  CN  = (float*) (W + 17039360);
    float*  HS  = (float*) (W + 17041408);
    bf16_t* ZQh = (bf16_t*)(W + 33554432);
    bf16_t* ZQl = (bf16_t*)(W + 41943040);
    // decoder 32^3 (split-2):
    bf16_t* D0h = (bf16_t*)(W + 50331648);
    bf16_t* D0l = (bf16_t*)(W + 67108864);
    bf16_t* Gh  = (bf16_t*)(W + 83886080);
    bf16_t* Gl  = (bf16_t*)(W + 100663296);
    // decoder 64^3 (split-2, full-batch, 67,108,864 B each):
    bf16_t* U0h = (bf16_t*)(W + 134217728);
    bf16_t* U0l = (bf16_t*)(W + 201326592);
    bf16_t* G1h = (bf16_t*)(W);
    bf16_t* G1l = (bf16_t*)(W + 67108864);

    // ---- weight arenas in d_out (dead until du1 overwrites) ----
    char* WB = (char*)d_out;
    bf16_t* e0c1h = (bf16_t*)(WB + 0);
    bf16_t* e0c1m = (bf16_t*)(WB + 221184);
    bf16_t* e0c1l = (bf16_t*)(WB + 442368);
    bf16_t* e0c2h = (bf16_t*)(WB + 663552);
    bf16_t* e0c2m = (bf16_t*)(WB + 884736);
    bf16_t* e0c2l = (bf16_t*)(WB + 1105920);
    bf16_t* ec1h  = (bf16_t*)(WB + 1327104);
    bf16_t* ec1m  = (bf16_t*)(WB + 2375680);
    bf16_t* ec1l  = (bf16_t*)(WB + 3424256);
    bf16_t* e1c1h = (bf16_t*)(WB + 4472832);
    bf16_t* e1c1m = (bf16_t*)(WB + 5357568);
    bf16_t* e1c1l = (bf16_t*)(WB + 6242304);
    bf16_t* e1c2h = (bf16_t*)(WB + 7127040);
    bf16_t* e1c2m = (bf16_t*)(WB + 8011776);
    bf16_t* e1c2l = (bf16_t*)(WB + 8896512);
    bf16_t* eoh   = (bf16_t*)(WB + 9781248);
    bf16_t* eom   = (bf16_t*)(WB + 10223616);
    bf16_t* eol   = (bf16_t*)(WB + 10665984);
    bf16_t* wec0h = (bf16_t*)(WB + 11108352);
    bf16_t* wec0m = (bf16_t*)(WB + 11116544);
    bf16_t* wec0l = (bf16_t*)(WB + 11124736);
    bf16_t* dc0h  = (bf16_t*)(WB + 0);
    bf16_t* dc0l  = (bf16_t*)(WB + 442368);
    bf16_t* d0c1h = (bf16_t*)(WB + 884736);
    bf16_t* d0c1l = (bf16_t*)(WB + 1769472);
    bf16_t* d0c2h = (bf16_t*)(WB + 2654208);
    bf16_t* d0c2l = (bf16_t*)(WB + 3538944);
    bf16_t* du0h  = (bf16_t*)(WB + 4423680);
    bf16_t* du0l  = (bf16_t*)(WB + 5472256);
    bf16_t* d1c1h = (bf16_t*)(WB + 6520832);
    bf16_t* d1c1l = (bf16_t*)(WB + 6742016);
    bf16_t* d1c2h = (bf16_t*)(WB + 6963200);
    bf16_t* d1c2l = (bf16_t*)(WB + 7184384);

    const float* fn = nullptr;
    const bf16_t* bn_ = nullptr;
    bf16_t* bo = nullptr;

    // ---- encoder weight prep (split-3, fragment-major) ----
    wprep3<<<16, 256, 0, stream>>>(ec0_w, wec0h, wec0m, wec0l, 64, 64, 4096);
    wprep3<<<432, 256, 0, stream>>>(er0_c1w, e0c1h, e0c1m, e0c1l, 64, 64, 110592);
    wprep3<<<432, 256, 0, stream>>>(er0_c2w, e0c2h, e0c2m, e0c2l, 64, 64, 110592);
    wprep3<<<2048, 256, 0, stream>>>(ec1_w, ec1h, ec1m, ec1l, 64, 128, 524288);
    wprep3<<<1728, 256, 0, stream>>>(er1_c1w, e1c1h, e1c1m, e1c1l, 128, 128, 442368);
    wprep3<<<1728, 256, 0, stream>>>(er1_c2w, e1c2h, e1c2m, e1c2l, 128, 128, 442368);
    wprep3<<<864, 256, 0, stream>>>(eo_w, eoh, eom, eol, 128, 64, 221184);

    // ---- encoder 64^3 stages PER BATCH (A/H planes are per-batch) ----
    for (int b = 0; b < 2; ++b) {
        const float* xb = x + (size_t)b * 2097152;            // 128^3
        bf16_t* E1hb = E1h + (size_t)b * 4194304;             // 32^3 x 128
        bf16_t* E1mb = E1m + (size_t)b * 4194304;
        bf16_t* E1lb = E1l + (size_t)b * 4194304;

        conv_ec0m<<<4096, 128, 0, stream>>>(xb, wec0h, wec0m, wec0l, ec0_b,
                                            Ah, Am, Al);
        conv3e<64, 64, 64, 1, 1, 0><<<4096, 128, 0, stream>>>(
            Ah, Am, Al, e0c1h, e0c1m, e0c1l, er0_c1b, fn, fn, fn, fn, fn,
            bn_, bn_, bn_, Hh, Hm, Hl, nullptr);
        conv3e<64, 64, 64, 1, 3, 0><<<4096, 128, 0, stream>>>(
            Hh, Hm, Hl, e0c2h, e0c2m, e0c2l, er0_c2b, er0_g, er0_be, er0_m,
            er0_v, er0_a, Ah, Am, Al, Ah, Am, Al, nullptr);
        convs2e<<<1024, 128, 0, stream>>>(Ah, Am, Al, ec1h, ec1m, ec1l, ec1_b,
                                          E1hb, E1mb, E1lb);
    }

    // ---- encoder 32^3 stages (full batch) ----
    conv3e<128, 128, 32, 2, 1, 0><<<2048, 128, 0, stream>>>(
        E1h, E1m, E1l, e1c1h, e1c1m, e1c1l, er1_c1b, fn, fn, fn, fn, fn,
        bn_, bn_, bn_, R1h, R1m, R1l, nullptr);
    conv3e<128, 128, 32, 2, 3, 0><<<2048, 128, 0, stream>>>(
        R1h, R1m, R1l, e1c2h, e1c2m, e1c2l, er1_c2b, er1_g, er1_be, er1_m, er1_v, er1_a,
        E1h, E1m, E1l, E1h, E1m, E1l, nullptr);

    conv3e<128, 64, 32, 1, 2, 1><<<2048, 64, 0, stream>>>(
        E1h, E1m, E1l, eoh, eom, eol, eo_b, fn, fn, fn, fn, eo_a,
        bn_, bn_, bn_, bo, bo, bo, Zf);

    // ---- VQ (exact fp32) ----
    vq_cnorm<<<8, 64, 0, stream>>>(cb, CN);
    zero512<<<1, 512, 0, stream>>>(HS);
    vq_assign<<<256, 256, 0, stream>>>(Zf, cb, CN, IDX, HS, 65536);
    perplexity_k<<<1, 512, 0, stream>>>(HS, out + 4194304, 1.0f / 65536.0f);
    vq_gather_split<<<4096, 256, 0, stream>>>(cb, IDX, ZQh, ZQl);

    // ---- decoder weight prep (split-2, fragment-major, overwrites arena) ----
    wprep_split<<<864, 256, 0, stream>>>(dc0_w, dc0h, dc0l, 64, 128, 221184);
    wprep_split<<<1728, 256, 0, stream>>>(dr0_c1w, d0c1h, d0c1l, 128, 128, 442368);
    wprep_split<<<1728, 256, 0, stream>>>(dr0_c2w, d0c2h, d0c2l, 128, 128, 442368);
    wprep_split<<<2048, 256, 0, stream>>>(du0_w, du0h, du0l, 128, 64, 524288);
    wprep_split<<<432, 256, 0, stream>>>(dr1_c1w, d1c1h, d1c1l, 64, 64, 110592);
    wprep_split<<<432, 256, 0, stream>>>(dr1_c2w, d1c2h, d1c2l, 64, 64, 110592);

    // ---- decoder (split-2 bf16) ----
    conv3d<64, 128, 32, 2, 2><<<2048, 128, 0, stream>>>(
        ZQh, ZQl, dc0h, dc0l, dc0_b, fn, fn, fn, fn, dc0_a, bn_, bn_, D0h, D0l);
    conv3d<128, 128, 32, 2, 1><<<2048, 128, 0, stream>>>(
        D0h, D0l, d0c1h, d0c1l, dr0_c1b, fn, fn, fn, fn, fn, bn_, bn_, Gh, Gl);
    conv3d<128, 128, 32, 2, 3><<<2048, 128, 0, stream>>>(
        Gh, Gl, d0c2h, d0c2l, dr0_c2b, dr0_g, dr0_be, dr0_m, dr0_v, dr0_a,
        D0h, D0l, D0h, D0l);

    convTm<<<8192, 256, 0, stream>>>(D0h, D0l, du0h, du0l, du0_b, U0h, U0l);

    conv3d<64, 64, 64, 1, 1><<<8192, 128, 0, stream>>>(
        U0h, U0l, d1c1h, d1c1l, dr1_c1b, fn, fn, fn, fn, fn, bn_, bn_, G1h, G1l);
    conv3d<64, 64, 64, 1, 3><<<8192, 128, 0, stream>>>(
        G1h, G1l, d1c2h, d1c2l, dr1_c2b, dr1_g, dr1_be, dr1_m, dr1_v, dr1_a,
        U0h, U0l, U0h, U0l);

    convT_du1w<<<65536, 256, 0, stream>>>(U0h, U0l, du1_w, du1_b, out);
}

// Round 14
// 6031.994 us; speedup vs baseline: 1.0121x; 1.0121x over previous
//
#include <hip/hip_runtime.h>
#include <cstdint>

// ---------------------------------------------------------------------------
// VQVAE forward — MFMA implicit-GEMM convolutions, channels-last.
//
// Round-14 = round-11 structure (proven 5506us) + parallel vq_assign.
//   - Encoder: fp32 activations in memory; EXACT 3-way bf16 split (v=h+m+l)
//     at LDS-stage time; 6-MFMA products => fp32-class => VQ argmin safe.
//     (Round-12/13's producer-side split REVERTED: measured net regression
//     from 1.5x staging bytes + per-batch serialization.)
//   - Decoder: split-2 bf16 (hi/lo) storage, 3-pass MFMA.
//   - vq_assign: 4 threads/z (128 codes each, 2-way ILP), shfl-xor min
//     reduce with lower-index tie-break (first-min semantics preserved).
//     Fixes the 615us latency/occupancy-bound serial scan (occ 11%).
// Retained: fragment-major weights w[tap][ks][half][cout][8k], T14 async-
// STAGE single-LDS-buffer, T1 XCD-chunked swizzle, LDS XOR swizzle,
// MFMA ec0, wave-level du1.
//
// C layout: col = lane&31, row = (reg&3) + 8*(reg>>2) + 4*(lane>>5)
// ---------------------------------------------------------------------------

typedef unsigned short bf16_t;
typedef __attribute__((ext_vector_type(8)))  short s8b;     // 8 x bf16 frag
typedef __attribute__((ext_vector_type(16))) float f32x16;  // 32x32 acc

__device__ __forceinline__ float b2f(bf16_t u) { return __uint_as_float((unsigned)u << 16); }
__device__ __forceinline__ bf16_t f2b(float f) {
    unsigned x = __float_as_uint(f);
    return (bf16_t)((x + 0x7FFFu + ((x >> 16) & 1u)) >> 16);
}

__device__ __forceinline__ void split3s(float v, unsigned short& h,
                                        unsigned short& m, unsigned short& l)
{
    const unsigned uv = __float_as_uint(v);
    const float fh = __uint_as_float(uv & 0xFFFF0000u);
    const float r1 = v - fh;
    const unsigned u1 = __float_as_uint(r1);
    const float fm = __uint_as_float(u1 & 0xFFFF0000u);
    const float r2 = r1 - fm;
    h = (unsigned short)(uv >> 16);
    m = (unsigned short)(u1 >> 16);
    l = (unsigned short)(__float_as_uint(r2) >> 16);
}

// ------------------------- weight prep ------------------------------------
// src [tap][ci][co] fp32 -> dst fragment-major [tap][ks][half][co][8k]
__device__ __forceinline__ int wdst(int tap, int ci_, int co_, int ci, int co)
{
    const int ks = ci_ >> 4, half = (ci_ >> 3) & 1, j = ci_ & 7;
    return (((tap * (ci >> 4) + ks) * 2 + half) * co + co_) * 8 + j;
}

__global__ __launch_bounds__(256)
void wprep3(const float* __restrict__ w, bf16_t* __restrict__ h,
            bf16_t* __restrict__ m, bf16_t* __restrict__ l,
            int ci, int co, int n)
{
    const int i = blockIdx.x * 256 + threadIdx.x;
    if (i >= n) return;
    const int co_ = i % co;
    const int ci_ = (i / co) % ci;
    const int tap = i / (co * ci);
    const int dst = wdst(tap, ci_, co_, ci, co);
    unsigned short hh, mm, ll2;
    split3s(w[i], hh, mm, ll2);
    h[dst] = hh; m[dst] = mm; l[dst] = ll2;
}

__global__ __launch_bounds__(256)
void wprep_split(const float* __restrict__ w, bf16_t* __restrict__ hi,
                 bf16_t* __restrict__ lo, int ci, int co, int n)
{
    const int i = blockIdx.x * 256 + threadIdx.x;
    if (i >= n) return;
    const int co_ = i % co;
    const int ci_ = (i / co) % ci;
    const int tap = i / (co * ci);
    const float v = w[i];
    const int dst = wdst(tap, ci_, co_, ci, co);
    const bf16_t h = f2b(v);
    hi[dst] = h;
    lo[dst] = f2b(v - b2f(h));
}

// ---------------- encoder 3x3x3 conv: fp32 in, T14-staged split-3 -----------
// EPI: 0=ReLU 1=swish 2=PReLU 3=BN+PReLU+skip+ReLU
template<int CIN, int COUT, int SD, int NW, int EPI>
__global__ __launch_bounds__((SD / 32) * NW * 64)
void conv3e(const float* __restrict__ xf,
            const bf16_t* __restrict__ wh, const bf16_t* __restrict__ wm,
            const bf16_t* __restrict__ wl,
            const float* __restrict__ bias,
            const float* __restrict__ g, const float* __restrict__ be,
            const float* __restrict__ mn, const float* __restrict__ vr,
            const float* __restrict__ al,
            const float* skf, float* __restrict__ of)
{
    constexpr int NT = (SD / 32) * NW * 64;
    constexpr int LP = (SD * CIN) / (4 * NT);
    constexpr int KS = CIN / 16;
    __shared__ bf16_t lh[SD * CIN], lm[SD * CIN], ll[SD * CIN];

    const int tid  = threadIdx.x;
    const int lane = tid & 63;
    const int wid  = tid >> 6;
    const int wn   = wid % NW, wm2 = wid / NW;
    const int half = lane >> 5, ln = lane & 31;
    const int w    = wm2 * 32 + ln;
    const int nwg  = gridDim.x;
    const int bid  = (blockIdx.x & 7) * (nwg >> 3) + (blockIdx.x >> 3);
    const int h    = bid % SD;
    const int d    = (bid / SD) % SD;
    const int b    = bid / (SD * SD);
    const int cout0 = wn * 64 + ln;

    int pz[9], py[9], pt[9], np = 0;
    for (int kd = 0; kd < 3; ++kd) {
        const int iz = d + kd - 1;
        if ((unsigned)iz >= (unsigned)SD) continue;
        for (int kh = 0; kh < 3; ++kh) {
            const int iy = h + kh - 1;
            if ((unsigned)iy >= (unsigned)SD) continue;
            pz[np] = iz; py[np] = iy; pt[np] = (kd * 3 + kh) * 3; ++np;
        }
    }

    f32x16 accA[2], accB[2];
#pragma unroll
    for (int i = 0; i < 16; ++i) {
        accA[0][i] = 0.f; accA[1][i] = 0.f;
        accB[0][i] = 0.f; accB[1][i] = 0.f;
    }

    float4 rg[LP];
    auto loadrow = [&](int iz, int iy) {
        const float* src = xf + ((size_t)((b * SD + iz) * SD + iy)) * SD * CIN;
#pragma unroll
        for (int j = 0; j < LP; ++j)
            rg[j] = *reinterpret_cast<const float4*>(src + (size_t)(tid + j * NT) * 4);
    };
    auto writerow = [&]() {
#pragma unroll
        for (int j = 0; j < LP; ++j) {
            const int idx = (tid + j * NT) * 4;
            const int vox = idx / CIN, ch = idx % CIN;
            ushort4 h4, m4, l4;
            split3s(rg[j].x, h4.x, m4.x, l4.x);
            split3s(rg[j].y, h4.y, m4.y, l4.y);
            split3s(rg[j].z, h4.z, m4.z, l4.z);
            split3s(rg[j].w, h4.w, m4.w, l4.w);
            const int bo = ((vox * CIN + ch) * 2) ^ ((vox & 7) << 4);
            *reinterpret_cast<ushort4*>((char*)&lh[0] + bo) = h4;
            *reinterpret_cast<ushort4*>((char*)&lm[0] + bo) = m4;
            *reinterpret_cast<ushort4*>((char*)&ll[0] + bo) = l4;
        }
    };

    loadrow(pz[0], py[0]);
    writerow();
    __syncthreads();
#pragma unroll 1
    for (int i = 0; i < np; ++i) {
        if (i + 1 < np) loadrow(pz[i + 1], py[i + 1]);   // issue early (T14)
#pragma unroll
        for (int kw = 0; kw < 3; ++kw) {
            const int tap = pt[i] + kw;
            const int iw = w + kw - 1;
            const bool edge = (unsigned)iw >= (unsigned)SD;
            const int wcl = edge ? w : iw;
            const s8b zz = {};
#pragma unroll
            for (int ks = 0; ks < KS; ++ks) {
                const int bo = ((wcl * CIN + half * 8 + ks * 16) * 2) ^ ((wcl & 7) << 4);
                s8b ah  = *reinterpret_cast<const s8b*>((const char*)&lh[0] + bo);
                s8b am  = *reinterpret_cast<const s8b*>((const char*)&lm[0] + bo);
                s8b al3 = *reinterpret_cast<const s8b*>((const char*)&ll[0] + bo);
                if (edge) { ah = zz; am = zz; al3 = zz; }
                const size_t wb0 = ((size_t)((tap * KS + ks) * 2 + half) * COUT + cout0) * 8;
#pragma unroll
                for (int n2 = 0; n2 < 2; ++n2) {
                    const size_t wb = wb0 + n2 * 256;   // cout += 32
                    const s8b bh = *reinterpret_cast<const s8b*>(wh + wb);
                    const s8b bm = *reinterpret_cast<const s8b*>(wm + wb);
                    const s8b bl = *reinterpret_cast<const s8b*>(wl + wb);
                    accA[n2] = __builtin_amdgcn_mfma_f32_32x32x16_bf16(ah, bh, accA[n2], 0, 0, 0);
                    accB[n2] = __builtin_amdgcn_mfma_f32_32x32x16_bf16(ah, bm, accB[n2], 0, 0, 0);
                    accA[n2] = __builtin_amdgcn_mfma_f32_32x32x16_bf16(am, bh, accA[n2], 0, 0, 0);
                    accB[n2] = __builtin_amdgcn_mfma_f32_32x32x16_bf16(am, bm, accB[n2], 0, 0, 0);
                    accA[n2] = __builtin_amdgcn_mfma_f32_32x32x16_bf16(al3, bh, accA[n2], 0, 0, 0);
                    accB[n2] = __builtin_amdgcn_mfma_f32_32x32x16_bf16(ah, bl, accB[n2], 0, 0, 0);
                }
            }
        }
        if (i + 1 < np) {
            __syncthreads();          // all waves done reading LDS
            writerow();               // implicit vmcnt wait on rg here
            __syncthreads();          // LDS ready
        }
    }

    const size_t outrow = ((size_t)((b * SD + d) * SD + h)) * SD;
#pragma unroll
    for (int n2 = 0; n2 < 2; ++n2) {
        const int cout = wn * 64 + n2 * 32 + ln;
        const float bv = bias[cout];
        float sc = 0.f, mm = 0.f, bb2 = 0.f, aa = 0.f;
        if constexpr (EPI == 3) {
            sc = g[cout] * (1.0f / sqrtf(vr[cout] + 1e-3f));
            mm = mn[cout]; bb2 = be[cout]; aa = al[cout];
        }
        if constexpr (EPI == 2) aa = al[cout];
#pragma unroll
        for (int r = 0; r < 16; ++r) {
            const int rl = (r & 3) + 8 * (r >> 2) + 4 * half;
            const size_t oe = (outrow + wm2 * 32 + rl) * COUT + cout;
            float y = accA[n2][r] + accB[n2][r] + bv;
            if constexpr (EPI == 0) y = fmaxf(y, 0.f);
            else if constexpr (EPI == 1) y = y / (1.f + expf(-y));
            else if constexpr (EPI == 2) y = y > 0.f ? y : aa * y;
            else {
                float t2 = (y - mm) * sc + bb2;
                t2 = t2 > 0.f ? t2 : aa * t2;
                y = fmaxf(skf[oe] + t2, 0.f);
            }
            of[oe] = y;
        }
    }
}

// ---------------- ec1: stride-2 k=4, fp32 in, T14-staged split-3 ------------
__global__ __launch_bounds__(128)
void convs2e(const float* __restrict__ xf,
             const bf16_t* __restrict__ wh, const bf16_t* __restrict__ wm,
             const bf16_t* __restrict__ wl,
             const float* __restrict__ bias, float* __restrict__ of)
{
    constexpr int NT = 128, LP = (64 * 64) / (4 * NT);
    __shared__ bf16_t lh[64 * 64], lm[64 * 64], ll[64 * 64];

    const int tid  = threadIdx.x;
    const int lane = tid & 63;
    const int wn   = tid >> 6;
    const int half = lane >> 5, ln = lane & 31;
    const int nwg  = gridDim.x;
    const int bid  = (blockIdx.x & 7) * (nwg >> 3) + (blockIdx.x >> 3);
    const int h    = bid % 32;
    const int d    = (bid / 32) % 32;
    const int b    = bid / 1024;
    const int cout0 = wn * 64 + ln;

    int pz[16], py[16], pt[16], np = 0;
    for (int kd = 0; kd < 4; ++kd) {
        const int iz = 2 * d + kd - 1;
        if ((unsigned)iz >= 64u) continue;
        for (int kh = 0; kh < 4; ++kh) {
            const int iy = 2 * h + kh - 1;
            if ((unsigned)iy >= 64u) continue;
            pz[np] = iz; py[np] = iy; pt[np] = (kd * 4 + kh) * 4; ++np;
        }
    }

    f32x16 accA[2], accB[2];
#pragma unroll
    for (int i = 0; i < 16; ++i) {
        accA[0][i] = 0.f; accA[1][i] = 0.f;
        accB[0][i] = 0.f; accB[1][i] = 0.f;
    }

    float4 rg[LP];
    auto loadrow = [&](int iz, int iy) {
        const float* src = xf + ((size_t)((b * 64 + iz) * 64 + iy)) * 64 * 64;
#pragma unroll
        for (int j = 0; j < LP; ++j)
            rg[j] = *reinterpret_cast<const float4*>(src + (size_t)(tid + j * NT) * 4);
    };
    auto writerow = [&]() {
#pragma unroll
        for (int j = 0; j < LP; ++j) {
            const int idx = (tid + j * NT) * 4;
            const int vox = idx / 64, ch = idx % 64;
            ushort4 h4, m4, l4;
            split3s(rg[j].x, h4.x, m4.x, l4.x);
            split3s(rg[j].y, h4.y, m4.y, l4.y);
            split3s(rg[j].z, h4.z, m4.z, l4.z);
            split3s(rg[j].w, h4.w, m4.w, l4.w);
            const int bo = ((vox * 64 + ch) * 2) ^ ((vox & 7) << 4);
            *reinterpret_cast<ushort4*>((char*)&lh[0] + bo) = h4;
            *reinterpret_cast<ushort4*>((char*)&lm[0] + bo) = m4;
            *reinterpret_cast<ushort4*>((char*)&ll[0] + bo) = l4;
        }
    };

    loadrow(pz[0], py[0]);
    writerow();
    __syncthreads();
#pragma unroll 1
    for (int i = 0; i < np; ++i) {
        if (i + 1 < np) loadrow(pz[i + 1], py[i + 1]);
#pragma unroll
        for (int kw = 0; kw < 4; ++kw) {
            const int tap = pt[i] + kw;
            const int iw = 2 * ln + kw - 1;
            const bool edge = (unsigned)iw >= 64u;
            const int wcl = edge ? 2 * ln : iw;
            const s8b zz = {};
#pragma unroll
            for (int ks = 0; ks < 4; ++ks) {
                const int bo = ((wcl * 64 + half * 8 + ks * 16) * 2) ^ ((wcl & 7) << 4);
                s8b ah  = *reinterpret_cast<const s8b*>((const char*)&lh[0] + bo);
                s8b am  = *reinterpret_cast<const s8b*>((const char*)&lm[0] + bo);
                s8b al3 = *reinterpret_cast<const s8b*>((const char*)&ll[0] + bo);
                if (edge) { ah = zz; am = zz; al3 = zz; }
                const size_t wb0 = ((size_t)((tap * 4 + ks) * 2 + half) * 128 + cout0) * 8;
#pragma unroll
                for (int n2 = 0; n2 < 2; ++n2) {
                    const size_t wb = wb0 + n2 * 256;
                    const s8b bh = *reinterpret_cast<const s8b*>(wh + wb);
                    const s8b bm = *reinterpret_cast<const s8b*>(wm + wb);
                    const s8b bl = *reinterpret_cast<const s8b*>(wl + wb);
                    accA[n2] = __builtin_amdgcn_mfma_f32_32x32x16_bf16(ah, bh, accA[n2], 0, 0, 0);
                    accB[n2] = __builtin_amdgcn_mfma_f32_32x32x16_bf16(ah, bm, accB[n2], 0, 0, 0);
                    accA[n2] = __builtin_amdgcn_mfma_f32_32x32x16_bf16(am, bh, accA[n2], 0, 0, 0);
                    accB[n2] = __builtin_amdgcn_mfma_f32_32x32x16_bf16(am, bm, accB[n2], 0, 0, 0);
                    accA[n2] = __builtin_amdgcn_mfma_f32_32x32x16_bf16(al3, bh, accA[n2], 0, 0, 0);
                    accB[n2] = __builtin_amdgcn_mfma_f32_32x32x16_bf16(ah, bl, accB[n2], 0, 0, 0);
                }
            }
        }
        if (i + 1 < np) {
            __syncthreads();
            writerow();
            __syncthreads();
        }
    }

    const size_t outrow = ((size_t)((b * 32 + d) * 32 + h)) * 32;
#pragma unroll
    for (int n2 = 0; n2 < 2; ++n2) {
        const int cout = wn * 64 + n2 * 32 + ln;
        const float bv = bias[cout];
#pragma unroll
        for (int r = 0; r < 16; ++r) {
            const int rl = (r & 3) + 8 * (r >> 2) + 4 * half;
            const size_t oe = (outrow + rl) * 128 + cout;
            of[oe] = fmaxf(accA[n2][r] + accB[n2][r] + bv, 0.f);
        }
    }
}

// ---------------- decoder 3x3x3 conv: split-2 bf16, T14-staged --------------
template<int CIN, int COUT, int SD, int NW, int EPI>
__global__ __launch_bounds__((SD / 32) * NW * 64)
void conv3d(const bf16_t* __restrict__ xh, const bf16_t* __restrict__ xl,
            const bf16_t* __restrict__ wh, const bf16_t* __restrict__ wl,
            const float* __restrict__ bias,
            const float* __restrict__ g, const float* __restrict__ be,
            const float* __restrict__ mn, const float* __restrict__ vr,
            const float* __restrict__ al,
            const bf16_t* skh, const bf16_t* skl,
            bf16_t* oh, bf16_t* ol)
{
    constexpr int NT = (SD / 32) * NW * 64;
    constexpr int LP = (SD * CIN) / (4 * NT);
    constexpr int KS = CIN / 16;
    __shared__ bf16_t lh[SD * CIN], ll[SD * CIN];

    const int tid  = threadIdx.x;
    const int lane = tid & 63;
    const int wid  = tid >> 6;
    const int wn   = wid % NW, wm2 = wid / NW;
    const int half = lane >> 5, ln = lane & 31;
    const int w    = wm2 * 32 + ln;
    const int nwg  = gridDim.x;
    const int bid  = (blockIdx.x & 7) * (nwg >> 3) + (blockIdx.x >> 3);
    const int h    = bid % SD;
    const int d    = (bid / SD) % SD;
    const int b    = bid / (SD * SD);
    const int cout0 = wn * 64 + ln;

    int pz[9], py[9], pt[9], np = 0;
    for (int kd = 0; kd < 3; ++kd) {
        const int iz = d + kd - 1;
        if ((unsigned)iz >= (unsigned)SD) continue;
        for (int kh = 0; kh < 3; ++kh) {
            const int iy = h + kh - 1;
            if ((unsigned)iy >= (unsigned)SD) continue;
            pz[np] = iz; py[np] = iy; pt[np] = (kd * 3 + kh) * 3; ++np;
        }
    }

    f32x16 accA[2], accB[2];
#pragma unroll
    for (int i = 0; i < 16; ++i) {
        accA[0][i] = 0.f; accA[1][i] = 0.f;
        accB[0][i] = 0.f; accB[1][i] = 0.f;
    }

    ushort4 rh[LP], rl2a[LP];
    auto loadrow = [&](int iz, int iy) {
        const size_t rb = ((size_t)((b * SD + iz) * SD + iy)) * SD * CIN;
#pragma unroll
        for (int j = 0; j < LP; ++j) {
            const int idx = (tid + j * NT) * 4;
            rh[j]   = *reinterpret_cast<const ushort4*>(xh + rb + idx);
            rl2a[j] = *reinterpret_cast<const ushort4*>(xl + rb + idx);
        }
    };
    auto writerow = [&]() {
#pragma unroll
        for (int j = 0; j < LP; ++j) {
            const int idx = (tid + j * NT) * 4;
            const int vox = idx / CIN, ch = idx % CIN;
            const int bo = ((vox * CIN + ch) * 2) ^ ((vox & 7) << 4);
            *reinterpret_cast<ushort4*>((char*)&lh[0] + bo) = rh[j];
            *reinterpret_cast<ushort4*>((char*)&ll[0] + bo) = rl2a[j];
        }
    };

    loadrow(pz[0], py[0]);
    writerow();
    __syncthreads();
#pragma unroll 1
    for (int i = 0; i < np; ++i) {
        if (i + 1 < np) loadrow(pz[i + 1], py[i + 1]);
#pragma unroll
        for (int kw = 0; kw < 3; ++kw) {
            const int tap = pt[i] + kw;
            const int iw = w + kw - 1;
            const bool edge = (unsigned)iw >= (unsigned)SD;
            const int wcl = edge ? w : iw;
            const s8b zz = {};
#pragma unroll
            for (int ks = 0; ks < KS; ++ks) {
                const int bo = ((wcl * CIN + half * 8 + ks * 16) * 2) ^ ((wcl & 7) << 4);
                s8b ah  = *reinterpret_cast<const s8b*>((const char*)&lh[0] + bo);
                s8b al2 = *reinterpret_cast<const s8b*>((const char*)&ll[0] + bo);
                if (edge) { ah = zz; al2 = zz; }
                const size_t wb0 = ((size_t)((tap * KS + ks) * 2 + half) * COUT + cout0) * 8;
#pragma unroll
                for (int n2 = 0; n2 < 2; ++n2) {
                    const size_t wb = wb0 + n2 * 256;
                    const s8b bh = *reinterpret_cast<const s8b*>(wh + wb);
                    const s8b bl = *reinterpret_cast<const s8b*>(wl + wb);
                    accA[n2] = __builtin_amdgcn_mfma_f32_32x32x16_bf16(ah, bh, accA[n2], 0, 0, 0);
                    accB[n2] = __builtin_amdgcn_mfma_f32_32x32x16_bf16(al2, bh, accB[n2], 0, 0, 0);
                    accB[n2] = __builtin_amdgcn_mfma_f32_32x32x16_bf16(ah, bl, accB[n2], 0, 0, 0);
                }
            }
        }
        if (i + 1 < np) {
            __syncthreads();
            writerow();
            __syncthreads();
        }
    }

    const size_t outrow = ((size_t)((b * SD + d) * SD + h)) * SD;
#pragma unroll
    for (int n2 = 0; n2 < 2; ++n2) {
        const int cout = wn * 64 + n2 * 32 + ln;
        const float bv = bias[cout];
        float sc = 0.f, mm = 0.f, bb2 = 0.f, aa = 0.f;
        if constexpr (EPI == 3) {
            sc = g[cout] * (1.0f / sqrtf(vr[cout] + 1e-3f));
            mm = mn[cout]; bb2 = be[cout]; aa = al[cout];
        }
        if constexpr (EPI == 2) aa = al[cout];
#pragma unroll
        for (int r = 0; r < 16; ++r) {
            const int rl3 = (r & 3) + 8 * (r >> 2) + 4 * half;
            const size_t oe = (outrow + wm2 * 32 + rl3) * COUT + cout;
            float y = accA[n2][r] + accB[n2][r] + bv;
            if constexpr (EPI == 0) y = fmaxf(y, 0.f);
            else if constexpr (EPI == 1) y = y / (1.f + expf(-y));
            else if constexpr (EPI == 2) y = y > 0.f ? y : aa * y;
            else {
                float t2 = (y - mm) * sc + bb2;
                t2 = t2 > 0.f ? t2 : aa * t2;
                float sv = b2f(skh[oe]) + b2f(skl[oe]);
                y = fmaxf(sv + t2, 0.f);
            }
            const bf16_t hh = f2b(y);
            oh[oe] = hh;
            ol[oe] = f2b(y - b2f(hh));
        }
    }
}

// ---------------- convT stride-2 k=4 (du0, split-2, T14-staged) -------------
__global__ __launch_bounds__(256)
void convTm(const bf16_t* __restrict__ xh, const bf16_t* __restrict__ xl,
            const bf16_t* __restrict__ wh, const bf16_t* __restrict__ wl,
            const float* __restrict__ bias,
            bf16_t* __restrict__ oh, bf16_t* __restrict__ ol)
{
    constexpr int NT = 256, LP = (32 * 128) / (4 * NT);
    __shared__ bf16_t lh[32 * 128], ll[32 * 128];

    const int tid  = threadIdx.x;
    const int lane = tid & 63;
    const int wid  = tid >> 6;
    const int wn   = wid & 1, p = wid >> 1;
    const int half = lane >> 5, ln = lane & 31;
    const int nwg  = gridDim.x;
    const int bid  = (blockIdx.x & 7) * (nwg >> 3) + (blockIdx.x >> 3);
    const int ohh  = bid % 64;
    const int od   = (bid / 64) % 64;
    const int b    = bid / 4096;
    const int pd = od & 1, dz = od >> 1;
    const int ph = ohh & 1, hy = ohh >> 1;
    const int cout = wn * 32 + ln;

    int pz[4], py[4], pt[4], np = 0;
    for (int jd = 0; jd < 2; ++jd) {
        const int kd = pd + 2 * jd;
        const int iz = dz + pd - 1 + jd;
        if ((unsigned)iz >= 32u) continue;
        for (int jh = 0; jh < 2; ++jh) {
            const int kh = ph + 2 * jh;
            const int iy = hy + ph - 1 + jh;
            if ((unsigned)iy >= 32u) continue;
            pz[np] = iz; py[np] = iy; pt[np] = (kd * 4 + kh) * 4; ++np;
        }
    }

    f32x16 accA, accB;
#pragma unroll
    for (int i = 0; i < 16; ++i) { accA[i] = 0.0f; accB[i] = 0.0f; }

    ushort4 rh[LP], rl2a[LP];
    auto loadrow = [&](int iz, int iy) {
        const size_t rb = ((size_t)((b * 32 + iz) * 32 + iy)) * 32 * 128;
#pragma unroll
        for (int j = 0; j < LP; ++j) {
            const int idx = (tid + j * NT) * 4;
            rh[j]   = *reinterpret_cast<const ushort4*>(xh + rb + idx);
            rl2a[j] = *reinterpret_cast<const ushort4*>(xl + rb + idx);
        }
    };
    auto writerow = [&]() {
#pragma unroll
        for (int j = 0; j < LP; ++j) {
            const int idx = (tid + j * NT) * 4;
            const int vox = idx / 128, ch = idx % 128;
            const int bo = ((vox * 128 + ch) * 2) ^ ((vox & 7) << 4);
            *reinterpret_cast<ushort4*>((char*)&lh[0] + bo) = rh[j];
            *reinterpret_cast<ushort4*>((char*)&ll[0] + bo) = rl2a[j];
        }
    };

    loadrow(pz[0], py[0]);
    writerow();
    __syncthreads();
#pragma unroll 1
    for (int i = 0; i < np; ++i) {
        if (i + 1 < np) loadrow(pz[i + 1], py[i + 1]);
#pragma unroll
        for (int jw = 0; jw < 2; ++jw) {
            const int kw = p + 2 * jw;
            const int tap = pt[i] + kw;
            const int ix = ln + p - 1 + jw;
            const bool edge = (unsigned)ix >= 32u;
            const int xcl = edge ? ln : ix;
            const s8b zz = {};
#pragma unroll
            for (int ks = 0; ks < 8; ++ks) {
                const int bo = ((xcl * 128 + half * 8 + ks * 16) * 2) ^ ((xcl & 7) << 4);
                s8b a  = *reinterpret_cast<const s8b*>((const char*)&lh[0] + bo);
                s8b a2 = *reinterpret_cast<const s8b*>((const char*)&ll[0] + bo);
                if (edge) { a = zz; a2 = zz; }
                const size_t wb = ((size_t)((tap * 8 + ks) * 2 + half) * 64 + cout) * 8;
                const s8b bb = *reinterpret_cast<const s8b*>(wh + wb);
                const s8b b2 = *reinterpret_cast<const s8b*>(wl + wb);
                accA = __builtin_amdgcn_mfma_f32_32x32x16_bf16(a, bb, accA, 0, 0, 0);
                accB = __builtin_amdgcn_mfma_f32_32x32x16_bf16(a2, bb, accB, 0, 0, 0);
                accB = __builtin_amdgcn_mfma_f32_32x32x16_bf16(a, b2, accB, 0, 0, 0);
            }
        }
        if (i + 1 < np) {
            __syncthreads();
            writerow();
            __syncthreads();
        }
    }

    const float bv = bias[cout];
#pragma unroll
    for (int r = 0; r < 16; ++r) {
        const int rl3 = (r & 3) + 8 * (r >> 2) + 4 * half;
        const int ow = 2 * rl3 + p;
        const size_t oe = (((size_t)((b * 64 + od) * 64 + ohh)) * 64 + ow) * 64 + cout;
        const float y = fmaxf(accA[r] + accB[r] + bv, 0.f);
        const bf16_t hh = f2b(y);
        oh[oe] = hh;
        ol[oe] = f2b(y - b2f(hh));
    }
}

// ---------------- ec0 via MFMA: s2 k=4, CIN=1, K=64 taps --------------------
__global__ __launch_bounds__(128)
void conv_ec0m(const float* __restrict__ x,
               const bf16_t* __restrict__ wh, const bf16_t* __restrict__ wm,
               const bf16_t* __restrict__ wl,
               const float* __restrict__ bias, float* __restrict__ of)
{
    __shared__ bf16_t lh[16 * 132], lm[16 * 132], ll[16 * 132];

    const int tid  = threadIdx.x;
    const int lane = tid & 63;
    const int wm2  = tid >> 6;
    const int half = lane >> 5, ln = lane & 31;
    const int w    = wm2 * 32 + ln;
    const int nwg  = gridDim.x;
    const int bid  = (blockIdx.x & 7) * (nwg >> 3) + (blockIdx.x >> 3);
    const int h    = bid % 64;
    const int d    = (bid / 64) % 64;
    const int b    = bid / 4096;

    for (int i = tid; i < 16 * 132; i += 128) {
        const int row = i / 132, col = i % 132;
        const int kd = row >> 2, kh = row & 3;
        const int iz = 2 * d + kd - 1, iy = 2 * h + kh - 1;
        const int ix = col - 1;
        float v = 0.f;
        if ((unsigned)iz < 128u && (unsigned)iy < 128u &&
            (unsigned)ix < 128u && col < 130)
            v = x[(size_t)((b * 128 + iz) * 128 + iy) * 128 + ix];
        unsigned short hh, mm2, ll2;
        split3s(v, hh, mm2, ll2);
        lh[i] = hh; lm[i] = mm2; ll[i] = ll2;
    }
    __syncthreads();

    f32x16 accA[2], accB[2];
#pragma unroll
    for (int i = 0; i < 16; ++i) {
        accA[0][i] = 0.f; accA[1][i] = 0.f;
        accB[0][i] = 0.f; accB[1][i] = 0.f;
    }

#pragma unroll
    for (int ks = 0; ks < 4; ++ks) {
        const int row0 = ks * 4 + 2 * half;
        const int i0 = row0 * 132 + 2 * w;
        const int i1 = i0 + 132;
        s8b ah, am, al3;
        {
            uint* ap = (uint*)&ah;
            ap[0] = *(const uint*)&lh[i0]; ap[1] = *(const uint*)&lh[i0 + 2];
            ap[2] = *(const uint*)&lh[i1]; ap[3] = *(const uint*)&lh[i1 + 2];
        }
        {
            uint* ap = (uint*)&am;
            ap[0] = *(const uint*)&lm[i0]; ap[1] = *(const uint*)&lm[i0 + 2];
            ap[2] = *(const uint*)&lm[i1]; ap[3] = *(const uint*)&lm[i1 + 2];
        }
        {
            uint* ap = (uint*)&al3;
            ap[0] = *(const uint*)&ll[i0]; ap[1] = *(const uint*)&ll[i0 + 2];
            ap[2] = *(const uint*)&ll[i1]; ap[3] = *(const uint*)&ll[i1 + 2];
        }
        const size_t wb0 = ((size_t)(ks * 2 + half) * 64 + ln) * 8;
#pragma unroll
        for (int n2 = 0; n2 < 2; ++n2) {
            const size_t wb = wb0 + n2 * 256;
            const s8b bh = *reinterpret_cast<const s8b*>(wh + wb);
            const s8b bm = *reinterpret_cast<const s8b*>(wm + wb);
            const s8b bl = *reinterpret_cast<const s8b*>(wl + wb);
            accA[n2] = __builtin_amdgcn_mfma_f32_32x32x16_bf16(ah, bh, accA[n2], 0, 0, 0);
            accB[n2] = __builtin_amdgcn_mfma_f32_32x32x16_bf16(ah, bm, accB[n2], 0, 0, 0);
            accA[n2] = __builtin_amdgcn_mfma_f32_32x32x16_bf16(am, bh, accA[n2], 0, 0, 0);
            accB[n2] = __builtin_amdgcn_mfma_f32_32x32x16_bf16(am, bm, accB[n2], 0, 0, 0);
            accA[n2] = __builtin_amdgcn_mfma_f32_32x32x16_bf16(al3, bh, accA[n2], 0, 0, 0);
            accB[n2] = __builtin_amdgcn_mfma_f32_32x32x16_bf16(ah, bl, accB[n2], 0, 0, 0);
        }
    }

    const size_t outrow = ((size_t)((b * 64 + d) * 64 + h)) * 64;
#pragma unroll
    for (int n2 = 0; n2 < 2; ++n2) {
        const int cout = n2 * 32 + ln;
        const float bv = bias[cout];
#pragma unroll
        for (int r = 0; r < 16; ++r) {
            const int rl3 = (r & 3) + 8 * (r >> 2) + 4 * half;
            const size_t oe = (outrow + wm2 * 32 + rl3) * 64 + cout;
            of[oe] = fmaxf(accA[n2][r] + accB[n2][r] + bv, 0.f);
        }
    }
}

// ---------------- du1: convT s2 k=4, CIN=64, COUT=1 — wave-level ------------
__global__ __launch_bounds__(256)
void convT_du1w(const bf16_t* __restrict__ inh, const bf16_t* __restrict__ inl,
                const float* __restrict__ wt, const float* __restrict__ bias,
                float* __restrict__ out)
{
    const int lane = threadIdx.x & 63;
    const int wv   = blockIdx.x * 4 + (threadIdx.x >> 6);
    const size_t obase = (size_t)wv * 16;
    const int ow0 = (int)(obase % 128);
    size_t rem = obase / 128;
    const int ohh = (int)(rem % 128); rem /= 128;
    const int od  = (int)(rem % 128); rem /= 128;
    const int b   = (int)rem;
    const int pd = od & 1, dz = od >> 1;
    const int ph = ohh & 1, hy = ohh >> 1;
    const int wx0 = ow0 >> 1;

    float acc[16];
#pragma unroll
    for (int o = 0; o < 16; ++o) acc[o] = 0.f;

#pragma unroll
    for (int jd = 0; jd < 2; ++jd) {
        const int kd = pd + 2 * jd;
        const int iz = dz + pd - 1 + jd;
        if ((unsigned)iz >= 64u) continue;
#pragma unroll
        for (int jh = 0; jh < 2; ++jh) {
            const int kh = ph + 2 * jh;
            const int iy = hy + ph - 1 + jh;
            if ((unsigned)iy >= 64u) continue;
            const size_t rbase = ((size_t)((b * 64 + iz) * 64 + iy)) * 64;
            float wv4[4];
#pragma unroll
            for (int kw = 0; kw < 4; ++kw)
                wv4[kw] = wt[(size_t)((kd * 4 + kh) * 4 + kw) * 64 + lane];
            float v[10];
#pragma unroll
            for (int t = 0; t < 10; ++t) {
                const int ix = wx0 - 1 + t;
                if ((unsigned)ix < 64u) {
                    const size_t a = (rbase + ix) * 64 + lane;
                    v[t] = b2f(inh[a]) + b2f(inl[a]);
                } else {
                    v[t] = 0.f;
                }
            }
#pragma unroll
            for (int o = 0; o < 16; ++o) {
                const int pw = o & 1;
                const int t0 = (o >> 1) + pw;
                acc[o] = fmaf(v[t0],     wv4[pw],     acc[o]);
                acc[o] = fmaf(v[t0 + 1], wv4[pw + 2], acc[o]);
            }
        }
    }

    const float b0 = bias[0];
#pragma unroll
    for (int o = 0; o < 16; ++o) {
        float s = acc[o];
        s += __shfl_xor(s, 1);
        s += __shfl_xor(s, 2);
        s += __shfl_xor(s, 4);
        s += __shfl_xor(s, 8);
        s += __shfl_xor(s, 16);
        s += __shfl_xor(s, 32);
        if (lane == 0) out[obase + o] = s + b0;
    }
}

// --------------------------------- VQ ---------------------------------------
__global__ void zero512(float* __restrict__ p) { p[threadIdx.x] = 0.0f; }

__global__ void vq_cnorm(const float* __restrict__ cb, float* __restrict__ cnorm)
{
    const int k = blockIdx.x * 64 + threadIdx.x;
    float s = 0.0f;
    for (int ci = 0; ci < 64; ++ci) { const float c = cb[k * 64 + ci]; s = fmaf(c, c, s); }
    cnorm[k] = s;
}

// 4 threads per z-vector, 128 codes each with 2-way ILP; shfl-xor min-reduce
// with lower-index tie-break (preserves first-min argmin semantics).
__global__ __launch_bounds__(256)
void vq_assign(const float* __restrict__ z, const float* __restrict__ cb,
               const float* __restrict__ cnorm, int* __restrict__ idx,
               float* __restrict__ hist, int N)
{
    const int gid = blockIdx.x * 256 + threadIdx.x;
    const int n   = gid >> 2;
    const int sub = gid & 3;
    const float4* zp = reinterpret_cast<const float4*>(z + (size_t)n * 64);
    float4 zv[16];
    float z2 = 0.0f;
#pragma unroll
    for (int i = 0; i < 16; ++i) {
        zv[i] = zp[i];
        z2 += zv[i].x * zv[i].x + zv[i].y * zv[i].y + zv[i].z * zv[i].z + zv[i].w * zv[i].w;
    }
    float best = 3.4e38f;
    int bi = 0;
    const int k0base = sub * 128;
#pragma unroll 1
    for (int k = k0base; k < k0base + 128; k += 2) {
        const float4* c0 = reinterpret_cast<const float4*>(cb + (size_t)k * 64);
        const float4* c1 = reinterpret_cast<const float4*>(cb + (size_t)(k + 1) * 64);
        float dot0 = 0.0f, dot1 = 0.0f;
#pragma unroll
        for (int i = 0; i < 16; ++i) {
            const float4 a = c0[i];
            const float4 c = c1[i];
            dot0 += zv[i].x * a.x + zv[i].y * a.y + zv[i].z * a.z + zv[i].w * a.w;
            dot1 += zv[i].x * c.x + zv[i].y * c.y + zv[i].z * c.z + zv[i].w * c.w;
        }
        const float d0 = z2 + cnorm[k] - 2.0f * dot0;
        const float d1 = z2 + cnorm[k + 1] - 2.0f * dot1;
        if (d0 < best) { best = d0; bi = k; }
        if (d1 < best) { best = d1; bi = k + 1; }
    }
    // reduce across the 4 sub-lanes (contiguous lanes of the same wave)
#pragma unroll
    for (int off = 1; off < 4; off <<= 1) {
        const float ob = __shfl_xor(best, off);
        const int   oi = __shfl_xor(bi, off);
        if (ob < best || (ob == best && oi < bi)) { best = ob; bi = oi; }
    }
    if (sub == 0) {
        idx[n] = bi;
        atomicAdd(&hist[bi], 1.0f);
    }
}

__global__ __launch_bounds__(256)
void vq_gather_split(const float* __restrict__ cb, const int* __restrict__ idx,
                     bf16_t* __restrict__ zh, bf16_t* __restrict__ zl)
{
    const int gid = blockIdx.x * 256 + threadIdx.x;
    const int n = gid >> 4, c4 = gid & 15;
    const int k = idx[n];
    const float4 c = reinterpret_cast<const float4*>(cb)[k * 16 + c4];
    ushort4 h, l;
    h.x = f2b(c.x); l.x = f2b(c.x - b2f(h.x));
    h.y = f2b(c.y); l.y = f2b(c.y - b2f(h.y));
    h.z = f2b(c.z); l.z = f2b(c.z - b2f(h.z));
    h.w = f2b(c.w); l.w = f2b(c.w - b2f(h.w));
    reinterpret_cast<ushort4*>(zh)[gid] = h;
    reinterpret_cast<ushort4*>(zl)[gid] = l;
}

__global__ __launch_bounds__(512)
void perplexity_k(const float* __restrict__ hist, float* __restrict__ out, float invN)
{
    __shared__ float red[512];
    const int t = threadIdx.x;
    const float p = hist[t] * invN;
    red[t] = p * logf(p + 1e-12f);
    __syncthreads();
    for (int s = 256; s > 0; s >>= 1) {
        if (t < s) red[t] += red[t + s];
        __syncthreads();
    }
    if (t == 0) out[0] = expf(-red[0]);
}

// ---------------------------------------------------------------------------
extern "C" void kernel_launch(void* const* d_in, const int* in_sizes, int n_in,
                              void* d_out, int out_size, void* d_ws, size_t ws_size,
                              hipStream_t stream)
{
    const float* x       = (const float*)d_in[0];
    const float* ec0_w   = (const float*)d_in[1];
    const float* ec0_b   = (const float*)d_in[2];
    const float* er0_c1w = (const float*)d_in[3];
    const float* er0_c1b = (const float*)d_in[4];
    const float* er0_c2w = (const float*)d_in[5];
    const float* er0_c2b = (const float*)d_in[6];
    const float* er0_g   = (const float*)d_in[7];
    const float* er0_be  = (const float*)d_in[8];
    const float* er0_m   = (const float*)d_in[9];
    const float* er0_v   = (const float*)d_in[10];
    const float* er0_a   = (const float*)d_in[11];
    const float* ec1_w   = (const float*)d_in[12];
    const float* ec1_b   = (const float*)d_in[13];
    const float* er1_c1w = (const float*)d_in[14];
    const float* er1_c1b = (const float*)d_in[15];
    const float* er1_c2w = (const float*)d_in[16];
    const float* er1_c2b = (const float*)d_in[17];
    const float* er1_g   = (const float*)d_in[18];
    const float* er1_be  = (const float*)d_in[19];
    const float* er1_m   = (const float*)d_in[20];
    const float* er1_v   = (const float*)d_in[21];
    const float* er1_a   = (const float*)d_in[22];
    const float* eo_w    = (const float*)d_in[23];
    const float* eo_b    = (const float*)d_in[24];
    const float* eo_a    = (const float*)d_in[25];
    const float* cb      = (const float*)d_in[26];
    const float* dc0_w   = (const float*)d_in[27];
    const float* dc0_b   = (const float*)d_in[28];
    const float* dc0_a   = (const float*)d_in[29];
    const float* dr0_c1w = (const float*)d_in[30];
    const float* dr0_c1b = (const float*)d_in[31];
    const float* dr0_c2w = (const float*)d_in[32];
    const float* dr0_c2b = (const float*)d_in[33];
    const float* dr0_g   = (const float*)d_in[34];
    const float* dr0_be  = (const float*)d_in[35];
    const float* dr0_m   = (const float*)d_in[36];
    const float* dr0_v   = (const float*)d_in[37];
    const float* dr0_a   = (const float*)d_in[38];
    const float* du0_w   = (const float*)d_in[39];
    const float* du0_b   = (const float*)d_in[40];
    const float* dr1_c1w = (const float*)d_in[41];
    const float* dr1_c1b = (const float*)d_in[42];
    const float* dr1_c2w = (const float*)d_in[43];
    const float* dr1_c2b = (const float*)d_in[44];
    const float* dr1_g   = (const float*)d_in[45];
    const float* dr1_be  = (const float*)d_in[46];
    const float* dr1_m   = (const float*)d_in[47];
    const float* dr1_v   = (const float*)d_in[48];
    const float* dr1_a   = (const float*)d_in[49];
    const float* du1_w   = (const float*)d_in[50];
    const float* du1_b   = (const float*)d_in[51];

    float* out = (float*)d_out;

    // ---- ws: A=[0,134MB) , H=[134MB,268MB) ----
    char* W = (char*)d_ws;
    float*  Af  = (float*)(W);
    float*  Hf  = (float*)(W + 134217728);
    float*  E1f = (float*)(W + 134217728);
    float*  R1f = (float*)(W + 134217728 + 33554432);
    float*  Zf  = (float*)(W);
    int*    IDX = (int*)  (W + 16777216);
    float*  CN  = (float*)(W + 17039360);
    float*  HS  = (float*)(W + 17041408);
    bf16_t* ZQh = (bf16_t*)(W + 33554432);
    bf16_t* ZQl = (bf16_t*)(W + 41943040);
    bf16_t* D0h = (bf16_t*)(W + 50331648);
    bf16_t* D0l = (bf16_t*)(W + 67108864);
    bf16_t* Gh  = (bf16_t*)(W + 83886080);
    bf16_t* Gl  = (bf16_t*)(W + 100663296);
    bf16_t* U0h = (bf16_t*)(W + 134217728);
    bf16_t* U0l = (bf16_t*)(W + 201326592);
    bf16_t* G1h = (bf16_t*)(W);
    bf16_t* G1l = (bf16_t*)(W + 67108864);

    // ---- weight arenas in d_out ----
    char* WB = (char*)d_out;
    bf16_t* e0c1h = (bf16_t*)(WB + 0);
    bf16_t* e0c1m = (bf16_t*)(WB + 221184);
    bf16_t* e0c1l = (bf16_t*)(WB + 442368);
    bf16_t* e0c2h = (bf16_t*)(WB + 663552);
    bf16_t* e0c2m = (bf16_t*)(WB + 884736);
    bf16_t* e0c2l = (bf16_t*)(WB + 1105920);
    bf16_t* ec1h  = (bf16_t*)(WB + 1327104);
    bf16_t* ec1m  = (bf16_t*)(WB + 2375680);
    bf16_t* ec1l  = (bf16_t*)(WB + 3424256);
    bf16_t* e1c1h = (bf16_t*)(WB + 4472832);
    bf16_t* e1c1m = (bf16_t*)(WB + 5357568);
    bf16_t* e1c1l = (bf16_t*)(WB + 6242304);
    bf16_t* e1c2h = (bf16_t*)(WB + 7127040);
    bf16_t* e1c2m = (bf16_t*)(WB + 8011776);
    bf16_t* e1c2l = (bf16_t*)(WB + 8896512);
    bf16_t* eoh   = (bf16_t*)(WB + 9781248);
    bf16_t* eom   = (bf16_t*)(WB + 10223616);
    bf16_t* eol   = (bf16_t*)(WB + 10665984);
    bf16_t* wec0h = (bf16_t*)(WB + 11108352);
    bf16_t* wec0m = (bf16_t*)(WB + 11116544);
    bf16_t* wec0l = (bf16_t*)(WB + 11124736);
    bf16_t* dc0h  = (bf16_t*)(WB + 0);
    bf16_t* dc0l  = (bf16_t*)(WB + 442368);
    bf16_t* d0c1h = (bf16_t*)(WB + 884736);
    bf16_t* d0c1l = (bf16_t*)(WB + 1769472);
    bf16_t* d0c2h = (bf16_t*)(WB + 2654208);
    bf16_t* d0c2l = (bf16_t*)(WB + 3538944);
    bf16_t* du0h  = (bf16_t*)(WB + 4423680);
    bf16_t* du0l  = (bf16_t*)(WB + 5472256);
    bf16_t* d1c1h = (bf16_t*)(WB + 6520832);
    bf16_t* d1c1l = (bf16_t*)(WB + 6742016);
    bf16_t* d1c2h = (bf16_t*)(WB + 6963200);
    bf16_t* d1c2l = (bf16_t*)(WB + 7184384);

    const float* fn = nullptr;
    const bf16_t* bn_ = nullptr;

    // ---- encoder weight prep (split-3, fragment-major) ----
    wprep3<<<16, 256, 0, stream>>>(ec0_w, wec0h, wec0m, wec0l, 64, 64, 4096);
    wprep3<<<432, 256, 0, stream>>>(er0_c1w, e0c1h, e0c1m, e0c1l, 64, 64, 110592);
    wprep3<<<432, 256, 0, stream>>>(er0_c2w, e0c2h, e0c2m, e0c2l, 64, 64, 110592);
    wprep3<<<2048, 256, 0, stream>>>(ec1_w, ec1h, ec1m, ec1l, 64, 128, 524288);
    wprep3<<<1728, 256, 0, stream>>>(er1_c1w, e1c1h, e1c1m, e1c1l, 128, 128, 442368);
    wprep3<<<1728, 256, 0, stream>>>(er1_c2w, e1c2h, e1c2m, e1c2l, 128, 128, 442368);
    wprep3<<<864, 256, 0, stream>>>(eo_w, eoh, eom, eol, 128, 64, 221184);

    // ---- encoder (fp32-class) ----
    conv_ec0m<<<8192, 128, 0, stream>>>(x, wec0h, wec0m, wec0l, ec0_b, Af);

    conv3e<64, 64, 64, 1, 1><<<8192, 128, 0, stream>>>(
        Af, e0c1h, e0c1m, e0c1l, er0_c1b, fn, fn, fn, fn, fn, fn, Hf);
    conv3e<64, 64, 64, 1, 3><<<8192, 128, 0, stream>>>(
        Hf, e0c2h, e0c2m, e0c2l, er0_c2b, er0_g, er0_be, er0_m, er0_v, er0_a, Af, Af);

    convs2e<<<2048, 128, 0, stream>>>(Af, ec1h, ec1m, ec1l, ec1_b, E1f);

    conv3e<128, 128, 32, 2, 1><<<2048, 128, 0, stream>>>(
        E1f, e1c1h, e1c1m, e1c1l, er1_c1b, fn, fn, fn, fn, fn, fn, R1f);
    conv3e<128, 128, 32, 2, 3><<<2048, 128, 0, stream>>>(
        R1f, e1c2h, e1c2m, e1c2l, er1_c2b, er1_g, er1_be, er1_m, er1_v, er1_a, E1f, E1f);

    conv3e<128, 64, 32, 1, 2><<<2048, 64, 0, stream>>>(
        E1f, eoh, eom, eol, eo_b, fn, fn, fn, fn, eo_a, fn, Zf);

    // ---- VQ (exact fp32, parallel assign) ----
    vq_cnorm<<<8, 64, 0, stream>>>(cb, CN);
    zero512<<<1, 512, 0, stream>>>(HS);
    vq_assign<<<1024, 256, 0, stream>>>(Zf, cb, CN, IDX, HS, 65536);
    perplexity_k<<<1, 512, 0, stream>>>(HS, out + 4194304, 1.0f / 65536.0f);
    vq_gather_split<<<4096, 256, 0, stream>>>(cb, IDX, ZQh, ZQl);

    // ---- decoder weight prep (split-2, fragment-major, overwrites arena) ----
    wprep_split<<<864, 256, 0, stream>>>(dc0_w, dc0h, dc0l, 64, 128, 221184);
    wprep_split<<<1728, 256, 0, stream>>>(dr0_c1w, d0c1h, d0c1l, 128, 128, 442368);
    wprep_split<<<1728, 256, 0, stream>>>(dr0_c2w, d0c2h, d0c2l, 128, 128, 442368);
    wprep_split<<<2048, 256, 0, stream>>>(du0_w, du0h, du0l, 128, 64, 524288);
    wprep_split<<<432, 256, 0, stream>>>(dr1_c1w, d1c1h, d1c1l, 64, 64, 110592);
    wprep_split<<<432, 256, 0, stream>>>(dr1_c2w, d1c2h, d1c2l, 64, 64, 110592);

    // ---- decoder (split-2 bf16) ----
    conv3d<64, 128, 32, 2, 2><<<2048, 128, 0, stream>>>(
        ZQh, ZQl, dc0h, dc0l, dc0_b, fn, fn, fn, fn, dc0_a, bn_, bn_, D0h, D0l);
    conv3d<128, 128, 32, 2, 1><<<2048, 128, 0, stream>>>(
        D0h, D0l, d0c1h, d0c1l, dr0_c1b, fn, fn, fn, fn, fn, bn_, bn_, Gh, Gl);
    conv3d<128, 128, 32, 2, 3><<<2048, 128, 0, stream>>>(
        Gh, Gl, d0c2h, d0c2l, dr0_c2b, dr0_g, dr0_be, dr0_m, dr0_v, dr0_a,
        D0h, D0l, D0h, D0l);

    convTm<<<8192, 256, 0, stream>>>(D0h, D0l, du0h, du0l, du0_b, U0h, U0l);

    conv3d<64, 64, 64, 1, 1><<<8192, 128, 0, stream>>>(
        U0h, U0l, d1c1h, d1c1l, dr1_c1b, fn, fn, fn, fn, fn, bn_, bn_, G1h, G1l);
    conv3d<64, 64, 64, 1, 3><<<8192, 128, 0, stream>>>(
        G1h, G1l, d1c2h, d1c2l, dr1_c2b, dr1_g, dr1_be, dr1_m, dr1_v, dr1_a,
        U0h, U0l, U0h, U0l);

    convT_du1w<<<65536, 256, 0, stream>>>(U0h, U0l, du1_w, du1_b, out);
}

// Round 15
// 5370.227 us; speedup vs baseline: 1.1369x; 1.1232x over previous
//
#include <hip/hip_runtime.h>
#include <cstdint>

// ---------------------------------------------------------------------------
// VQVAE forward — MFMA implicit-GEMM convolutions, channels-last.
//
// Round-15 = round-11 structure + ILP vq_assign (uniform-k preserved).
//   - Encoder: fp32 activations in memory; EXACT 3-way bf16 split (v=h+m+l)
//     at LDS-stage time; 6-MFMA products => fp32-class => VQ argmin safe.
//   - Decoder: split-2 bf16 (hi/lo) storage, 3-pass MFMA.
//   - vq_assign: 1 thread/z (k loop WAVE-UNIFORM => scalar cb loads),
//     k unrolled x4 with 4 independent dot chains (pipelines the 4-cyc
//     VALU dep latency). Round-14's lane-split k REVERTED: it broke the
//     scalar-load broadcast (VALUBusy 16->9.7%, dur 615->1067).
//     Per-code dot order unchanged => distances bit-identical.
// Retained: fragment-major weights w[tap][ks][half][cout][8k], T14 async-
// STAGE single-LDS-buffer, T1 XCD-chunked swizzle, LDS XOR swizzle,
// MFMA ec0, wave-level du1.
//
// C layout: col = lane&31, row = (reg&3) + 8*(reg>>2) + 4*(lane>>5)
// ---------------------------------------------------------------------------

typedef unsigned short bf16_t;
typedef __attribute__((ext_vector_type(8)))  short s8b;     // 8 x bf16 frag
typedef __attribute__((ext_vector_type(16))) float f32x16;  // 32x32 acc

__device__ __forceinline__ float b2f(bf16_t u) { return __uint_as_float((unsigned)u << 16); }
__device__ __forceinline__ bf16_t f2b(float f) {
    unsigned x = __float_as_uint(f);
    return (bf16_t)((x + 0x7FFFu + ((x >> 16) & 1u)) >> 16);
}

__device__ __forceinline__ void split3s(float v, unsigned short& h,
                                        unsigned short& m, unsigned short& l)
{
    const unsigned uv = __float_as_uint(v);
    const float fh = __uint_as_float(uv & 0xFFFF0000u);
    const float r1 = v - fh;
    const unsigned u1 = __float_as_uint(r1);
    const float fm = __uint_as_float(u1 & 0xFFFF0000u);
    const float r2 = r1 - fm;
    h = (unsigned short)(uv >> 16);
    m = (unsigned short)(u1 >> 16);
    l = (unsigned short)(__float_as_uint(r2) >> 16);
}

// ------------------------- weight prep ------------------------------------
// src [tap][ci][co] fp32 -> dst fragment-major [tap][ks][half][co][8k]
__device__ __forceinline__ int wdst(int tap, int ci_, int co_, int ci, int co)
{
    const int ks = ci_ >> 4, half = (ci_ >> 3) & 1, j = ci_ & 7;
    return (((tap * (ci >> 4) + ks) * 2 + half) * co + co_) * 8 + j;
}

__global__ __launch_bounds__(256)
void wprep3(const float* __restrict__ w, bf16_t* __restrict__ h,
            bf16_t* __restrict__ m, bf16_t* __restrict__ l,
            int ci, int co, int n)
{
    const int i = blockIdx.x * 256 + threadIdx.x;
    if (i >= n) return;
    const int co_ = i % co;
    const int ci_ = (i / co) % ci;
    const int tap = i / (co * ci);
    const int dst = wdst(tap, ci_, co_, ci, co);
    unsigned short hh, mm, ll2;
    split3s(w[i], hh, mm, ll2);
    h[dst] = hh; m[dst] = mm; l[dst] = ll2;
}

__global__ __launch_bounds__(256)
void wprep_split(const float* __restrict__ w, bf16_t* __restrict__ hi,
                 bf16_t* __restrict__ lo, int ci, int co, int n)
{
    const int i = blockIdx.x * 256 + threadIdx.x;
    if (i >= n) return;
    const int co_ = i % co;
    const int ci_ = (i / co) % ci;
    const int tap = i / (co * ci);
    const float v = w[i];
    const int dst = wdst(tap, ci_, co_, ci, co);
    const bf16_t h = f2b(v);
    hi[dst] = h;
    lo[dst] = f2b(v - b2f(h));
}

// ---------------- encoder 3x3x3 conv: fp32 in, T14-staged split-3 -----------
// EPI: 0=ReLU 1=swish 2=PReLU 3=BN+PReLU+skip+ReLU
template<int CIN, int COUT, int SD, int NW, int EPI>
__global__ __launch_bounds__((SD / 32) * NW * 64)
void conv3e(const float* __restrict__ xf,
            const bf16_t* __restrict__ wh, const bf16_t* __restrict__ wm,
            const bf16_t* __restrict__ wl,
            const float* __restrict__ bias,
            const float* __restrict__ g, const float* __restrict__ be,
            const float* __restrict__ mn, const float* __restrict__ vr,
            const float* __restrict__ al,
            const float* skf, float* __restrict__ of)
{
    constexpr int NT = (SD / 32) * NW * 64;
    constexpr int LP = (SD * CIN) / (4 * NT);
    constexpr int KS = CIN / 16;
    __shared__ bf16_t lh[SD * CIN], lm[SD * CIN], ll[SD * CIN];

    const int tid  = threadIdx.x;
    const int lane = tid & 63;
    const int wid  = tid >> 6;
    const int wn   = wid % NW, wm2 = wid / NW;
    const int half = lane >> 5, ln = lane & 31;
    const int w    = wm2 * 32 + ln;
    const int nwg  = gridDim.x;
    const int bid  = (blockIdx.x & 7) * (nwg >> 3) + (blockIdx.x >> 3);
    const int h    = bid % SD;
    const int d    = (bid / SD) % SD;
    const int b    = bid / (SD * SD);
    const int cout0 = wn * 64 + ln;

    int pz[9], py[9], pt[9], np = 0;
    for (int kd = 0; kd < 3; ++kd) {
        const int iz = d + kd - 1;
        if ((unsigned)iz >= (unsigned)SD) continue;
        for (int kh = 0; kh < 3; ++kh) {
            const int iy = h + kh - 1;
            if ((unsigned)iy >= (unsigned)SD) continue;
            pz[np] = iz; py[np] = iy; pt[np] = (kd * 3 + kh) * 3; ++np;
        }
    }

    f32x16 accA[2], accB[2];
#pragma unroll
    for (int i = 0; i < 16; ++i) {
        accA[0][i] = 0.f; accA[1][i] = 0.f;
        accB[0][i] = 0.f; accB[1][i] = 0.f;
    }

    float4 rg[LP];
    auto loadrow = [&](int iz, int iy) {
        const float* src = xf + ((size_t)((b * SD + iz) * SD + iy)) * SD * CIN;
#pragma unroll
        for (int j = 0; j < LP; ++j)
            rg[j] = *reinterpret_cast<const float4*>(src + (size_t)(tid + j * NT) * 4);
    };
    auto writerow = [&]() {
#pragma unroll
        for (int j = 0; j < LP; ++j) {
            const int idx = (tid + j * NT) * 4;
            const int vox = idx / CIN, ch = idx % CIN;
            ushort4 h4, m4, l4;
            split3s(rg[j].x, h4.x, m4.x, l4.x);
            split3s(rg[j].y, h4.y, m4.y, l4.y);
            split3s(rg[j].z, h4.z, m4.z, l4.z);
            split3s(rg[j].w, h4.w, m4.w, l4.w);
            const int bo = ((vox * CIN + ch) * 2) ^ ((vox & 7) << 4);
            *reinterpret_cast<ushort4*>((char*)&lh[0] + bo) = h4;
            *reinterpret_cast<ushort4*>((char*)&lm[0] + bo) = m4;
            *reinterpret_cast<ushort4*>((char*)&ll[0] + bo) = l4;
        }
    };

    loadrow(pz[0], py[0]);
    writerow();
    __syncthreads();
#pragma unroll 1
    for (int i = 0; i < np; ++i) {
        if (i + 1 < np) loadrow(pz[i + 1], py[i + 1]);   // issue early (T14)
#pragma unroll
        for (int kw = 0; kw < 3; ++kw) {
            const int tap = pt[i] + kw;
            const int iw = w + kw - 1;
            const bool edge = (unsigned)iw >= (unsigned)SD;
            const int wcl = edge ? w : iw;
            const s8b zz = {};
#pragma unroll
            for (int ks = 0; ks < KS; ++ks) {
                const int bo = ((wcl * CIN + half * 8 + ks * 16) * 2) ^ ((wcl & 7) << 4);
                s8b ah  = *reinterpret_cast<const s8b*>((const char*)&lh[0] + bo);
                s8b am  = *reinterpret_cast<const s8b*>((const char*)&lm[0] + bo);
                s8b al3 = *reinterpret_cast<const s8b*>((const char*)&ll[0] + bo);
                if (edge) { ah = zz; am = zz; al3 = zz; }
                const size_t wb0 = ((size_t)((tap * KS + ks) * 2 + half) * COUT + cout0) * 8;
#pragma unroll
                for (int n2 = 0; n2 < 2; ++n2) {
                    const size_t wb = wb0 + n2 * 256;   // cout += 32
                    const s8b bh = *reinterpret_cast<const s8b*>(wh + wb);
                    const s8b bm = *reinterpret_cast<const s8b*>(wm + wb);
                    const s8b bl = *reinterpret_cast<const s8b*>(wl + wb);
                    accA[n2] = __builtin_amdgcn_mfma_f32_32x32x16_bf16(ah, bh, accA[n2], 0, 0, 0);
                    accB[n2] = __builtin_amdgcn_mfma_f32_32x32x16_bf16(ah, bm, accB[n2], 0, 0, 0);
                    accA[n2] = __builtin_amdgcn_mfma_f32_32x32x16_bf16(am, bh, accA[n2], 0, 0, 0);
                    accB[n2] = __builtin_amdgcn_mfma_f32_32x32x16_bf16(am, bm, accB[n2], 0, 0, 0);
                    accA[n2] = __builtin_amdgcn_mfma_f32_32x32x16_bf16(al3, bh, accA[n2], 0, 0, 0);
                    accB[n2] = __builtin_amdgcn_mfma_f32_32x32x16_bf16(ah, bl, accB[n2], 0, 0, 0);
                }
            }
        }
        if (i + 1 < np) {
            __syncthreads();          // all waves done reading LDS
            writerow();               // implicit vmcnt wait on rg here
            __syncthreads();          // LDS ready
        }
    }

    const size_t outrow = ((size_t)((b * SD + d) * SD + h)) * SD;
#pragma unroll
    for (int n2 = 0; n2 < 2; ++n2) {
        const int cout = wn * 64 + n2 * 32 + ln;
        const float bv = bias[cout];
        float sc = 0.f, mm = 0.f, bb2 = 0.f, aa = 0.f;
        if constexpr (EPI == 3) {
            sc = g[cout] * (1.0f / sqrtf(vr[cout] + 1e-3f));
            mm = mn[cout]; bb2 = be[cout]; aa = al[cout];
        }
        if constexpr (EPI == 2) aa = al[cout];
#pragma unroll
        for (int r = 0; r < 16; ++r) {
            const int rl = (r & 3) + 8 * (r >> 2) + 4 * half;
            const size_t oe = (outrow + wm2 * 32 + rl) * COUT + cout;
            float y = accA[n2][r] + accB[n2][r] + bv;
            if constexpr (EPI == 0) y = fmaxf(y, 0.f);
            else if constexpr (EPI == 1) y = y / (1.f + expf(-y));
            else if constexpr (EPI == 2) y = y > 0.f ? y : aa * y;
            else {
                float t2 = (y - mm) * sc + bb2;
                t2 = t2 > 0.f ? t2 : aa * t2;
                y = fmaxf(skf[oe] + t2, 0.f);
            }
            of[oe] = y;
        }
    }
}

// ---------------- ec1: stride-2 k=4, fp32 in, T14-staged split-3 ------------
__global__ __launch_bounds__(128)
void convs2e(const float* __restrict__ xf,
             const bf16_t* __restrict__ wh, const bf16_t* __restrict__ wm,
             const bf16_t* __restrict__ wl,
             const float* __restrict__ bias, float* __restrict__ of)
{
    constexpr int NT = 128, LP = (64 * 64) / (4 * NT);
    __shared__ bf16_t lh[64 * 64], lm[64 * 64], ll[64 * 64];

    const int tid  = threadIdx.x;
    const int lane = tid & 63;
    const int wn   = tid >> 6;
    const int half = lane >> 5, ln = lane & 31;
    const int nwg  = gridDim.x;
    const int bid  = (blockIdx.x & 7) * (nwg >> 3) + (blockIdx.x >> 3);
    const int h    = bid % 32;
    const int d    = (bid / 32) % 32;
    const int b    = bid / 1024;
    const int cout0 = wn * 64 + ln;

    int pz[16], py[16], pt[16], np = 0;
    for (int kd = 0; kd < 4; ++kd) {
        const int iz = 2 * d + kd - 1;
        if ((unsigned)iz >= 64u) continue;
        for (int kh = 0; kh < 4; ++kh) {
            const int iy = 2 * h + kh - 1;
            if ((unsigned)iy >= 64u) continue;
            pz[np] = iz; py[np] = iy; pt[np] = (kd * 4 + kh) * 4; ++np;
        }
    }

    f32x16 accA[2], accB[2];
#pragma unroll
    for (int i = 0; i < 16; ++i) {
        accA[0][i] = 0.f; accA[1][i] = 0.f;
        accB[0][i] = 0.f; accB[1][i] = 0.f;
    }

    float4 rg[LP];
    auto loadrow = [&](int iz, int iy) {
        const float* src = xf + ((size_t)((b * 64 + iz) * 64 + iy)) * 64 * 64;
#pragma unroll
        for (int j = 0; j < LP; ++j)
            rg[j] = *reinterpret_cast<const float4*>(src + (size_t)(tid + j * NT) * 4);
    };
    auto writerow = [&]() {
#pragma unroll
        for (int j = 0; j < LP; ++j) {
            const int idx = (tid + j * NT) * 4;
            const int vox = idx / 64, ch = idx % 64;
            ushort4 h4, m4, l4;
            split3s(rg[j].x, h4.x, m4.x, l4.x);
            split3s(rg[j].y, h4.y, m4.y, l4.y);
            split3s(rg[j].z, h4.z, m4.z, l4.z);
            split3s(rg[j].w, h4.w, m4.w, l4.w);
            const int bo = ((vox * 64 + ch) * 2) ^ ((vox & 7) << 4);
            *reinterpret_cast<ushort4*>((char*)&lh[0] + bo) = h4;
            *reinterpret_cast<ushort4*>((char*)&lm[0] + bo) = m4;
            *reinterpret_cast<ushort4*>((char*)&ll[0] + bo) = l4;
        }
    };

    loadrow(pz[0], py[0]);
    writerow();
    __syncthreads();
#pragma unroll 1
    for (int i = 0; i < np; ++i) {
        if (i + 1 < np) loadrow(pz[i + 1], py[i + 1]);
#pragma unroll
        for (int kw = 0; kw < 4; ++kw) {
            const int tap = pt[i] + kw;
            const int iw = 2 * ln + kw - 1;
            const bool edge = (unsigned)iw >= 64u;
            const int wcl = edge ? 2 * ln : iw;
            const s8b zz = {};
#pragma unroll
            for (int ks = 0; ks < 4; ++ks) {
                const int bo = ((wcl * 64 + half * 8 + ks * 16) * 2) ^ ((wcl & 7) << 4);
                s8b ah  = *reinterpret_cast<const s8b*>((const char*)&lh[0] + bo);
                s8b am  = *reinterpret_cast<const s8b*>((const char*)&lm[0] + bo);
                s8b al3 = *reinterpret_cast<const s8b*>((const char*)&ll[0] + bo);
                if (edge) { ah = zz; am = zz; al3 = zz; }
                const size_t wb0 = ((size_t)((tap * 4 + ks) * 2 + half) * 128 + cout0) * 8;
#pragma unroll
                for (int n2 = 0; n2 < 2; ++n2) {
                    const size_t wb = wb0 + n2 * 256;
                    const s8b bh = *reinterpret_cast<const s8b*>(wh + wb);
                    const s8b bm = *reinterpret_cast<const s8b*>(wm + wb);
                    const s8b bl = *reinterpret_cast<const s8b*>(wl + wb);
                    accA[n2] = __builtin_amdgcn_mfma_f32_32x32x16_bf16(ah, bh, accA[n2], 0, 0, 0);
                    accB[n2] = __builtin_amdgcn_mfma_f32_32x32x16_bf16(ah, bm, accB[n2], 0, 0, 0);
                    accA[n2] = __builtin_amdgcn_mfma_f32_32x32x16_bf16(am, bh, accA[n2], 0, 0, 0);
                    accB[n2] = __builtin_amdgcn_mfma_f32_32x32x16_bf16(am, bm, accB[n2], 0, 0, 0);
                    accA[n2] = __builtin_amdgcn_mfma_f32_32x32x16_bf16(al3, bh, accA[n2], 0, 0, 0);
                    accB[n2] = __builtin_amdgcn_mfma_f32_32x32x16_bf16(ah, bl, accB[n2], 0, 0, 0);
                }
            }
        }
        if (i + 1 < np) {
            __syncthreads();
            writerow();
            __syncthreads();
        }
    }

    const size_t outrow = ((size_t)((b * 32 + d) * 32 + h)) * 32;
#pragma unroll
    for (int n2 = 0; n2 < 2; ++n2) {
        const int cout = wn * 64 + n2 * 32 + ln;
        const float bv = bias[cout];
#pragma unroll
        for (int r = 0; r < 16; ++r) {
            const int rl = (r & 3) + 8 * (r >> 2) + 4 * half;
            const size_t oe = (outrow + rl) * 128 + cout;
            of[oe] = fmaxf(accA[n2][r] + accB[n2][r] + bv, 0.f);
        }
    }
}

// ---------------- decoder 3x3x3 conv: split-2 bf16, T14-staged --------------
template<int CIN, int COUT, int SD, int NW, int EPI>
__global__ __launch_bounds__((SD / 32) * NW * 64)
void conv3d(const bf16_t* __restrict__ xh, const bf16_t* __restrict__ xl,
            const bf16_t* __restrict__ wh, const bf16_t* __restrict__ wl,
            const float* __restrict__ bias,
            const float* __restrict__ g, const float* __restrict__ be,
            const float* __restrict__ mn, const float* __restrict__ vr,
            const float* __restrict__ al,
            const bf16_t* skh, const bf16_t* skl,
            bf16_t* oh, bf16_t* ol)
{
    constexpr int NT = (SD / 32) * NW * 64;
    constexpr int LP = (SD * CIN) / (4 * NT);
    constexpr int KS = CIN / 16;
    __shared__ bf16_t lh[SD * CIN], ll[SD * CIN];

    const int tid  = threadIdx.x;
    const int lane = tid & 63;
    const int wid  = tid >> 6;
    const int wn   = wid % NW, wm2 = wid / NW;
    const int half = lane >> 5, ln = lane & 31;
    const int w    = wm2 * 32 + ln;
    const int nwg  = gridDim.x;
    const int bid  = (blockIdx.x & 7) * (nwg >> 3) + (blockIdx.x >> 3);
    const int h    = bid % SD;
    const int d    = (bid / SD) % SD;
    const int b    = bid / (SD * SD);
    const int cout0 = wn * 64 + ln;

    int pz[9], py[9], pt[9], np = 0;
    for (int kd = 0; kd < 3; ++kd) {
        const int iz = d + kd - 1;
        if ((unsigned)iz >= (unsigned)SD) continue;
        for (int kh = 0; kh < 3; ++kh) {
            const int iy = h + kh - 1;
            if ((unsigned)iy >= (unsigned)SD) continue;
            pz[np] = iz; py[np] = iy; pt[np] = (kd * 3 + kh) * 3; ++np;
        }
    }

    f32x16 accA[2], accB[2];
#pragma unroll
    for (int i = 0; i < 16; ++i) {
        accA[0][i] = 0.f; accA[1][i] = 0.f;
        accB[0][i] = 0.f; accB[1][i] = 0.f;
    }

    ushort4 rh[LP], rl2a[LP];
    auto loadrow = [&](int iz, int iy) {
        const size_t rb = ((size_t)((b * SD + iz) * SD + iy)) * SD * CIN;
#pragma unroll
        for (int j = 0; j < LP; ++j) {
            const int idx = (tid + j * NT) * 4;
            rh[j]   = *reinterpret_cast<const ushort4*>(xh + rb + idx);
            rl2a[j] = *reinterpret_cast<const ushort4*>(xl + rb + idx);
        }
    };
    auto writerow = [&]() {
#pragma unroll
        for (int j = 0; j < LP; ++j) {
            const int idx = (tid + j * NT) * 4;
            const int vox = idx / CIN, ch = idx % CIN;
            const int bo = ((vox * CIN + ch) * 2) ^ ((vox & 7) << 4);
            *reinterpret_cast<ushort4*>((char*)&lh[0] + bo) = rh[j];
            *reinterpret_cast<ushort4*>((char*)&ll[0] + bo) = rl2a[j];
        }
    };

    loadrow(pz[0], py[0]);
    writerow();
    __syncthreads();
#pragma unroll 1
    for (int i = 0; i < np; ++i) {
        if (i + 1 < np) loadrow(pz[i + 1], py[i + 1]);
#pragma unroll
        for (int kw = 0; kw < 3; ++kw) {
            const int tap = pt[i] + kw;
            const int iw = w + kw - 1;
            const bool edge = (unsigned)iw >= (unsigned)SD;
            const int wcl = edge ? w : iw;
            const s8b zz = {};
#pragma unroll
            for (int ks = 0; ks < KS; ++ks) {
                const int bo = ((wcl * CIN + half * 8 + ks * 16) * 2) ^ ((wcl & 7) << 4);
                s8b ah  = *reinterpret_cast<const s8b*>((const char*)&lh[0] + bo);
                s8b al2 = *reinterpret_cast<const s8b*>((const char*)&ll[0] + bo);
                if (edge) { ah = zz; al2 = zz; }
                const size_t wb0 = ((size_t)((tap * KS + ks) * 2 + half) * COUT + cout0) * 8;
#pragma unroll
                for (int n2 = 0; n2 < 2; ++n2) {
                    const size_t wb = wb0 + n2 * 256;
                    const s8b bh = *reinterpret_cast<const s8b*>(wh + wb);
                    const s8b bl = *reinterpret_cast<const s8b*>(wl + wb);
                    accA[n2] = __builtin_amdgcn_mfma_f32_32x32x16_bf16(ah, bh, accA[n2], 0, 0, 0);
                    accB[n2] = __builtin_amdgcn_mfma_f32_32x32x16_bf16(al2, bh, accB[n2], 0, 0, 0);
                    accB[n2] = __builtin_amdgcn_mfma_f32_32x32x16_bf16(ah, bl, accB[n2], 0, 0, 0);
                }
            }
        }
        if (i + 1 < np) {
            __syncthreads();
            writerow();
            __syncthreads();
        }
    }

    const size_t outrow = ((size_t)((b * SD + d) * SD + h)) * SD;
#pragma unroll
    for (int n2 = 0; n2 < 2; ++n2) {
        const int cout = wn * 64 + n2 * 32 + ln;
        const float bv = bias[cout];
        float sc = 0.f, mm = 0.f, bb2 = 0.f, aa = 0.f;
        if constexpr (EPI == 3) {
            sc = g[cout] * (1.0f / sqrtf(vr[cout] + 1e-3f));
            mm = mn[cout]; bb2 = be[cout]; aa = al[cout];
        }
        if constexpr (EPI == 2) aa = al[cout];
#pragma unroll
        for (int r = 0; r < 16; ++r) {
            const int rl3 = (r & 3) + 8 * (r >> 2) + 4 * half;
            const size_t oe = (outrow + wm2 * 32 + rl3) * COUT + cout;
            float y = accA[n2][r] + accB[n2][r] + bv;
            if constexpr (EPI == 0) y = fmaxf(y, 0.f);
            else if constexpr (EPI == 1) y = y / (1.f + expf(-y));
            else if constexpr (EPI == 2) y = y > 0.f ? y : aa * y;
            else {
                float t2 = (y - mm) * sc + bb2;
                t2 = t2 > 0.f ? t2 : aa * t2;
                float sv = b2f(skh[oe]) + b2f(skl[oe]);
                y = fmaxf(sv + t2, 0.f);
            }
            const bf16_t hh = f2b(y);
            oh[oe] = hh;
            ol[oe] = f2b(y - b2f(hh));
        }
    }
}

// ---------------- convT stride-2 k=4 (du0, split-2, T14-staged) -------------
__global__ __launch_bounds__(256)
void convTm(const bf16_t* __restrict__ xh, const bf16_t* __restrict__ xl,
            const bf16_t* __restrict__ wh, const bf16_t* __restrict__ wl,
            const float* __restrict__ bias,
            bf16_t* __restrict__ oh, bf16_t* __restrict__ ol)
{
    constexpr int NT = 256, LP = (32 * 128) / (4 * NT);
    __shared__ bf16_t lh[32 * 128], ll[32 * 128];

    const int tid  = threadIdx.x;
    const int lane = tid & 63;
    const int wid  = tid >> 6;
    const int wn   = wid & 1, p = wid >> 1;
    const int half = lane >> 5, ln = lane & 31;
    const int nwg  = gridDim.x;
    const int bid  = (blockIdx.x & 7) * (nwg >> 3) + (blockIdx.x >> 3);
    const int ohh  = bid % 64;
    const int od   = (bid / 64) % 64;
    const int b    = bid / 4096;
    const int pd = od & 1, dz = od >> 1;
    const int ph = ohh & 1, hy = ohh >> 1;
    const int cout = wn * 32 + ln;

    int pz[4], py[4], pt[4], np = 0;
    for (int jd = 0; jd < 2; ++jd) {
        const int kd = pd + 2 * jd;
        const int iz = dz + pd - 1 + jd;
        if ((unsigned)iz >= 32u) continue;
        for (int jh = 0; jh < 2; ++jh) {
            const int kh = ph + 2 * jh;
            const int iy = hy + ph - 1 + jh;
            if ((unsigned)iy >= 32u) continue;
            pz[np] = iz; py[np] = iy; pt[np] = (kd * 4 + kh) * 4; ++np;
        }
    }

    f32x16 accA, accB;
#pragma unroll
    for (int i = 0; i < 16; ++i) { accA[i] = 0.0f; accB[i] = 0.0f; }

    ushort4 rh[LP], rl2a[LP];
    auto loadrow = [&](int iz, int iy) {
        const size_t rb = ((size_t)((b * 32 + iz) * 32 + iy)) * 32 * 128;
#pragma unroll
        for (int j = 0; j < LP; ++j) {
            const int idx = (tid + j * NT) * 4;
            rh[j]   = *reinterpret_cast<const ushort4*>(xh + rb + idx);
            rl2a[j] = *reinterpret_cast<const ushort4*>(xl + rb + idx);
        }
    };
    auto writerow = [&]() {
#pragma unroll
        for (int j = 0; j < LP; ++j) {
            const int idx = (tid + j * NT) * 4;
            const int vox = idx / 128, ch = idx % 128;
            const int bo = ((vox * 128 + ch) * 2) ^ ((vox & 7) << 4);
            *reinterpret_cast<ushort4*>((char*)&lh[0] + bo) = rh[j];
            *reinterpret_cast<ushort4*>((char*)&ll[0] + bo) = rl2a[j];
        }
    };

    loadrow(pz[0], py[0]);
    writerow();
    __syncthreads();
#pragma unroll 1
    for (int i = 0; i < np; ++i) {
        if (i + 1 < np) loadrow(pz[i + 1], py[i + 1]);
#pragma unroll
        for (int jw = 0; jw < 2; ++jw) {
            const int kw = p + 2 * jw;
            const int tap = pt[i] + kw;
            const int ix = ln + p - 1 + jw;
            const bool edge = (unsigned)ix >= 32u;
            const int xcl = edge ? ln : ix;
            const s8b zz = {};
#pragma unroll
            for (int ks = 0; ks < 8; ++ks) {
                const int bo = ((xcl * 128 + half * 8 + ks * 16) * 2) ^ ((xcl & 7) << 4);
                s8b a  = *reinterpret_cast<const s8b*>((const char*)&lh[0] + bo);
                s8b a2 = *reinterpret_cast<const s8b*>((const char*)&ll[0] + bo);
                if (edge) { a = zz; a2 = zz; }
                const size_t wb = ((size_t)((tap * 8 + ks) * 2 + half) * 64 + cout) * 8;
                const s8b bb = *reinterpret_cast<const s8b*>(wh + wb);
                const s8b b2 = *reinterpret_cast<const s8b*>(wl + wb);
                accA = __builtin_amdgcn_mfma_f32_32x32x16_bf16(a, bb, accA, 0, 0, 0);
                accB = __builtin_amdgcn_mfma_f32_32x32x16_bf16(a2, bb, accB, 0, 0, 0);
                accB = __builtin_amdgcn_mfma_f32_32x32x16_bf16(a, b2, accB, 0, 0, 0);
            }
        }
        if (i + 1 < np) {
            __syncthreads();
            writerow();
            __syncthreads();
        }
    }

    const float bv = bias[cout];
#pragma unroll
    for (int r = 0; r < 16; ++r) {
        const int rl3 = (r & 3) + 8 * (r >> 2) + 4 * half;
        const int ow = 2 * rl3 + p;
        const size_t oe = (((size_t)((b * 64 + od) * 64 + ohh)) * 64 + ow) * 64 + cout;
        const float y = fmaxf(accA[r] + accB[r] + bv, 0.f);
        const bf16_t hh = f2b(y);
        oh[oe] = hh;
        ol[oe] = f2b(y - b2f(hh));
    }
}

// ---------------- ec0 via MFMA: s2 k=4, CIN=1, K=64 taps --------------------
__global__ __launch_bounds__(128)
void conv_ec0m(const float* __restrict__ x,
               const bf16_t* __restrict__ wh, const bf16_t* __restrict__ wm,
               const bf16_t* __restrict__ wl,
               const float* __restrict__ bias, float* __restrict__ of)
{
    __shared__ bf16_t lh[16 * 132], lm[16 * 132], ll[16 * 132];

    const int tid  = threadIdx.x;
    const int lane = tid & 63;
    const int wm2  = tid >> 6;
    const int half = lane >> 5, ln = lane & 31;
    const int w    = wm2 * 32 + ln;
    const int nwg  = gridDim.x;
    const int bid  = (blockIdx.x & 7) * (nwg >> 3) + (blockIdx.x >> 3);
    const int h    = bid % 64;
    const int d    = (bid / 64) % 64;
    const int b    = bid / 4096;

    for (int i = tid; i < 16 * 132; i += 128) {
        const int row = i / 132, col = i % 132;
        const int kd = row >> 2, kh = row & 3;
        const int iz = 2 * d + kd - 1, iy = 2 * h + kh - 1;
        const int ix = col - 1;
        float v = 0.f;
        if ((unsigned)iz < 128u && (unsigned)iy < 128u &&
            (unsigned)ix < 128u && col < 130)
            v = x[(size_t)((b * 128 + iz) * 128 + iy) * 128 + ix];
        unsigned short hh, mm2, ll2;
        split3s(v, hh, mm2, ll2);
        lh[i] = hh; lm[i] = mm2; ll[i] = ll2;
    }
    __syncthreads();

    f32x16 accA[2], accB[2];
#pragma unroll
    for (int i = 0; i < 16; ++i) {
        accA[0][i] = 0.f; accA[1][i] = 0.f;
        accB[0][i] = 0.f; accB[1][i] = 0.f;
    }

#pragma unroll
    for (int ks = 0; ks < 4; ++ks) {
        const int row0 = ks * 4 + 2 * half;
        const int i0 = row0 * 132 + 2 * w;
        const int i1 = i0 + 132;
        s8b ah, am, al3;
        {
            uint* ap = (uint*)&ah;
            ap[0] = *(const uint*)&lh[i0]; ap[1] = *(const uint*)&lh[i0 + 2];
            ap[2] = *(const uint*)&lh[i1]; ap[3] = *(const uint*)&lh[i1 + 2];
        }
        {
            uint* ap = (uint*)&am;
            ap[0] = *(const uint*)&lm[i0]; ap[1] = *(const uint*)&lm[i0 + 2];
            ap[2] = *(const uint*)&lm[i1]; ap[3] = *(const uint*)&lm[i1 + 2];
        }
        {
            uint* ap = (uint*)&al3;
            ap[0] = *(const uint*)&ll[i0]; ap[1] = *(const uint*)&ll[i0 + 2];
            ap[2] = *(const uint*)&ll[i1]; ap[3] = *(const uint*)&ll[i1 + 2];
        }
        const size_t wb0 = ((size_t)(ks * 2 + half) * 64 + ln) * 8;
#pragma unroll
        for (int n2 = 0; n2 < 2; ++n2) {
            const size_t wb = wb0 + n2 * 256;
            const s8b bh = *reinterpret_cast<const s8b*>(wh + wb);
            const s8b bm = *reinterpret_cast<const s8b*>(wm + wb);
            const s8b bl = *reinterpret_cast<const s8b*>(wl + wb);
            accA[n2] = __builtin_amdgcn_mfma_f32_32x32x16_bf16(ah, bh, accA[n2], 0, 0, 0);
            accB[n2] = __builtin_amdgcn_mfma_f32_32x32x16_bf16(ah, bm, accB[n2], 0, 0, 0);
            accA[n2] = __builtin_amdgcn_mfma_f32_32x32x16_bf16(am, bh, accA[n2], 0, 0, 0);
            accB[n2] = __builtin_amdgcn_mfma_f32_32x32x16_bf16(am, bm, accB[n2], 0, 0, 0);
            accA[n2] = __builtin_amdgcn_mfma_f32_32x32x16_bf16(al3, bh, accA[n2], 0, 0, 0);
            accB[n2] = __builtin_amdgcn_mfma_f32_32x32x16_bf16(ah, bl, accB[n2], 0, 0, 0);
        }
    }

    const size_t outrow = ((size_t)((b * 64 + d) * 64 + h)) * 64;
#pragma unroll
    for (int n2 = 0; n2 < 2; ++n2) {
        const int cout = n2 * 32 + ln;
        const float bv = bias[cout];
#pragma unroll
        for (int r = 0; r < 16; ++r) {
            const int rl3 = (r & 3) + 8 * (r >> 2) + 4 * half;
            const size_t oe = (outrow + wm2 * 32 + rl3) * 64 + cout;
            of[oe] = fmaxf(accA[n2][r] + accB[n2][r] + bv, 0.f);
        }
    }
}

// ---------------- du1: convT s2 k=4, CIN=64, COUT=1 — wave-level ------------
__global__ __launch_bounds__(256)
void convT_du1w(const bf16_t* __restrict__ inh, const bf16_t* __restrict__ inl,
                const float* __restrict__ wt, const float* __restrict__ bias,
                float* __restrict__ out)
{
    const int lane = threadIdx.x & 63;
    const int wv   = blockIdx.x * 4 + (threadIdx.x >> 6);
    const size_t obase = (size_t)wv * 16;
    const int ow0 = (int)(obase % 128);
    size_t rem = obase / 128;
    const int ohh = (int)(rem % 128); rem /= 128;
    const int od  = (int)(rem % 128); rem /= 128;
    const int b   = (int)rem;
    const int pd = od & 1, dz = od >> 1;
    const int ph = ohh & 1, hy = ohh >> 1;
    const int wx0 = ow0 >> 1;

    float acc[16];
#pragma unroll
    for (int o = 0; o < 16; ++o) acc[o] = 0.f;

#pragma unroll
    for (int jd = 0; jd < 2; ++jd) {
        const int kd = pd + 2 * jd;
        const int iz = dz + pd - 1 + jd;
        if ((unsigned)iz >= 64u) continue;
#pragma unroll
        for (int jh = 0; jh < 2; ++jh) {
            const int kh = ph + 2 * jh;
            const int iy = hy + ph - 1 + jh;
            if ((unsigned)iy >= 64u) continue;
            const size_t rbase = ((size_t)((b * 64 + iz) * 64 + iy)) * 64;
            float wv4[4];
#pragma unroll
            for (int kw = 0; kw < 4; ++kw)
                wv4[kw] = wt[(size_t)((kd * 4 + kh) * 4 + kw) * 64 + lane];
            float v[10];
#pragma unroll
            for (int t = 0; t < 10; ++t) {
                const int ix = wx0 - 1 + t;
                if ((unsigned)ix < 64u) {
                    const size_t a = (rbase + ix) * 64 + lane;
                    v[t] = b2f(inh[a]) + b2f(inl[a]);
                } else {
                    v[t] = 0.f;
                }
            }
#pragma unroll
            for (int o = 0; o < 16; ++o) {
                const int pw = o & 1;
                const int t0 = (o >> 1) + pw;
                acc[o] = fmaf(v[t0],     wv4[pw],     acc[o]);
                acc[o] = fmaf(v[t0 + 1], wv4[pw + 2], acc[o]);
            }
        }
    }

    const float b0 = bias[0];
#pragma unroll
    for (int o = 0; o < 16; ++o) {
        float s = acc[o];
        s += __shfl_xor(s, 1);
        s += __shfl_xor(s, 2);
        s += __shfl_xor(s, 4);
        s += __shfl_xor(s, 8);
        s += __shfl_xor(s, 16);
        s += __shfl_xor(s, 32);
        if (lane == 0) out[obase + o] = s + b0;
    }
}

// --------------------------------- VQ ---------------------------------------
__global__ void zero512(float* __restrict__ p) { p[threadIdx.x] = 0.0f; }

__global__ void vq_cnorm(const float* __restrict__ cb, float* __restrict__ cnorm)
{
    const int k = blockIdx.x * 64 + threadIdx.x;
    float s = 0.0f;
    for (int ci = 0; ci < 64; ++ci) { const float c = cb[k * 64 + ci]; s = fmaf(c, c, s); }
    cnorm[k] = s;
}

// 1 thread per z (k loop wave-uniform => scalar cb loads), k unrolled x4
// with 4 independent dot chains. Per-code dot order identical to the
// original serial kernel => distances bit-identical => same argmins.
__global__ __launch_bounds__(256)
void vq_assign(const float* __restrict__ z, const float* __restrict__ cb,
               const float* __restrict__ cnorm, int* __restrict__ idx,
               float* __restrict__ hist, int N)
{
    const int n = blockIdx.x * 256 + threadIdx.x;
    const float4* zp = reinterpret_cast<const float4*>(z + (size_t)n * 64);
    float4 zv[16];
    float z2 = 0.0f;
#pragma unroll
    for (int i = 0; i < 16; ++i) {
        zv[i] = zp[i];
        z2 += zv[i].x * zv[i].x + zv[i].y * zv[i].y + zv[i].z * zv[i].z + zv[i].w * zv[i].w;
    }
    float best = 3.4e38f;
    int bi = 0;
#pragma unroll 1
    for (int k = 0; k < 512; k += 4) {
        float dot0 = 0.f, dot1 = 0.f, dot2 = 0.f, dot3 = 0.f;
        const float4* c0 = reinterpret_cast<const float4*>(cb + (size_t)(k + 0) * 64);
        const float4* c1 = reinterpret_cast<const float4*>(cb + (size_t)(k + 1) * 64);
        const float4* c2 = reinterpret_cast<const float4*>(cb + (size_t)(k + 2) * 64);
        const float4* c3 = reinterpret_cast<const float4*>(cb + (size_t)(k + 3) * 64);
#pragma unroll
        for (int i = 0; i < 16; ++i) {
            const float4 zi = zv[i];
            const float4 a0 = c0[i];
            const float4 a1 = c1[i];
            const float4 a2 = c2[i];
            const float4 a3 = c3[i];
            dot0 += zi.x * a0.x + zi.y * a0.y + zi.z * a0.z + zi.w * a0.w;
            dot1 += zi.x * a1.x + zi.y * a1.y + zi.z * a1.z + zi.w * a1.w;
            dot2 += zi.x * a2.x + zi.y * a2.y + zi.z * a2.z + zi.w * a2.w;
            dot3 += zi.x * a3.x + zi.y * a3.y + zi.z * a3.z + zi.w * a3.w;
        }
        const float d0 = z2 + cnorm[k + 0] - 2.0f * dot0;
        const float d1 = z2 + cnorm[k + 1] - 2.0f * dot1;
        const float d2 = z2 + cnorm[k + 2] - 2.0f * dot2;
        const float d3 = z2 + cnorm[k + 3] - 2.0f * dot3;
        if (d0 < best) { best = d0; bi = k + 0; }
        if (d1 < best) { best = d1; bi = k + 1; }
        if (d2 < best) { best = d2; bi = k + 2; }
        if (d3 < best) { best = d3; bi = k + 3; }
    }
    idx[n] = bi;
    atomicAdd(&hist[bi], 1.0f);
}

__global__ __launch_bounds__(256)
void vq_gather_split(const float* __restrict__ cb, const int* __restrict__ idx,
                     bf16_t* __restrict__ zh, bf16_t* __restrict__ zl)
{
    const int gid = blockIdx.x * 256 + threadIdx.x;
    const int n = gid >> 4, c4 = gid & 15;
    const int k = idx[n];
    const float4 c = reinterpret_cast<const float4*>(cb)[k * 16 + c4];
    ushort4 h, l;
    h.x = f2b(c.x); l.x = f2b(c.x - b2f(h.x));
    h.y = f2b(c.y); l.y = f2b(c.y - b2f(h.y));
    h.z = f2b(c.z); l.z = f2b(c.z - b2f(h.z));
    h.w = f2b(c.w); l.w = f2b(c.w - b2f(h.w));
    reinterpret_cast<ushort4*>(zh)[gid] = h;
    reinterpret_cast<ushort4*>(zl)[gid] = l;
}

__global__ __launch_bounds__(512)
void perplexity_k(const float* __restrict__ hist, float* __restrict__ out, float invN)
{
    __shared__ float red[512];
    const int t = threadIdx.x;
    const float p = hist[t] * invN;
    red[t] = p * logf(p + 1e-12f);
    __syncthreads();
    for (int s = 256; s > 0; s >>= 1) {
        if (t < s) red[t] += red[t + s];
        __syncthreads();
    }
    if (t == 0) out[0] = expf(-red[0]);
}

// ---------------------------------------------------------------------------
extern "C" void kernel_launch(void* const* d_in, const int* in_sizes, int n_in,
                              void* d_out, int out_size, void* d_ws, size_t ws_size,
                              hipStream_t stream)
{
    const float* x       = (const float*)d_in[0];
    const float* ec0_w   = (const float*)d_in[1];
    const float* ec0_b   = (const float*)d_in[2];
    const float* er0_c1w = (const float*)d_in[3];
    const float* er0_c1b = (const float*)d_in[4];
    const float* er0_c2w = (const float*)d_in[5];
    const float* er0_c2b = (const float*)d_in[6];
    const float* er0_g   = (const float*)d_in[7];
    const float* er0_be  = (const float*)d_in[8];
    const float* er0_m   = (const float*)d_in[9];
    const float* er0_v   = (const float*)d_in[10];
    const float* er0_a   = (const float*)d_in[11];
    const float* ec1_w   = (const float*)d_in[12];
    const float* ec1_b   = (const float*)d_in[13];
    const float* er1_c1w = (const float*)d_in[14];
    const float* er1_c1b = (const float*)d_in[15];
    const float* er1_c2w = (const float*)d_in[16];
    const float* er1_c2b = (const float*)d_in[17];
    const float* er1_g   = (const float*)d_in[18];
    const float* er1_be  = (const float*)d_in[19];
    const float* er1_m   = (const float*)d_in[20];
    const float* er1_v   = (const float*)d_in[21];
    const float* er1_a   = (const float*)d_in[22];
    const float* eo_w    = (const float*)d_in[23];
    const float* eo_b    = (const float*)d_in[24];
    const float* eo_a    = (const float*)d_in[25];
    const float* cb      = (const float*)d_in[26];
    const float* dc0_w   = (const float*)d_in[27];
    const float* dc0_b   = (const float*)d_in[28];
    const float* dc0_a   = (const float*)d_in[29];
    const float* dr0_c1w = (const float*)d_in[30];
    const float* dr0_c1b = (const float*)d_in[31];
    const float* dr0_c2w = (const float*)d_in[32];
    const float* dr0_c2b = (const float*)d_in[33];
    const float* dr0_g   = (const float*)d_in[34];
    const float* dr0_be  = (const float*)d_in[35];
    const float* dr0_m   = (const float*)d_in[36];
    const float* dr0_v   = (const float*)d_in[37];
    const float* dr0_a   = (const float*)d_in[38];
    const float* du0_w   = (const float*)d_in[39];
    const float* du0_b   = (const float*)d_in[40];
    const float* dr1_c1w = (const float*)d_in[41];
    const float* dr1_c1b = (const float*)d_in[42];
    const float* dr1_c2w = (const float*)d_in[43];
    const float* dr1_c2b = (const float*)d_in[44];
    const float* dr1_g   = (const float*)d_in[45];
    const float* dr1_be  = (const float*)d_in[46];
    const float* dr1_m   = (const float*)d_in[47];
    const float* dr1_v   = (const float*)d_in[48];
    const float* dr1_a   = (const float*)d_in[49];
    const float* du1_w   = (const float*)d_in[50];
    const float* du1_b   = (const float*)d_in[51];

    float* out = (float*)d_out;

    // ---- ws: A=[0,134MB) , H=[134MB,268MB) ----
    char* W = (char*)d_ws;
    float*  Af  = (float*)(W);
    float*  Hf  = (float*)(W + 134217728);
    float*  E1f = (float*)(W + 134217728);
    float*  R1f = (float*)(W + 134217728 + 33554432);
    float*  Zf  = (float*)(W);
    int*    IDX = (int*)  (W + 16777216);
    float*  CN  = (float*)(W + 17039360);
    float*  HS  = (float*)(W + 17041408);
    bf16_t* ZQh = (bf16_t*)(W + 33554432);
    bf16_t* ZQl = (bf16_t*)(W + 41943040);
    bf16_t* D0h = (bf16_t*)(W + 50331648);
    bf16_t* D0l = (bf16_t*)(W + 67108864);
    bf16_t* Gh  = (bf16_t*)(W + 83886080);
    bf16_t* Gl  = (bf16_t*)(W + 100663296);
    bf16_t* U0h = (bf16_t*)(W + 134217728);
    bf16_t* U0l = (bf16_t*)(W + 201326592);
    bf16_t* G1h = (bf16_t*)(W);
    bf16_t* G1l = (bf16_t*)(W + 67108864);

    // ---- weight arenas in d_out ----
    char* WB = (char*)d_out;
    bf16_t* e0c1h = (bf16_t*)(WB + 0);
    bf16_t* e0c1m = (bf16_t*)(WB + 221184);
    bf16_t* e0c1l = (bf16_t*)(WB + 442368);
    bf16_t* e0c2h = (bf16_t*)(WB + 663552);
    bf16_t* e0c2m = (bf16_t*)(WB + 884736);
    bf16_t* e0c2l = (bf16_t*)(WB + 1105920);
    bf16_t* ec1h  = (bf16_t*)(WB + 1327104);
    bf16_t* ec1m  = (bf16_t*)(WB + 2375680);
    bf16_t* ec1l  = (bf16_t*)(WB + 3424256);
    bf16_t* e1c1h = (bf16_t*)(WB + 4472832);
    bf16_t* e1c1m = (bf16_t*)(WB + 5357568);
    bf16_t* e1c1l = (bf16_t*)(WB + 6242304);
    bf16_t* e1c2h = (bf16_t*)(WB + 7127040);
    bf16_t* e1c2m = (bf16_t*)(WB + 8011776);
    bf16_t* e1c2l = (bf16_t*)(WB + 8896512);
    bf16_t* eoh   = (bf16_t*)(WB + 9781248);
    bf16_t* eom   = (bf16_t*)(WB + 10223616);
    bf16_t* eol   = (bf16_t*)(WB + 10665984);
    bf16_t* wec0h = (bf16_t*)(WB + 11108352);
    bf16_t* wec0m = (bf16_t*)(WB + 11116544);
    bf16_t* wec0l = (bf16_t*)(WB + 11124736);
    bf16_t* dc0h  = (bf16_t*)(WB + 0);
    bf16_t* dc0l  = (bf16_t*)(WB + 442368);
    bf16_t* d0c1h = (bf16_t*)(WB + 884736);
    bf16_t* d0c1l = (bf16_t*)(WB + 1769472);
    bf16_t* d0c2h = (bf16_t*)(WB + 2654208);
    bf16_t* d0c2l = (bf16_t*)(WB + 3538944);
    bf16_t* du0h  = (bf16_t*)(WB + 4423680);
    bf16_t* du0l  = (bf16_t*)(WB + 5472256);
    bf16_t* d1c1h = (bf16_t*)(WB + 6520832);
    bf16_t* d1c1l = (bf16_t*)(WB + 6742016);
    bf16_t* d1c2h = (bf16_t*)(WB + 6963200);
    bf16_t* d1c2l = (bf16_t*)(WB + 7184384);

    const float* fn = nullptr;
    const bf16_t* bn_ = nullptr;

    // ---- encoder weight prep (split-3, fragment-major) ----
    wprep3<<<16, 256, 0, stream>>>(ec0_w, wec0h, wec0m, wec0l, 64, 64, 4096);
    wprep3<<<432, 256, 0, stream>>>(er0_c1w, e0c1h, e0c1m, e0c1l, 64, 64, 110592);
    wprep3<<<432, 256, 0, stream>>>(er0_c2w, e0c2h, e0c2m, e0c2l, 64, 64, 110592);
    wprep3<<<2048, 256, 0, stream>>>(ec1_w, ec1h, ec1m, ec1l, 64, 128, 524288);
    wprep3<<<1728, 256, 0, stream>>>(er1_c1w, e1c1h, e1c1m, e1c1l, 128, 128, 442368);
    wprep3<<<1728, 256, 0, stream>>>(er1_c2w, e1c2h, e1c2m, e1c2l, 128, 128, 442368);
    wprep3<<<864, 256, 0, stream>>>(eo_w, eoh, eom, eol, 128, 64, 221184);

    // ---- encoder (fp32-class) ----
    conv_ec0m<<<8192, 128, 0, stream>>>(x, wec0h, wec0m, wec0l, ec0_b, Af);

    conv3e<64, 64, 64, 1, 1><<<8192, 128, 0, stream>>>(
        Af, e0c1h, e0c1m, e0c1l, er0_c1b, fn, fn, fn, fn, fn, fn, Hf);
    conv3e<64, 64, 64, 1, 3><<<8192, 128, 0, stream>>>(
        Hf, e0c2h, e0c2m, e0c2l, er0_c2b, er0_g, er0_be, er0_m, er0_v, er0_a, Af, Af);

    convs2e<<<2048, 128, 0, stream>>>(Af, ec1h, ec1m, ec1l, ec1_b, E1f);

    conv3e<128, 128, 32, 2, 1><<<2048, 128, 0, stream>>>(
        E1f, e1c1h, e1c1m, e1c1l, er1_c1b, fn, fn, fn, fn, fn, fn, R1f);
    conv3e<128, 128, 32, 2, 3><<<2048, 128, 0, stream>>>(
        R1f, e1c2h, e1c2m, e1c2l, er1_c2b, er1_g, er1_be, er1_m, er1_v, er1_a, E1f, E1f);

    conv3e<128, 64, 32, 1, 2><<<2048, 64, 0, stream>>>(
        E1f, eoh, eom, eol, eo_b, fn, fn, fn, fn, eo_a, fn, Zf);

    // ---- VQ (exact fp32, ILP assign) ----
    vq_cnorm<<<8, 64, 0, stream>>>(cb, CN);
    zero512<<<1, 512, 0, stream>>>(HS);
    vq_assign<<<256, 256, 0, stream>>>(Zf, cb, CN, IDX, HS, 65536);
    perplexity_k<<<1, 512, 0, stream>>>(HS, out + 4194304, 1.0f / 65536.0f);
    vq_gather_split<<<4096, 256, 0, stream>>>(cb, IDX, ZQh, ZQl);

    // ---- decoder weight prep (split-2, fragment-major, overwrites arena) ----
    wprep_split<<<864, 256, 0, stream>>>(dc0_w, dc0h, dc0l, 64, 128, 221184);
    wprep_split<<<1728, 256, 0, stream>>>(dr0_c1w, d0c1h, d0c1l, 128, 128, 442368);
    wprep_split<<<1728, 256, 0, stream>>>(dr0_c2w, d0c2h, d0c2l, 128, 128, 442368);
    wprep_split<<<2048, 256, 0, stream>>>(du0_w, du0h, du0l, 128, 64, 524288);
    wprep_split<<<432, 256, 0, stream>>>(dr1_c1w, d1c1h, d1c1l, 64, 64, 110592);
    wprep_split<<<432, 256, 0, stream>>>(dr1_c2w, d1c2h, d1c2l, 64, 64, 110592);

    // ---- decoder (split-2 bf16) ----
    conv3d<64, 128, 32, 2, 2><<<2048, 128, 0, stream>>>(
        ZQh, ZQl, dc0h, dc0l, dc0_b, fn, fn, fn, fn, dc0_a, bn_, bn_, D0h, D0l);
    conv3d<128, 128, 32, 2, 1><<<2048, 128, 0, stream>>>(
        D0h, D0l, d0c1h, d0c1l, dr0_c1b, fn, fn, fn, fn, fn, bn_, bn_, Gh, Gl);
    conv3d<128, 128, 32, 2, 3><<<2048, 128, 0, stream>>>(
        Gh, Gl, d0c2h, d0c2l, dr0_c2b, dr0_g, dr0_be, dr0_m, dr0_v, dr0_a,
        D0h, D0l, D0h, D0l);

    convTm<<<8192, 256, 0, stream>>>(D0h, D0l, du0h, du0l, du0_b, U0h, U0l);

    conv3d<64, 64, 64, 1, 1><<<8192, 128, 0, stream>>>(
        U0h, U0l, d1c1h, d1c1l, dr1_c1b, fn, fn, fn, fn, fn, bn_, bn_, G1h, G1l);
    conv3d<64, 64, 64, 1, 3><<<8192, 128, 0, stream>>>(
        G1h, G1l, d1c2h, d1c2l, dr1_c2b, dr1_g, dr1_be, dr1_m, dr1_v, dr1_a,
        U0h, U0l, U0h, U0l);

    convT_du1w<<<65536, 256, 0, stream>>>(U0h, U0l, du1_w, du1_b, out);
}

// Round 16
// 5202.943 us; speedup vs baseline: 1.1734x; 1.0322x over previous
//
#include <hip/hip_runtime.h>
#include <cstdint>

// ---------------------------------------------------------------------------
// VQVAE forward — MFMA implicit-GEMM convolutions, channels-last.
//
// Round-16 = round-15 + 4-wave blocks (32 couts/wave, n2 loop removed).
//   Per-block tile & grids unchanged; per-thread staging and accumulator
//   registers halve => waves/CU ~2x (occupancy 21.5% -> ~40-60%) to hide
//   barrier drains and weight-load latency across blocks. Numerics are
//   bit-identical (same MFMA ops, same order per output).
//   - Encoder: fp32 activations; EXACT 3-way bf16 split at LDS-stage time;
//     6-MFMA products => fp32-class => VQ argmin safe.
//   - Decoder: split-2 bf16 storage, 3-pass MFMA.
//   - vq_assign: uniform-k, 4 independent dot chains (round-15, proven).
// Retained: fragment-major weights w[tap][ks][half][cout][8k], T14 async-
// STAGE single-LDS-buffer, T1 XCD-chunked swizzle, LDS XOR swizzle,
// MFMA ec0, wave-level du1.
//
// C layout: col = lane&31, row = (reg&3) + 8*(reg>>2) + 4*(lane>>5)
// ---------------------------------------------------------------------------

typedef unsigned short bf16_t;
typedef __attribute__((ext_vector_type(8)))  short s8b;     // 8 x bf16 frag
typedef __attribute__((ext_vector_type(16))) float f32x16;  // 32x32 acc

__device__ __forceinline__ float b2f(bf16_t u) { return __uint_as_float((unsigned)u << 16); }
__device__ __forceinline__ bf16_t f2b(float f) {
    unsigned x = __float_as_uint(f);
    return (bf16_t)((x + 0x7FFFu + ((x >> 16) & 1u)) >> 16);
}

__device__ __forceinline__ void split3s(float v, unsigned short& h,
                                        unsigned short& m, unsigned short& l)
{
    const unsigned uv = __float_as_uint(v);
    const float fh = __uint_as_float(uv & 0xFFFF0000u);
    const float r1 = v - fh;
    const unsigned u1 = __float_as_uint(r1);
    const float fm = __uint_as_float(u1 & 0xFFFF0000u);
    const float r2 = r1 - fm;
    h = (unsigned short)(uv >> 16);
    m = (unsigned short)(u1 >> 16);
    l = (unsigned short)(__float_as_uint(r2) >> 16);
}

// ------------------------- weight prep ------------------------------------
// src [tap][ci][co] fp32 -> dst fragment-major [tap][ks][half][co][8k]
__device__ __forceinline__ int wdst(int tap, int ci_, int co_, int ci, int co)
{
    const int ks = ci_ >> 4, half = (ci_ >> 3) & 1, j = ci_ & 7;
    return (((tap * (ci >> 4) + ks) * 2 + half) * co + co_) * 8 + j;
}

__global__ __launch_bounds__(256)
void wprep3(const float* __restrict__ w, bf16_t* __restrict__ h,
            bf16_t* __restrict__ m, bf16_t* __restrict__ l,
            int ci, int co, int n)
{
    const int i = blockIdx.x * 256 + threadIdx.x;
    if (i >= n) return;
    const int co_ = i % co;
    const int ci_ = (i / co) % ci;
    const int tap = i / (co * ci);
    const int dst = wdst(tap, ci_, co_, ci, co);
    unsigned short hh, mm, ll2;
    split3s(w[i], hh, mm, ll2);
    h[dst] = hh; m[dst] = mm; l[dst] = ll2;
}

__global__ __launch_bounds__(256)
void wprep_split(const float* __restrict__ w, bf16_t* __restrict__ hi,
                 bf16_t* __restrict__ lo, int ci, int co, int n)
{
    const int i = blockIdx.x * 256 + threadIdx.x;
    if (i >= n) return;
    const int co_ = i % co;
    const int ci_ = (i / co) % ci;
    const int tap = i / (co * ci);
    const float v = w[i];
    const int dst = wdst(tap, ci_, co_, ci, co);
    const bf16_t h = f2b(v);
    hi[dst] = h;
    lo[dst] = f2b(v - b2f(h));
}

// ---------------- encoder 3x3x3 conv: fp32 in, T14-staged split-3 -----------
// NWC = COUT/32 waves in N (32 couts/wave). (SD/32) waves in M.
// EPI: 0=ReLU 1=swish 2=PReLU 3=BN+PReLU+skip+ReLU
template<int CIN, int COUT, int SD, int NWC, int EPI>
__global__ __launch_bounds__((SD / 32) * NWC * 64)
void conv3e(const float* __restrict__ xf,
            const bf16_t* __restrict__ wh, const bf16_t* __restrict__ wm,
            const bf16_t* __restrict__ wl,
            const float* __restrict__ bias,
            const float* __restrict__ g, const float* __restrict__ be,
            const float* __restrict__ mn, const float* __restrict__ vr,
            const float* __restrict__ al,
            const float* skf, float* __restrict__ of)
{
    constexpr int NT = (SD / 32) * NWC * 64;
    constexpr int LP = (SD * CIN) / (4 * NT);
    constexpr int KS = CIN / 16;
    __shared__ bf16_t lh[SD * CIN], lm[SD * CIN], ll[SD * CIN];

    const int tid  = threadIdx.x;
    const int lane = tid & 63;
    const int wid  = tid >> 6;
    const int wn   = wid % NWC, wm2 = wid / NWC;
    const int half = lane >> 5, ln = lane & 31;
    const int w    = wm2 * 32 + ln;
    const int nwg  = gridDim.x;
    const int bid  = (blockIdx.x & 7) * (nwg >> 3) + (blockIdx.x >> 3);
    const int h    = bid % SD;
    const int d    = (bid / SD) % SD;
    const int b    = bid / (SD * SD);
    const int cout = wn * 32 + ln;

    int pz[9], py[9], pt[9], np = 0;
    for (int kd = 0; kd < 3; ++kd) {
        const int iz = d + kd - 1;
        if ((unsigned)iz >= (unsigned)SD) continue;
        for (int kh = 0; kh < 3; ++kh) {
            const int iy = h + kh - 1;
            if ((unsigned)iy >= (unsigned)SD) continue;
            pz[np] = iz; py[np] = iy; pt[np] = (kd * 3 + kh) * 3; ++np;
        }
    }

    f32x16 accA, accB;
#pragma unroll
    for (int i = 0; i < 16; ++i) { accA[i] = 0.f; accB[i] = 0.f; }

    float4 rg[LP];
    auto loadrow = [&](int iz, int iy) {
        const float* src = xf + ((size_t)((b * SD + iz) * SD + iy)) * SD * CIN;
#pragma unroll
        for (int j = 0; j < LP; ++j)
            rg[j] = *reinterpret_cast<const float4*>(src + (size_t)(tid + j * NT) * 4);
    };
    auto writerow = [&]() {
#pragma unroll
        for (int j = 0; j < LP; ++j) {
            const int idx = (tid + j * NT) * 4;
            const int vox = idx / CIN, ch = idx % CIN;
            ushort4 h4, m4, l4;
            split3s(rg[j].x, h4.x, m4.x, l4.x);
            split3s(rg[j].y, h4.y, m4.y, l4.y);
            split3s(rg[j].z, h4.z, m4.z, l4.z);
            split3s(rg[j].w, h4.w, m4.w, l4.w);
            const int bo = ((vox * CIN + ch) * 2) ^ ((vox & 7) << 4);
            *reinterpret_cast<ushort4*>((char*)&lh[0] + bo) = h4;
            *reinterpret_cast<ushort4*>((char*)&lm[0] + bo) = m4;
            *reinterpret_cast<ushort4*>((char*)&ll[0] + bo) = l4;
        }
    };

    loadrow(pz[0], py[0]);
    writerow();
    __syncthreads();
#pragma unroll 1
    for (int i = 0; i < np; ++i) {
        if (i + 1 < np) loadrow(pz[i + 1], py[i + 1]);   // issue early (T14)
#pragma unroll
        for (int kw = 0; kw < 3; ++kw) {
            const int tap = pt[i] + kw;
            const int iw = w + kw - 1;
            const bool edge = (unsigned)iw >= (unsigned)SD;
            const int wcl = edge ? w : iw;
            const s8b zz = {};
#pragma unroll
            for (int ks = 0; ks < KS; ++ks) {
                const int bo = ((wcl * CIN + half * 8 + ks * 16) * 2) ^ ((wcl & 7) << 4);
                s8b ah  = *reinterpret_cast<const s8b*>((const char*)&lh[0] + bo);
                s8b am  = *reinterpret_cast<const s8b*>((const char*)&lm[0] + bo);
                s8b al3 = *reinterpret_cast<const s8b*>((const char*)&ll[0] + bo);
                if (edge) { ah = zz; am = zz; al3 = zz; }
                const size_t wb = ((size_t)((tap * KS + ks) * 2 + half) * COUT + cout) * 8;
                const s8b bh = *reinterpret_cast<const s8b*>(wh + wb);
                const s8b bm = *reinterpret_cast<const s8b*>(wm + wb);
                const s8b bl = *reinterpret_cast<const s8b*>(wl + wb);
                accA = __builtin_amdgcn_mfma_f32_32x32x16_bf16(ah, bh, accA, 0, 0, 0);
                accB = __builtin_amdgcn_mfma_f32_32x32x16_bf16(ah, bm, accB, 0, 0, 0);
                accA = __builtin_amdgcn_mfma_f32_32x32x16_bf16(am, bh, accA, 0, 0, 0);
                accB = __builtin_amdgcn_mfma_f32_32x32x16_bf16(am, bm, accB, 0, 0, 0);
                accA = __builtin_amdgcn_mfma_f32_32x32x16_bf16(al3, bh, accA, 0, 0, 0);
                accB = __builtin_amdgcn_mfma_f32_32x32x16_bf16(ah, bl, accB, 0, 0, 0);
            }
        }
        if (i + 1 < np) {
            __syncthreads();          // all waves done reading LDS
            writerow();               // implicit vmcnt wait on rg here
            __syncthreads();          // LDS ready
        }
    }

    const size_t outrow = ((size_t)((b * SD + d) * SD + h)) * SD;
    const float bv = bias[cout];
    float sc = 0.f, mm = 0.f, bb2 = 0.f, aa = 0.f;
    if constexpr (EPI == 3) {
        sc = g[cout] * (1.0f / sqrtf(vr[cout] + 1e-3f));
        mm = mn[cout]; bb2 = be[cout]; aa = al[cout];
    }
    if constexpr (EPI == 2) aa = al[cout];
#pragma unroll
    for (int r = 0; r < 16; ++r) {
        const int rl = (r & 3) + 8 * (r >> 2) + 4 * half;
        const size_t oe = (outrow + wm2 * 32 + rl) * COUT + cout;
        float y = accA[r] + accB[r] + bv;
        if constexpr (EPI == 0) y = fmaxf(y, 0.f);
        else if constexpr (EPI == 1) y = y / (1.f + expf(-y));
        else if constexpr (EPI == 2) y = y > 0.f ? y : aa * y;
        else {
            float t2 = (y - mm) * sc + bb2;
            t2 = t2 > 0.f ? t2 : aa * t2;
            y = fmaxf(skf[oe] + t2, 0.f);
        }
        of[oe] = y;
    }
}

// ---------------- ec1: stride-2 k=4, fp32 in, T14-staged split-3 ------------
// 4 waves x 32 couts (COUT=128), 32 voxels per wave row.
__global__ __launch_bounds__(256)
void convs2e(const float* __restrict__ xf,
             const bf16_t* __restrict__ wh, const bf16_t* __restrict__ wm,
             const bf16_t* __restrict__ wl,
             const float* __restrict__ bias, float* __restrict__ of)
{
    constexpr int NT = 256, LP = (64 * 64) / (4 * NT);
    __shared__ bf16_t lh[64 * 64], lm[64 * 64], ll[64 * 64];

    const int tid  = threadIdx.x;
    const int lane = tid & 63;
    const int wn   = tid >> 6;          // 4 waves x 32 couts
    const int half = lane >> 5, ln = lane & 31;
    const int nwg  = gridDim.x;
    const int bid  = (blockIdx.x & 7) * (nwg >> 3) + (blockIdx.x >> 3);
    const int h    = bid % 32;
    const int d    = (bid / 32) % 32;
    const int b    = bid / 1024;
    const int cout = wn * 32 + ln;

    int pz[16], py[16], pt[16], np = 0;
    for (int kd = 0; kd < 4; ++kd) {
        const int iz = 2 * d + kd - 1;
        if ((unsigned)iz >= 64u) continue;
        for (int kh = 0; kh < 4; ++kh) {
            const int iy = 2 * h + kh - 1;
            if ((unsigned)iy >= 64u) continue;
            pz[np] = iz; py[np] = iy; pt[np] = (kd * 4 + kh) * 4; ++np;
        }
    }

    f32x16 accA, accB;
#pragma unroll
    for (int i = 0; i < 16; ++i) { accA[i] = 0.f; accB[i] = 0.f; }

    float4 rg[LP];
    auto loadrow = [&](int iz, int iy) {
        const float* src = xf + ((size_t)((b * 64 + iz) * 64 + iy)) * 64 * 64;
#pragma unroll
        for (int j = 0; j < LP; ++j)
            rg[j] = *reinterpret_cast<const float4*>(src + (size_t)(tid + j * NT) * 4);
    };
    auto writerow = [&]() {
#pragma unroll
        for (int j = 0; j < LP; ++j) {
            const int idx = (tid + j * NT) * 4;
            const int vox = idx / 64, ch = idx % 64;
            ushort4 h4, m4, l4;
            split3s(rg[j].x, h4.x, m4.x, l4.x);
            split3s(rg[j].y, h4.y, m4.y, l4.y);
            split3s(rg[j].z, h4.z, m4.z, l4.z);
            split3s(rg[j].w, h4.w, m4.w, l4.w);
            const int bo = ((vox * 64 + ch) * 2) ^ ((vox & 7) << 4);
            *reinterpret_cast<ushort4*>((char*)&lh[0] + bo) = h4;
            *reinterpret_cast<ushort4*>((char*)&lm[0] + bo) = m4;
            *reinterpret_cast<ushort4*>((char*)&ll[0] + bo) = l4;
        }
    };

    loadrow(pz[0], py[0]);
    writerow();
    __syncthreads();
#pragma unroll 1
    for (int i = 0; i < np; ++i) {
        if (i + 1 < np) loadrow(pz[i + 1], py[i + 1]);
#pragma unroll
        for (int kw = 0; kw < 4; ++kw) {
            const int tap = pt[i] + kw;
            const int iw = 2 * ln + kw - 1;
            const bool edge = (unsigned)iw >= 64u;
            const int wcl = edge ? 2 * ln : iw;
            const s8b zz = {};
#pragma unroll
            for (int ks = 0; ks < 4; ++ks) {
                const int bo = ((wcl * 64 + half * 8 + ks * 16) * 2) ^ ((wcl & 7) << 4);
                s8b ah  = *reinterpret_cast<const s8b*>((const char*)&lh[0] + bo);
                s8b am  = *reinterpret_cast<const s8b*>((const char*)&lm[0] + bo);
                s8b al3 = *reinterpret_cast<const s8b*>((const char*)&ll[0] + bo);
                if (edge) { ah = zz; am = zz; al3 = zz; }
                const size_t wb = ((size_t)((tap * 4 + ks) * 2 + half) * 128 + cout) * 8;
                const s8b bh = *reinterpret_cast<const s8b*>(wh + wb);
                const s8b bm = *reinterpret_cast<const s8b*>(wm + wb);
                const s8b bl = *reinterpret_cast<const s8b*>(wl + wb);
                accA = __builtin_amdgcn_mfma_f32_32x32x16_bf16(ah, bh, accA, 0, 0, 0);
                accB = __builtin_amdgcn_mfma_f32_32x32x16_bf16(ah, bm, accB, 0, 0, 0);
                accA = __builtin_amdgcn_mfma_f32_32x32x16_bf16(am, bh, accA, 0, 0, 0);
                accB = __builtin_amdgcn_mfma_f32_32x32x16_bf16(am, bm, accB, 0, 0, 0);
                accA = __builtin_amdgcn_mfma_f32_32x32x16_bf16(al3, bh, accA, 0, 0, 0);
                accB = __builtin_amdgcn_mfma_f32_32x32x16_bf16(ah, bl, accB, 0, 0, 0);
            }
        }
        if (i + 1 < np) {
            __syncthreads();
            writerow();
            __syncthreads();
        }
    }

    const size_t outrow = ((size_t)((b * 32 + d) * 32 + h)) * 32;
    const float bv = bias[cout];
#pragma unroll
    for (int r = 0; r < 16; ++r) {
        const int rl = (r & 3) + 8 * (r >> 2) + 4 * half;
        const size_t oe = (outrow + rl) * 128 + cout;
        of[oe] = fmaxf(accA[r] + accB[r] + bv, 0.f);
    }
}

// ---------------- decoder 3x3x3 conv: split-2 bf16, T14-staged --------------
template<int CIN, int COUT, int SD, int NWC, int EPI>
__global__ __launch_bounds__((SD / 32) * NWC * 64)
void conv3d(const bf16_t* __restrict__ xh, const bf16_t* __restrict__ xl,
            const bf16_t* __restrict__ wh, const bf16_t* __restrict__ wl,
            const float* __restrict__ bias,
            const float* __restrict__ g, const float* __restrict__ be,
            const float* __restrict__ mn, const float* __restrict__ vr,
            const float* __restrict__ al,
            const bf16_t* skh, const bf16_t* skl,
            bf16_t* oh, bf16_t* ol)
{
    constexpr int NT = (SD / 32) * NWC * 64;
    constexpr int LP = (SD * CIN) / (4 * NT);
    constexpr int KS = CIN / 16;
    __shared__ bf16_t lh[SD * CIN], ll[SD * CIN];

    const int tid  = threadIdx.x;
    const int lane = tid & 63;
    const int wid  = tid >> 6;
    const int wn   = wid % NWC, wm2 = wid / NWC;
    const int half = lane >> 5, ln = lane & 31;
    const int w    = wm2 * 32 + ln;
    const int nwg  = gridDim.x;
    const int bid  = (blockIdx.x & 7) * (nwg >> 3) + (blockIdx.x >> 3);
    const int h    = bid % SD;
    const int d    = (bid / SD) % SD;
    const int b    = bid / (SD * SD);
    const int cout = wn * 32 + ln;

    int pz[9], py[9], pt[9], np = 0;
    for (int kd = 0; kd < 3; ++kd) {
        const int iz = d + kd - 1;
        if ((unsigned)iz >= (unsigned)SD) continue;
        for (int kh = 0; kh < 3; ++kh) {
            const int iy = h + kh - 1;
            if ((unsigned)iy >= (unsigned)SD) continue;
            pz[np] = iz; py[np] = iy; pt[np] = (kd * 3 + kh) * 3; ++np;
        }
    }

    f32x16 accA, accB;
#pragma unroll
    for (int i = 0; i < 16; ++i) { accA[i] = 0.f; accB[i] = 0.f; }

    ushort4 rh[LP], rl2a[LP];
    auto loadrow = [&](int iz, int iy) {
        const size_t rb = ((size_t)((b * SD + iz) * SD + iy)) * SD * CIN;
#pragma unroll
        for (int j = 0; j < LP; ++j) {
            const int idx = (tid + j * NT) * 4;
            rh[j]   = *reinterpret_cast<const ushort4*>(xh + rb + idx);
            rl2a[j] = *reinterpret_cast<const ushort4*>(xl + rb + idx);
        }
    };
    auto writerow = [&]() {
#pragma unroll
        for (int j = 0; j < LP; ++j) {
            const int idx = (tid + j * NT) * 4;
            const int vox = idx / CIN, ch = idx % CIN;
            const int bo = ((vox * CIN + ch) * 2) ^ ((vox & 7) << 4);
            *reinterpret_cast<ushort4*>((char*)&lh[0] + bo) = rh[j];
            *reinterpret_cast<ushort4*>((char*)&ll[0] + bo) = rl2a[j];
        }
    };

    loadrow(pz[0], py[0]);
    writerow();
    __syncthreads();
#pragma unroll 1
    for (int i = 0; i < np; ++i) {
        if (i + 1 < np) loadrow(pz[i + 1], py[i + 1]);
#pragma unroll
        for (int kw = 0; kw < 3; ++kw) {
            const int tap = pt[i] + kw;
            const int iw = w + kw - 1;
            const bool edge = (unsigned)iw >= (unsigned)SD;
            const int wcl = edge ? w : iw;
            const s8b zz = {};
#pragma unroll
            for (int ks = 0; ks < KS; ++ks) {
                const int bo = ((wcl * CIN + half * 8 + ks * 16) * 2) ^ ((wcl & 7) << 4);
                s8b ah  = *reinterpret_cast<const s8b*>((const char*)&lh[0] + bo);
                s8b al2 = *reinterpret_cast<const s8b*>((const char*)&ll[0] + bo);
                if (edge) { ah = zz; al2 = zz; }
                const size_t wb = ((size_t)((tap * KS + ks) * 2 + half) * COUT + cout) * 8;
                const s8b bh = *reinterpret_cast<const s8b*>(wh + wb);
                const s8b bl = *reinterpret_cast<const s8b*>(wl + wb);
                accA = __builtin_amdgcn_mfma_f32_32x32x16_bf16(ah, bh, accA, 0, 0, 0);
                accB = __builtin_amdgcn_mfma_f32_32x32x16_bf16(al2, bh, accB, 0, 0, 0);
                accB = __builtin_amdgcn_mfma_f32_32x32x16_bf16(ah, bl, accB, 0, 0, 0);
            }
        }
        if (i + 1 < np) {
            __syncthreads();
            writerow();
            __syncthreads();
        }
    }

    const size_t outrow = ((size_t)((b * SD + d) * SD + h)) * SD;
    const float bv = bias[cout];
    float sc = 0.f, mm = 0.f, bb2 = 0.f, aa = 0.f;
    if constexpr (EPI == 3) {
        sc = g[cout] * (1.0f / sqrtf(vr[cout] + 1e-3f));
        mm = mn[cout]; bb2 = be[cout]; aa = al[cout];
    }
    if constexpr (EPI == 2) aa = al[cout];
#pragma unroll
    for (int r = 0; r < 16; ++r) {
        const int rl3 = (r & 3) + 8 * (r >> 2) + 4 * half;
        const size_t oe = (outrow + wm2 * 32 + rl3) * COUT + cout;
        float y = accA[r] + accB[r] + bv;
        if constexpr (EPI == 0) y = fmaxf(y, 0.f);
        else if constexpr (EPI == 1) y = y / (1.f + expf(-y));
        else if constexpr (EPI == 2) y = y > 0.f ? y : aa * y;
        else {
            float t2 = (y - mm) * sc + bb2;
            t2 = t2 > 0.f ? t2 : aa * t2;
            float sv = b2f(skh[oe]) + b2f(skl[oe]);
            y = fmaxf(sv + t2, 0.f);
        }
        const bf16_t hh = f2b(y);
        oh[oe] = hh;
        ol[oe] = f2b(y - b2f(hh));
    }
}

// ---------------- convT stride-2 k=4 (du0, split-2, T14-staged) -------------
__global__ __launch_bounds__(256)
void convTm(const bf16_t* __restrict__ xh, const bf16_t* __restrict__ xl,
            const bf16_t* __restrict__ wh, const bf16_t* __restrict__ wl,
            const float* __restrict__ bias,
            bf16_t* __restrict__ oh, bf16_t* __restrict__ ol)
{
    constexpr int NT = 256, LP = (32 * 128) / (4 * NT);
    __shared__ bf16_t lh[32 * 128], ll[32 * 128];

    const int tid  = threadIdx.x;
    const int lane = tid & 63;
    const int wid  = tid >> 6;
    const int wn   = wid & 1, p = wid >> 1;
    const int half = lane >> 5, ln = lane & 31;
    const int nwg  = gridDim.x;
    const int bid  = (blockIdx.x & 7) * (nwg >> 3) + (blockIdx.x >> 3);
    const int ohh  = bid % 64;
    const int od   = (bid / 64) % 64;
    const int b    = bid / 4096;
    const int pd = od & 1, dz = od >> 1;
    const int ph = ohh & 1, hy = ohh >> 1;
    const int cout = wn * 32 + ln;

    int pz[4], py[4], pt[4], np = 0;
    for (int jd = 0; jd < 2; ++jd) {
        const int kd = pd + 2 * jd;
        const int iz = dz + pd - 1 + jd;
        if ((unsigned)iz >= 32u) continue;
        for (int jh = 0; jh < 2; ++jh) {
            const int kh = ph + 2 * jh;
            const int iy = hy + ph - 1 + jh;
            if ((unsigned)iy >= 32u) continue;
            pz[np] = iz; py[np] = iy; pt[np] = (kd * 4 + kh) * 4; ++np;
        }
    }

    f32x16 accA, accB;
#pragma unroll
    for (int i = 0; i < 16; ++i) { accA[i] = 0.0f; accB[i] = 0.0f; }

    ushort4 rh[LP], rl2a[LP];
    auto loadrow = [&](int iz, int iy) {
        const size_t rb = ((size_t)((b * 32 + iz) * 32 + iy)) * 32 * 128;
#pragma unroll
        for (int j = 0; j < LP; ++j) {
            const int idx = (tid + j * NT) * 4;
            rh[j]   = *reinterpret_cast<const ushort4*>(xh + rb + idx);
            rl2a[j] = *reinterpret_cast<const ushort4*>(xl + rb + idx);
        }
    };
    auto writerow = [&]() {
#pragma unroll
        for (int j = 0; j < LP; ++j) {
            const int idx = (tid + j * NT) * 4;
            const int vox = idx / 128, ch = idx % 128;
            const int bo = ((vox * 128 + ch) * 2) ^ ((vox & 7) << 4);
            *reinterpret_cast<ushort4*>((char*)&lh[0] + bo) = rh[j];
            *reinterpret_cast<ushort4*>((char*)&ll[0] + bo) = rl2a[j];
        }
    };

    loadrow(pz[0], py[0]);
    writerow();
    __syncthreads();
#pragma unroll 1
    for (int i = 0; i < np; ++i) {
        if (i + 1 < np) loadrow(pz[i + 1], py[i + 1]);
#pragma unroll
        for (int jw = 0; jw < 2; ++jw) {
            const int kw = p + 2 * jw;
            const int tap = pt[i] + kw;
            const int ix = ln + p - 1 + jw;
            const bool edge = (unsigned)ix >= 32u;
            const int xcl = edge ? ln : ix;
            const s8b zz = {};
#pragma unroll
            for (int ks = 0; ks < 8; ++ks) {
                const int bo = ((xcl * 128 + half * 8 + ks * 16) * 2) ^ ((xcl & 7) << 4);
                s8b a  = *reinterpret_cast<const s8b*>((const char*)&lh[0] + bo);
                s8b a2 = *reinterpret_cast<const s8b*>((const char*)&ll[0] + bo);
                if (edge) { a = zz; a2 = zz; }
                const size_t wb = ((size_t)((tap * 8 + ks) * 2 + half) * 64 + cout) * 8;
                const s8b bb = *reinterpret_cast<const s8b*>(wh + wb);
                const s8b b2 = *reinterpret_cast<const s8b*>(wl + wb);
                accA = __builtin_amdgcn_mfma_f32_32x32x16_bf16(a, bb, accA, 0, 0, 0);
                accB = __builtin_amdgcn_mfma_f32_32x32x16_bf16(a2, bb, accB, 0, 0, 0);
                accB = __builtin_amdgcn_mfma_f32_32x32x16_bf16(a, b2, accB, 0, 0, 0);
            }
        }
        if (i + 1 < np) {
            __syncthreads();
            writerow();
            __syncthreads();
        }
    }

    const float bv = bias[cout];
#pragma unroll
    for (int r = 0; r < 16; ++r) {
        const int rl3 = (r & 3) + 8 * (r >> 2) + 4 * half;
        const int ow = 2 * rl3 + p;
        const size_t oe = (((size_t)((b * 64 + od) * 64 + ohh)) * 64 + ow) * 64 + cout;
        const float y = fmaxf(accA[r] + accB[r] + bv, 0.f);
        const bf16_t hh = f2b(y);
        oh[oe] = hh;
        ol[oe] = f2b(y - b2f(hh));
    }
}

// ---------------- ec0 via MFMA: s2 k=4, CIN=1, K=64 taps --------------------
__global__ __launch_bounds__(128)
void conv_ec0m(const float* __restrict__ x,
               const bf16_t* __restrict__ wh, const bf16_t* __restrict__ wm,
               const bf16_t* __restrict__ wl,
               const float* __restrict__ bias, float* __restrict__ of)
{
    __shared__ bf16_t lh[16 * 132], lm[16 * 132], ll[16 * 132];

    const int tid  = threadIdx.x;
    const int lane = tid & 63;
    const int wm2  = tid >> 6;
    const int half = lane >> 5, ln = lane & 31;
    const int w    = wm2 * 32 + ln;
    const int nwg  = gridDim.x;
    const int bid  = (blockIdx.x & 7) * (nwg >> 3) + (blockIdx.x >> 3);
    const int h    = bid % 64;
    const int d    = (bid / 64) % 64;
    const int b    = bid / 4096;

    for (int i = tid; i < 16 * 132; i += 128) {
        const int row = i / 132, col = i % 132;
        const int kd = row >> 2, kh = row & 3;
        const int iz = 2 * d + kd - 1, iy = 2 * h + kh - 1;
        const int ix = col - 1;
        float v = 0.f;
        if ((unsigned)iz < 128u && (unsigned)iy < 128u &&
            (unsigned)ix < 128u && col < 130)
            v = x[(size_t)((b * 128 + iz) * 128 + iy) * 128 + ix];
        unsigned short hh, mm2, ll2;
        split3s(v, hh, mm2, ll2);
        lh[i] = hh; lm[i] = mm2; ll[i] = ll2;
    }
    __syncthreads();

    f32x16 accA[2], accB[2];
#pragma unroll
    for (int i = 0; i < 16; ++i) {
        accA[0][i] = 0.f; accA[1][i] = 0.f;
        accB[0][i] = 0.f; accB[1][i] = 0.f;
    }

#pragma unroll
    for (int ks = 0; ks < 4; ++ks) {
        const int row0 = ks * 4 + 2 * half;
        const int i0 = row0 * 132 + 2 * w;
        const int i1 = i0 + 132;
        s8b ah, am, al3;
        {
            uint* ap = (uint*)&ah;
            ap[0] = *(const uint*)&lh[i0]; ap[1] = *(const uint*)&lh[i0 + 2];
            ap[2] = *(const uint*)&lh[i1]; ap[3] = *(const uint*)&lh[i1 + 2];
        }
        {
            uint* ap = (uint*)&am;
            ap[0] = *(const uint*)&lm[i0]; ap[1] = *(const uint*)&lm[i0 + 2];
            ap[2] = *(const uint*)&lm[i1]; ap[3] = *(const uint*)&lm[i1 + 2];
        }
        {
            uint* ap = (uint*)&al3;
            ap[0] = *(const uint*)&ll[i0]; ap[1] = *(const uint*)&ll[i0 + 2];
            ap[2] = *(const uint*)&ll[i1]; ap[3] = *(const uint*)&ll[i1 + 2];
        }
        const size_t wb0 = ((size_t)(ks * 2 + half) * 64 + ln) * 8;
#pragma unroll
        for (int n2 = 0; n2 < 2; ++n2) {
            const size_t wb = wb0 + n2 * 256;
            const s8b bh = *reinterpret_cast<const s8b*>(wh + wb);
            const s8b bm = *reinterpret_cast<const s8b*>(wm + wb);
            const s8b bl = *reinterpret_cast<const s8b*>(wl + wb);
            accA[n2] = __builtin_amdgcn_mfma_f32_32x32x16_bf16(ah, bh, accA[n2], 0, 0, 0);
            accB[n2] = __builtin_amdgcn_mfma_f32_32x32x16_bf16(ah, bm, accB[n2], 0, 0, 0);
            accA[n2] = __builtin_amdgcn_mfma_f32_32x32x16_bf16(am, bh, accA[n2], 0, 0, 0);
            accB[n2] = __builtin_amdgcn_mfma_f32_32x32x16_bf16(am, bm, accB[n2], 0, 0, 0);
            accA[n2] = __builtin_amdgcn_mfma_f32_32x32x16_bf16(al3, bh, accA[n2], 0, 0, 0);
            accB[n2] = __builtin_amdgcn_mfma_f32_32x32x16_bf16(ah, bl, accB[n2], 0, 0, 0);
        }
    }

    const size_t outrow = ((size_t)((b * 64 + d) * 64 + h)) * 64;
#pragma unroll
    for (int n2 = 0; n2 < 2; ++n2) {
        const int cout = n2 * 32 + ln;
        const float bv = bias[cout];
#pragma unroll
        for (int r = 0; r < 16; ++r) {
            const int rl3 = (r & 3) + 8 * (r >> 2) + 4 * half;
            const size_t oe = (outrow + wm2 * 32 + rl3) * 64 + cout;
            of[oe] = fmaxf(accA[n2][r] + accB[n2][r] + bv, 0.f);
        }
    }
}

// ---------------- du1: convT s2 k=4, CIN=64, COUT=1 — wave-level ------------
__global__ __launch_bounds__(256)
void convT_du1w(const bf16_t* __restrict__ inh, const bf16_t* __restrict__ inl,
                const float* __restrict__ wt, const float* __restrict__ bias,
                float* __restrict__ out)
{
    const int lane = threadIdx.x & 63;
    const int wv   = blockIdx.x * 4 + (threadIdx.x >> 6);
    const size_t obase = (size_t)wv * 16;
    const int ow0 = (int)(obase % 128);
    size_t rem = obase / 128;
    const int ohh = (int)(rem % 128); rem /= 128;
    const int od  = (int)(rem % 128); rem /= 128;
    const int b   = (int)rem;
    const int pd = od & 1, dz = od >> 1;
    const int ph = ohh & 1, hy = ohh >> 1;
    const int wx0 = ow0 >> 1;

    float acc[16];
#pragma unroll
    for (int o = 0; o < 16; ++o) acc[o] = 0.f;

#pragma unroll
    for (int jd = 0; jd < 2; ++jd) {
        const int kd = pd + 2 * jd;
        const int iz = dz + pd - 1 + jd;
        if ((unsigned)iz >= 64u) continue;
#pragma unroll
        for (int jh = 0; jh < 2; ++jh) {
            const int kh = ph + 2 * jh;
            const int iy = hy + ph - 1 + jh;
            if ((unsigned)iy >= 64u) continue;
            const size_t rbase = ((size_t)((b * 64 + iz) * 64 + iy)) * 64;
            float wv4[4];
#pragma unroll
            for (int kw = 0; kw < 4; ++kw)
                wv4[kw] = wt[(size_t)((kd * 4 + kh) * 4 + kw) * 64 + lane];
            float v[10];
#pragma unroll
            for (int t = 0; t < 10; ++t) {
                const int ix = wx0 - 1 + t;
                if ((unsigned)ix < 64u) {
                    const size_t a = (rbase + ix) * 64 + lane;
                    v[t] = b2f(inh[a]) + b2f(inl[a]);
                } else {
                    v[t] = 0.f;
                }
            }
#pragma unroll
            for (int o = 0; o < 16; ++o) {
                const int pw = o & 1;
                const int t0 = (o >> 1) + pw;
                acc[o] = fmaf(v[t0],     wv4[pw],     acc[o]);
                acc[o] = fmaf(v[t0 + 1], wv4[pw + 2], acc[o]);
            }
        }
    }

    const float b0 = bias[0];
#pragma unroll
    for (int o = 0; o < 16; ++o) {
        float s = acc[o];
        s += __shfl_xor(s, 1);
        s += __shfl_xor(s, 2);
        s += __shfl_xor(s, 4);
        s += __shfl_xor(s, 8);
        s += __shfl_xor(s, 16);
        s += __shfl_xor(s, 32);
        if (lane == 0) out[obase + o] = s + b0;
    }
}

// --------------------------------- VQ ---------------------------------------
__global__ void zero512(float* __restrict__ p) { p[threadIdx.x] = 0.0f; }

__global__ void vq_cnorm(const float* __restrict__ cb, float* __restrict__ cnorm)
{
    const int k = blockIdx.x * 64 + threadIdx.x;
    float s = 0.0f;
    for (int ci = 0; ci < 64; ++ci) { const float c = cb[k * 64 + ci]; s = fmaf(c, c, s); }
    cnorm[k] = s;
}

// 1 thread per z (k loop wave-uniform => scalar cb loads), k unrolled x4
// with 4 independent dot chains (round-15, proven).
__global__ __launch_bounds__(256)
void vq_assign(const float* __restrict__ z, const float* __restrict__ cb,
               const float* __restrict__ cnorm, int* __restrict__ idx,
               float* __restrict__ hist, int N)
{
    const int n = blockIdx.x * 256 + threadIdx.x;
    const float4* zp = reinterpret_cast<const float4*>(z + (size_t)n * 64);
    float4 zv[16];
    float z2 = 0.0f;
#pragma unroll
    for (int i = 0; i < 16; ++i) {
        zv[i] = zp[i];
        z2 += zv[i].x * zv[i].x + zv[i].y * zv[i].y + zv[i].z * zv[i].z + zv[i].w * zv[i].w;
    }
    float best = 3.4e38f;
    int bi = 0;
#pragma unroll 1
    for (int k = 0; k < 512; k += 4) {
        float dot0 = 0.f, dot1 = 0.f, dot2 = 0.f, dot3 = 0.f;
        const float4* c0 = reinterpret_cast<const float4*>(cb + (size_t)(k + 0) * 64);
        const float4* c1 = reinterpret_cast<const float4*>(cb + (size_t)(k + 1) * 64);
        const float4* c2 = reinterpret_cast<const float4*>(cb + (size_t)(k + 2) * 64);
        const float4* c3 = reinterpret_cast<const float4*>(cb + (size_t)(k + 3) * 64);
#pragma unroll
        for (int i = 0; i < 16; ++i) {
            const float4 zi = zv[i];
            const float4 a0 = c0[i];
            const float4 a1 = c1[i];
            const float4 a2 = c2[i];
            const float4 a3 = c3[i];
            dot0 += zi.x * a0.x + zi.y * a0.y + zi.z * a0.z + zi.w * a0.w;
            dot1 += zi.x * a1.x + zi.y * a1.y + zi.z * a1.z + zi.w * a1.w;
            dot2 += zi.x * a2.x + zi.y * a2.y + zi.z * a2.z + zi.w * a2.w;
            dot3 += zi.x * a3.x + zi.y * a3.y + zi.z * a3.z + zi.w * a3.w;
        }
        const float d0 = z2 + cnorm[k + 0] - 2.0f * dot0;
        const float d1 = z2 + cnorm[k + 1] - 2.0f * dot1;
        const float d2 = z2 + cnorm[k + 2] - 2.0f * dot2;
        const float d3 = z2 + cnorm[k + 3] - 2.0f * dot3;
        if (d0 < best) { best = d0; bi = k + 0; }
        if (d1 < best) { best = d1; bi = k + 1; }
        if (d2 < best) { best = d2; bi = k + 2; }
        if (d3 < best) { best = d3; bi = k + 3; }
    }
    idx[n] = bi;
    atomicAdd(&hist[bi], 1.0f);
}

__global__ __launch_bounds__(256)
void vq_gather_split(const float* __restrict__ cb, const int* __restrict__ idx,
                     bf16_t* __restrict__ zh, bf16_t* __restrict__ zl)
{
    const int gid = blockIdx.x * 256 + threadIdx.x;
    const int n = gid >> 4, c4 = gid & 15;
    const int k = idx[n];
    const float4 c = reinterpret_cast<const float4*>(cb)[k * 16 + c4];
    ushort4 h, l;
    h.x = f2b(c.x); l.x = f2b(c.x - b2f(h.x));
    h.y = f2b(c.y); l.y = f2b(c.y - b2f(h.y));
    h.z = f2b(c.z); l.z = f2b(c.z - b2f(h.z));
    h.w = f2b(c.w); l.w = f2b(c.w - b2f(h.w));
    reinterpret_cast<ushort4*>(zh)[gid] = h;
    reinterpret_cast<ushort4*>(zl)[gid] = l;
}

__global__ __launch_bounds__(512)
void perplexity_k(const float* __restrict__ hist, float* __restrict__ out, float invN)
{
    __shared__ float red[512];
    const int t = threadIdx.x;
    const float p = hist[t] * invN;
    red[t] = p * logf(p + 1e-12f);
    __syncthreads();
    for (int s = 256; s > 0; s >>= 1) {
        if (t < s) red[t] += red[t + s];
        __syncthreads();
    }
    if (t == 0) out[0] = expf(-red[0]);
}

// ---------------------------------------------------------------------------
extern "C" void kernel_launch(void* const* d_in, const int* in_sizes, int n_in,
                              void* d_out, int out_size, void* d_ws, size_t ws_size,
                              hipStream_t stream)
{
    const float* x       = (const float*)d_in[0];
    const float* ec0_w   = (const float*)d_in[1];
    const float* ec0_b   = (const float*)d_in[2];
    const float* er0_c1w = (const float*)d_in[3];
    const float* er0_c1b = (const float*)d_in[4];
    const float* er0_c2w = (const float*)d_in[5];
    const float* er0_c2b = (const float*)d_in[6];
    const float* er0_g   = (const float*)d_in[7];
    const float* er0_be  = (const float*)d_in[8];
    const float* er0_m   = (const float*)d_in[9];
    const float* er0_v   = (const float*)d_in[10];
    const float* er0_a   = (const float*)d_in[11];
    const float* ec1_w   = (const float*)d_in[12];
    const float* ec1_b   = (const float*)d_in[13];
    const float* er1_c1w = (const float*)d_in[14];
    const float* er1_c1b = (const float*)d_in[15];
    const float* er1_c2w = (const float*)d_in[16];
    const float* er1_c2b = (const float*)d_in[17];
    const float* er1_g   = (const float*)d_in[18];
    const float* er1_be  = (const float*)d_in[19];
    const float* er1_m   = (const float*)d_in[20];
    const float* er1_v   = (const float*)d_in[21];
    const float* er1_a   = (const float*)d_in[22];
    const float* eo_w    = (const float*)d_in[23];
    const float* eo_b    = (const float*)d_in[24];
    const float* eo_a    = (const float*)d_in[25];
    const float* cb      = (const float*)d_in[26];
    const float* dc0_w   = (const float*)d_in[27];
    const float* dc0_b   = (const float*)d_in[28];
    const float* dc0_a   = (const float*)d_in[29];
    const float* dr0_c1w = (const float*)d_in[30];
    const float* dr0_c1b = (const float*)d_in[31];
    const float* dr0_c2w = (const float*)d_in[32];
    const float* dr0_c2b = (const float*)d_in[33];
    const float* dr0_g   = (const float*)d_in[34];
    const float* dr0_be  = (const float*)d_in[35];
    const float* dr0_m   = (const float*)d_in[36];
    const float* dr0_v   = (const float*)d_in[37];
    const float* dr0_a   = (const float*)d_in[38];
    const float* du0_w   = (const float*)d_in[39];
    const float* du0_b   = (const float*)d_in[40];
    const float* dr1_c1w = (const float*)d_in[41];
    const float* dr1_c1b = (const float*)d_in[42];
    const float* dr1_c2w = (const float*)d_in[43];
    const float* dr1_c2b = (const float*)d_in[44];
    const float* dr1_g   = (const float*)d_in[45];
    const float* dr1_be  = (const float*)d_in[46];
    const float* dr1_m   = (const float*)d_in[47];
    const float* dr1_v   = (const float*)d_in[48];
    const float* dr1_a   = (const float*)d_in[49];
    const float* du1_w   = (const float*)d_in[50];
    const float* du1_b   = (const float*)d_in[51];

    float* out = (float*)d_out;

    // ---- ws: A=[0,134MB) , H=[134MB,268MB) ----
    char* W = (char*)d_ws;
    float*  Af  = (float*)(W);
    float*  Hf  = (float*)(W + 134217728);
    float*  E1f = (float*)(W + 134217728);
    float*  R1f = (float*)(W + 134217728 + 33554432);
    float*  Zf  = (float*)(W);
    int*    IDX = (int*)  (W + 16777216);
    float*  CN  = (float*)(W + 17039360);
    float*  HS  = (float*)(W + 17041408);
    bf16_t* ZQh = (bf16_t*)(W + 33554432);
    bf16_t* ZQl = (bf16_t*)(W + 41943040);
    bf16_t* D0h = (bf16_t*)(W + 50331648);
    bf16_t* D0l = (bf16_t*)(W + 67108864);
    bf16_t* Gh  = (bf16_t*)(W + 83886080);
    bf16_t* Gl  = (bf16_t*)(W + 100663296);
    bf16_t* U0h = (bf16_t*)(W + 134217728);
    bf16_t* U0l = (bf16_t*)(W + 201326592);
    bf16_t* G1h = (bf16_t*)(W);
    bf16_t* G1l = (bf16_t*)(W + 67108864);

    // ---- weight arenas in d_out ----
    char* WB = (char*)d_out;
    bf16_t* e0c1h = (bf16_t*)(WB + 0);
    bf16_t* e0c1m = (bf16_t*)(WB + 221184);
    bf16_t* e0c1l = (bf16_t*)(WB + 442368);
    bf16_t* e0c2h = (bf16_t*)(WB + 663552);
    bf16_t* e0c2m = (bf16_t*)(WB + 884736);
    bf16_t* e0c2l = (bf16_t*)(WB + 1105920);
    bf16_t* ec1h  = (bf16_t*)(WB + 1327104);
    bf16_t* ec1m  = (bf16_t*)(WB + 2375680);
    bf16_t* ec1l  = (bf16_t*)(WB + 3424256);
    bf16_t* e1c1h = (bf16_t*)(WB + 4472832);
    bf16_t* e1c1m = (bf16_t*)(WB + 5357568);
    bf16_t* e1c1l = (bf16_t*)(WB + 6242304);
    bf16_t* e1c2h = (bf16_t*)(WB + 7127040);
    bf16_t* e1c2m = (bf16_t*)(WB + 8011776);
    bf16_t* e1c2l = (bf16_t*)(WB + 8896512);
    bf16_t* eoh   = (bf16_t*)(WB + 9781248);
    bf16_t* eom   = (bf16_t*)(WB + 10223616);
    bf16_t* eol   = (bf16_t*)(WB + 10665984);
    bf16_t* wec0h = (bf16_t*)(WB + 11108352);
    bf16_t* wec0m = (bf16_t*)(WB + 11116544);
    bf16_t* wec0l = (bf16_t*)(WB + 11124736);
    bf16_t* dc0h  = (bf16_t*)(WB + 0);
    bf16_t* dc0l  = (bf16_t*)(WB + 442368);
    bf16_t* d0c1h = (bf16_t*)(WB + 884736);
    bf16_t* d0c1l = (bf16_t*)(WB + 1769472);
    bf16_t* d0c2h = (bf16_t*)(WB + 2654208);
    bf16_t* d0c2l = (bf16_t*)(WB + 3538944);
    bf16_t* du0h  = (bf16_t*)(WB + 4423680);
    bf16_t* du0l  = (bf16_t*)(WB + 5472256);
    bf16_t* d1c1h = (bf16_t*)(WB + 6520832);
    bf16_t* d1c1l = (bf16_t*)(WB + 6742016);
    bf16_t* d1c2h = (bf16_t*)(WB + 6963200);
    bf16_t* d1c2l = (bf16_t*)(WB + 7184384);

    const float* fn = nullptr;
    const bf16_t* bn_ = nullptr;

    // ---- encoder weight prep (split-3, fragment-major) ----
    wprep3<<<16, 256, 0, stream>>>(ec0_w, wec0h, wec0m, wec0l, 64, 64, 4096);
    wprep3<<<432, 256, 0, stream>>>(er0_c1w, e0c1h, e0c1m, e0c1l, 64, 64, 110592);
    wprep3<<<432, 256, 0, stream>>>(er0_c2w, e0c2h, e0c2m, e0c2l, 64, 64, 110592);
    wprep3<<<2048, 256, 0, stream>>>(ec1_w, ec1h, ec1m, ec1l, 64, 128, 524288);
    wprep3<<<1728, 256, 0, stream>>>(er1_c1w, e1c1h, e1c1m, e1c1l, 128, 128, 442368);
    wprep3<<<1728, 256, 0, stream>>>(er1_c2w, e1c2h, e1c2m, e1c2l, 128, 128, 442368);
    wprep3<<<864, 256, 0, stream>>>(eo_w, eoh, eom, eol, 128, 64, 221184);

    // ---- encoder (fp32-class) ----
    conv_ec0m<<<8192, 128, 0, stream>>>(x, wec0h, wec0m, wec0l, ec0_b, Af);

    conv3e<64, 64, 64, 2, 1><<<8192, 256, 0, stream>>>(
        Af, e0c1h, e0c1m, e0c1l, er0_c1b, fn, fn, fn, fn, fn, fn, Hf);
    conv3e<64, 64, 64, 2, 3><<<8192, 256, 0, stream>>>(
        Hf, e0c2h, e0c2m, e0c2l, er0_c2b, er0_g, er0_be, er0_m, er0_v, er0_a, Af, Af);

    convs2e<<<2048, 256, 0, stream>>>(Af, ec1h, ec1m, ec1l, ec1_b, E1f);

    conv3e<128, 128, 32, 4, 1><<<2048, 256, 0, stream>>>(
        E1f, e1c1h, e1c1m, e1c1l, er1_c1b, fn, fn, fn, fn, fn, fn, R1f);
    conv3e<128, 128, 32, 4, 3><<<2048, 256, 0, stream>>>(
        R1f, e1c2h, e1c2m, e1c2l, er1_c2b, er1_g, er1_be, er1_m, er1_v, er1_a, E1f, E1f);

    conv3e<128, 64, 32, 2, 2><<<2048, 128, 0, stream>>>(
        E1f, eoh, eom, eol, eo_b, fn, fn, fn, fn, eo_a, fn, Zf);

    // ---- VQ (exact fp32, ILP assign) ----
    vq_cnorm<<<8, 64, 0, stream>>>(cb, CN);
    zero512<<<1, 512, 0, stream>>>(HS);
    vq_assign<<<256, 256, 0, stream>>>(Zf, cb, CN, IDX, HS, 65536);
    perplexity_k<<<1, 512, 0, stream>>>(HS, out + 4194304, 1.0f / 65536.0f);
    vq_gather_split<<<4096, 256, 0, stream>>>(cb, IDX, ZQh, ZQl);

    // ---- decoder weight prep (split-2, fragment-major, overwrites arena) ----
    wprep_split<<<864, 256, 0, stream>>>(dc0_w, dc0h, dc0l, 64, 128, 221184);
    wprep_split<<<1728, 256, 0, stream>>>(dr0_c1w, d0c1h, d0c1l, 128, 128, 442368);
    wprep_split<<<1728, 256, 0, stream>>>(dr0_c2w, d0c2h, d0c2l, 128, 128, 442368);
    wprep_split<<<2048, 256, 0, stream>>>(du0_w, du0h, du0l, 128, 64, 524288);
    wprep_split<<<432, 256, 0, stream>>>(dr1_c1w, d1c1h, d1c1l, 64, 64, 110592);
    wprep_split<<<432, 256, 0, stream>>>(dr1_c2w, d1c2h, d1c2l, 64, 64, 110592);

    // ---- decoder (split-2 bf16) ----
    conv3d<64, 128, 32, 4, 2><<<2048, 256, 0, stream>>>(
        ZQh, ZQl, dc0h, dc0l, dc0_b, fn, fn, fn, fn, dc0_a, bn_, bn_, D0h, D0l);
    conv3d<128, 128, 32, 4, 1><<<2048, 256, 0, stream>>>(
        D0h, D0l, d0c1h, d0c1l, dr0_c1b, fn, fn, fn, fn, fn, bn_, bn_, Gh, Gl);
    conv3d<128, 128, 32, 4, 3><<<2048, 256, 0, stream>>>(
        Gh, Gl, d0c2h, d0c2l, dr0_c2b, dr0_g, dr0_be, dr0_m, dr0_v, dr0_a,
        D0h, D0l, D0h, D0l);

    convTm<<<8192, 256, 0, stream>>>(D0h, D0l, du0h, du0l, du0_b, U0h, U0l);

    conv3d<64, 64, 64, 2, 1><<<8192, 256, 0, stream>>>(
        U0h, U0l, d1c1h, d1c1l, dr1_c1b, fn, fn, fn, fn, fn, bn_, bn_, G1h, G1l);
    conv3d<64, 64, 64, 2, 3><<<8192, 256, 0, stream>>>(
        G1h, G1l, d1c2h, d1c2l, dr1_c2b, dr1_g, dr1_be, dr1_m, dr1_v, dr1_a,
        U0h, U0l, U0h, U0l);

    convT_du1w<<<65536, 256, 0, stream>>>(U0h, U0l, du1_w, du1_b, out);
}

// Round 17
// 5177.272 us; speedup vs baseline: 1.1792x; 1.0050x over previous
//
#include <hip/hip_runtime.h>
#include <cstdint>

// ---------------------------------------------------------------------------
// VQVAE forward — MFMA implicit-GEMM convolutions, channels-last.
//
// Round-17 = round-16 + ZERO-PADDED LDS rows (pads at pv=0 and pv=SD+1,
//   zeroed once; stage at pv=vox+1; read at pv=w+kw unconditionally).
//   Removes ~144 v_cndmask + edge bools per row*thread from the issue-
//   saturated inner loops (MfmaUtil 48% + VALUBusy 39% ~= 87% issue).
//   Pad reads return stored zeros == the old masked zeros => numerics
//   bit-identical.
//   - Encoder: fp32 activations; EXACT 3-way bf16 split at LDS-stage time;
//     6-MFMA products => fp32-class => VQ argmin safe.
//   - Decoder: split-2 bf16 storage, 3-pass MFMA.
//   - vq_assign: uniform-k, 4 independent dot chains (round-15, proven).
// Retained: 4-wave blocks (32 couts/wave), fragment-major weights,
// T14 async-STAGE single-LDS-buffer, T1 XCD-chunked swizzle, LDS XOR
// swizzle, MFMA ec0, wave-level du1.
//
// C layout: col = lane&31, row = (reg&3) + 8*(reg>>2) + 4*(lane>>5)
// ---------------------------------------------------------------------------

typedef unsigned short bf16_t;
typedef __attribute__((ext_vector_type(8)))  short s8b;     // 8 x bf16 frag
typedef __attribute__((ext_vector_type(16))) float f32x16;  // 32x32 acc

__device__ __forceinline__ float b2f(bf16_t u) { return __uint_as_float((unsigned)u << 16); }
__device__ __forceinline__ bf16_t f2b(float f) {
    unsigned x = __float_as_uint(f);
    return (bf16_t)((x + 0x7FFFu + ((x >> 16) & 1u)) >> 16);
}

__device__ __forceinline__ void split3s(float v, unsigned short& h,
                                        unsigned short& m, unsigned short& l)
{
    const unsigned uv = __float_as_uint(v);
    const float fh = __uint_as_float(uv & 0xFFFF0000u);
    const float r1 = v - fh;
    const unsigned u1 = __float_as_uint(r1);
    const float fm = __uint_as_float(u1 & 0xFFFF0000u);
    const float r2 = r1 - fm;
    h = (unsigned short)(uv >> 16);
    m = (unsigned short)(u1 >> 16);
    l = (unsigned short)(__float_as_uint(r2) >> 16);
}

// ------------------------- weight prep ------------------------------------
// src [tap][ci][co] fp32 -> dst fragment-major [tap][ks][half][co][8k]
__device__ __forceinline__ int wdst(int tap, int ci_, int co_, int ci, int co)
{
    const int ks = ci_ >> 4, half = (ci_ >> 3) & 1, j = ci_ & 7;
    return (((tap * (ci >> 4) + ks) * 2 + half) * co + co_) * 8 + j;
}

__global__ __launch_bounds__(256)
void wprep3(const float* __restrict__ w, bf16_t* __restrict__ h,
            bf16_t* __restrict__ m, bf16_t* __restrict__ l,
            int ci, int co, int n)
{
    const int i = blockIdx.x * 256 + threadIdx.x;
    if (i >= n) return;
    const int co_ = i % co;
    const int ci_ = (i / co) % ci;
    const int tap = i / (co * ci);
    const int dst = wdst(tap, ci_, co_, ci, co);
    unsigned short hh, mm, ll2;
    split3s(w[i], hh, mm, ll2);
    h[dst] = hh; m[dst] = mm; l[dst] = ll2;
}

__global__ __launch_bounds__(256)
void wprep_split(const float* __restrict__ w, bf16_t* __restrict__ hi,
                 bf16_t* __restrict__ lo, int ci, int co, int n)
{
    const int i = blockIdx.x * 256 + threadIdx.x;
    if (i >= n) return;
    const int co_ = i % co;
    const int ci_ = (i / co) % ci;
    const int tap = i / (co * ci);
    const float v = w[i];
    const int dst = wdst(tap, ci_, co_, ci, co);
    const bf16_t h = f2b(v);
    hi[dst] = h;
    lo[dst] = f2b(v - b2f(h));
}

// ---------------- encoder 3x3x3 conv: fp32 in, padded LDS, split-3 ----------
// NWC = COUT/32 waves in N (32 couts/wave). (SD/32) waves in M.
// EPI: 0=ReLU 1=swish 2=PReLU 3=BN+PReLU+skip+ReLU
template<int CIN, int COUT, int SD, int NWC, int EPI>
__global__ __launch_bounds__((SD / 32) * NWC * 64)
void conv3e(const float* __restrict__ xf,
            const bf16_t* __restrict__ wh, const bf16_t* __restrict__ wm,
            const bf16_t* __restrict__ wl,
            const float* __restrict__ bias,
            const float* __restrict__ g, const float* __restrict__ be,
            const float* __restrict__ mn, const float* __restrict__ vr,
            const float* __restrict__ al,
            const float* skf, float* __restrict__ of)
{
    constexpr int NT = (SD / 32) * NWC * 64;
    constexpr int LP = (SD * CIN) / (4 * NT);
    constexpr int KS = CIN / 16;
    __shared__ bf16_t lh[(SD + 2) * CIN], lm[(SD + 2) * CIN], ll[(SD + 2) * CIN];

    const int tid  = threadIdx.x;
    const int lane = tid & 63;
    const int wid  = tid >> 6;
    const int wn   = wid % NWC, wm2 = wid / NWC;
    const int half = lane >> 5, ln = lane & 31;
    const int w    = wm2 * 32 + ln;
    const int nwg  = gridDim.x;
    const int bid  = (blockIdx.x & 7) * (nwg >> 3) + (blockIdx.x >> 3);
    const int h    = bid % SD;
    const int d    = (bid / SD) % SD;
    const int b    = bid / (SD * SD);
    const int cout = wn * 32 + ln;

    int pz[9], py[9], pt[9], np = 0;
    for (int kd = 0; kd < 3; ++kd) {
        const int iz = d + kd - 1;
        if ((unsigned)iz >= (unsigned)SD) continue;
        for (int kh = 0; kh < 3; ++kh) {
            const int iy = h + kh - 1;
            if ((unsigned)iy >= (unsigned)SD) continue;
            pz[np] = iz; py[np] = iy; pt[np] = (kd * 3 + kh) * 3; ++np;
        }
    }

    f32x16 accA, accB;
#pragma unroll
    for (int i = 0; i < 16; ++i) { accA[i] = 0.f; accB[i] = 0.f; }

    // zero the pad voxels (pv = 0 and pv = SD+1), once
    for (int i = tid; i < CIN / 2; i += NT) {
        const int pv = (i < CIN / 4) ? 0 : (SD + 1);
        const int ch = (i % (CIN / 4)) * 4;
        const int bo = ((pv * CIN + ch) * 2) ^ ((pv & 7) << 4);
        const ushort4 z4 = make_ushort4(0, 0, 0, 0);
        *reinterpret_cast<ushort4*>((char*)&lh[0] + bo) = z4;
        *reinterpret_cast<ushort4*>((char*)&lm[0] + bo) = z4;
        *reinterpret_cast<ushort4*>((char*)&ll[0] + bo) = z4;
    }

    float4 rg[LP];
    auto loadrow = [&](int iz, int iy) {
        const float* src = xf + ((size_t)((b * SD + iz) * SD + iy)) * SD * CIN;
#pragma unroll
        for (int j = 0; j < LP; ++j)
            rg[j] = *reinterpret_cast<const float4*>(src + (size_t)(tid + j * NT) * 4);
    };
    auto writerow = [&]() {
#pragma unroll
        for (int j = 0; j < LP; ++j) {
            const int idx = (tid + j * NT) * 4;
            const int pv = idx / CIN + 1, ch = idx % CIN;
            ushort4 h4, m4, l4;
            split3s(rg[j].x, h4.x, m4.x, l4.x);
            split3s(rg[j].y, h4.y, m4.y, l4.y);
            split3s(rg[j].z, h4.z, m4.z, l4.z);
            split3s(rg[j].w, h4.w, m4.w, l4.w);
            const int bo = ((pv * CIN + ch) * 2) ^ ((pv & 7) << 4);
            *reinterpret_cast<ushort4*>((char*)&lh[0] + bo) = h4;
            *reinterpret_cast<ushort4*>((char*)&lm[0] + bo) = m4;
            *reinterpret_cast<ushort4*>((char*)&ll[0] + bo) = l4;
        }
    };

    loadrow(pz[0], py[0]);
    writerow();
    __syncthreads();
#pragma unroll 1
    for (int i = 0; i < np; ++i) {
        if (i + 1 < np) loadrow(pz[i + 1], py[i + 1]);   // issue early (T14)
#pragma unroll
        for (int kw = 0; kw < 3; ++kw) {
            const int tap = pt[i] + kw;
            const int pv = w + kw;                       // padded index 0..SD+1
#pragma unroll
            for (int ks = 0; ks < KS; ++ks) {
                const int bo = ((pv * CIN + half * 8 + ks * 16) * 2) ^ ((pv & 7) << 4);
                const s8b ah  = *reinterpret_cast<const s8b*>((const char*)&lh[0] + bo);
                const s8b am  = *reinterpret_cast<const s8b*>((const char*)&lm[0] + bo);
                const s8b al3 = *reinterpret_cast<const s8b*>((const char*)&ll[0] + bo);
                const size_t wb = ((size_t)((tap * KS + ks) * 2 + half) * COUT + cout) * 8;
                const s8b bh = *reinterpret_cast<const s8b*>(wh + wb);
                const s8b bm = *reinterpret_cast<const s8b*>(wm + wb);
                const s8b bl = *reinterpret_cast<const s8b*>(wl + wb);
                accA = __builtin_amdgcn_mfma_f32_32x32x16_bf16(ah, bh, accA, 0, 0, 0);
                accB = __builtin_amdgcn_mfma_f32_32x32x16_bf16(ah, bm, accB, 0, 0, 0);
                accA = __builtin_amdgcn_mfma_f32_32x32x16_bf16(am, bh, accA, 0, 0, 0);
                accB = __builtin_amdgcn_mfma_f32_32x32x16_bf16(am, bm, accB, 0, 0, 0);
                accA = __builtin_amdgcn_mfma_f32_32x32x16_bf16(al3, bh, accA, 0, 0, 0);
                accB = __builtin_amdgcn_mfma_f32_32x32x16_bf16(ah, bl, accB, 0, 0, 0);
            }
        }
        if (i + 1 < np) {
            __syncthreads();          // all waves done reading LDS
            writerow();               // implicit vmcnt wait on rg here
            __syncthreads();          // LDS ready
        }
    }

    const size_t outrow = ((size_t)((b * SD + d) * SD + h)) * SD;
    const float bv = bias[cout];
    float sc = 0.f, mm = 0.f, bb2 = 0.f, aa = 0.f;
    if constexpr (EPI == 3) {
        sc = g[cout] * (1.0f / sqrtf(vr[cout] + 1e-3f));
        mm = mn[cout]; bb2 = be[cout]; aa = al[cout];
    }
    if constexpr (EPI == 2) aa = al[cout];
#pragma unroll
    for (int r = 0; r < 16; ++r) {
        const int rl = (r & 3) + 8 * (r >> 2) + 4 * half;
        const size_t oe = (outrow + wm2 * 32 + rl) * COUT + cout;
        float y = accA[r] + accB[r] + bv;
        if constexpr (EPI == 0) y = fmaxf(y, 0.f);
        else if constexpr (EPI == 1) y = y / (1.f + expf(-y));
        else if constexpr (EPI == 2) y = y > 0.f ? y : aa * y;
        else {
            float t2 = (y - mm) * sc + bb2;
            t2 = t2 > 0.f ? t2 : aa * t2;
            y = fmaxf(skf[oe] + t2, 0.f);
        }
        of[oe] = y;
    }
}

// ---------------- ec1: stride-2 k=4, fp32 in, padded LDS, split-3 -----------
__global__ __launch_bounds__(256)
void convs2e(const float* __restrict__ xf,
             const bf16_t* __restrict__ wh, const bf16_t* __restrict__ wm,
             const bf16_t* __restrict__ wl,
             const float* __restrict__ bias, float* __restrict__ of)
{
    constexpr int NT = 256, LP = (64 * 64) / (4 * NT);
    __shared__ bf16_t lh[66 * 64], lm[66 * 64], ll[66 * 64];

    const int tid  = threadIdx.x;
    const int lane = tid & 63;
    const int wn   = tid >> 6;          // 4 waves x 32 couts
    const int half = lane >> 5, ln = lane & 31;
    const int nwg  = gridDim.x;
    const int bid  = (blockIdx.x & 7) * (nwg >> 3) + (blockIdx.x >> 3);
    const int h    = bid % 32;
    const int d    = (bid / 32) % 32;
    const int b    = bid / 1024;
    const int cout = wn * 32 + ln;

    int pz[16], py[16], pt[16], np = 0;
    for (int kd = 0; kd < 4; ++kd) {
        const int iz = 2 * d + kd - 1;
        if ((unsigned)iz >= 64u) continue;
        for (int kh = 0; kh < 4; ++kh) {
            const int iy = 2 * h + kh - 1;
            if ((unsigned)iy >= 64u) continue;
            pz[np] = iz; py[np] = iy; pt[np] = (kd * 4 + kh) * 4; ++np;
        }
    }

    f32x16 accA, accB;
#pragma unroll
    for (int i = 0; i < 16; ++i) { accA[i] = 0.f; accB[i] = 0.f; }

    for (int i = tid; i < 32; i += NT) {       // 2 pads x 64/4
        const int pv = (i < 16) ? 0 : 65;
        const int ch = (i % 16) * 4;
        const int bo = ((pv * 64 + ch) * 2) ^ ((pv & 7) << 4);
        const ushort4 z4 = make_ushort4(0, 0, 0, 0);
        *reinterpret_cast<ushort4*>((char*)&lh[0] + bo) = z4;
        *reinterpret_cast<ushort4*>((char*)&lm[0] + bo) = z4;
        *reinterpret_cast<ushort4*>((char*)&ll[0] + bo) = z4;
    }

    float4 rg[LP];
    auto loadrow = [&](int iz, int iy) {
        const float* src = xf + ((size_t)((b * 64 + iz) * 64 + iy)) * 64 * 64;
#pragma unroll
        for (int j = 0; j < LP; ++j)
            rg[j] = *reinterpret_cast<const float4*>(src + (size_t)(tid + j * NT) * 4);
    };
    auto writerow = [&]() {
#pragma unroll
        for (int j = 0; j < LP; ++j) {
            const int idx = (tid + j * NT) * 4;
            const int pv = idx / 64 + 1, ch = idx % 64;
            ushort4 h4, m4, l4;
            split3s(rg[j].x, h4.x, m4.x, l4.x);
            split3s(rg[j].y, h4.y, m4.y, l4.y);
            split3s(rg[j].z, h4.z, m4.z, l4.z);
            split3s(rg[j].w, h4.w, m4.w, l4.w);
            const int bo = ((pv * 64 + ch) * 2) ^ ((pv & 7) << 4);
            *reinterpret_cast<ushort4*>((char*)&lh[0] + bo) = h4;
            *reinterpret_cast<ushort4*>((char*)&lm[0] + bo) = m4;
            *reinterpret_cast<ushort4*>((char*)&ll[0] + bo) = l4;
        }
    };

    loadrow(pz[0], py[0]);
    writerow();
    __syncthreads();
#pragma unroll 1
    for (int i = 0; i < np; ++i) {
        if (i + 1 < np) loadrow(pz[i + 1], py[i + 1]);
#pragma unroll
        for (int kw = 0; kw < 4; ++kw) {
            const int tap = pt[i] + kw;
            const int pv = 2 * ln + kw;                 // padded 0..65
#pragma unroll
            for (int ks = 0; ks < 4; ++ks) {
                const int bo = ((pv * 64 + half * 8 + ks * 16) * 2) ^ ((pv & 7) << 4);
                const s8b ah  = *reinterpret_cast<const s8b*>((const char*)&lh[0] + bo);
                const s8b am  = *reinterpret_cast<const s8b*>((const char*)&lm[0] + bo);
                const s8b al3 = *reinterpret_cast<const s8b*>((const char*)&ll[0] + bo);
                const size_t wb = ((size_t)((tap * 4 + ks) * 2 + half) * 128 + cout) * 8;
                const s8b bh = *reinterpret_cast<const s8b*>(wh + wb);
                const s8b bm = *reinterpret_cast<const s8b*>(wm + wb);
                const s8b bl = *reinterpret_cast<const s8b*>(wl + wb);
                accA = __builtin_amdgcn_mfma_f32_32x32x16_bf16(ah, bh, accA, 0, 0, 0);
                accB = __builtin_amdgcn_mfma_f32_32x32x16_bf16(ah, bm, accB, 0, 0, 0);
                accA = __builtin_amdgcn_mfma_f32_32x32x16_bf16(am, bh, accA, 0, 0, 0);
                accB = __builtin_amdgcn_mfma_f32_32x32x16_bf16(am, bm, accB, 0, 0, 0);
                accA = __builtin_amdgcn_mfma_f32_32x32x16_bf16(al3, bh, accA, 0, 0, 0);
                accB = __builtin_amdgcn_mfma_f32_32x32x16_bf16(ah, bl, accB, 0, 0, 0);
            }
        }
        if (i + 1 < np) {
            __syncthreads();
            writerow();
            __syncthreads();
        }
    }

    const size_t outrow = ((size_t)((b * 32 + d) * 32 + h)) * 32;
    const float bv = bias[cout];
#pragma unroll
    for (int r = 0; r < 16; ++r) {
        const int rl = (r & 3) + 8 * (r >> 2) + 4 * half;
        const size_t oe = (outrow + rl) * 128 + cout;
        of[oe] = fmaxf(accA[r] + accB[r] + bv, 0.f);
    }
}

// ---------------- decoder 3x3x3 conv: split-2 bf16, padded LDS --------------
template<int CIN, int COUT, int SD, int NWC, int EPI>
__global__ __launch_bounds__((SD / 32) * NWC * 64)
void conv3d(const bf16_t* __restrict__ xh, const bf16_t* __restrict__ xl,
            const bf16_t* __restrict__ wh, const bf16_t* __restrict__ wl,
            const float* __restrict__ bias,
            const float* __restrict__ g, const float* __restrict__ be,
            const float* __restrict__ mn, const float* __restrict__ vr,
            const float* __restrict__ al,
            const bf16_t* skh, const bf16_t* skl,
            bf16_t* oh, bf16_t* ol)
{
    constexpr int NT = (SD / 32) * NWC * 64;
    constexpr int LP = (SD * CIN) / (4 * NT);
    constexpr int KS = CIN / 16;
    __shared__ bf16_t lh[(SD + 2) * CIN], ll[(SD + 2) * CIN];

    const int tid  = threadIdx.x;
    const int lane = tid & 63;
    const int wid  = tid >> 6;
    const int wn   = wid % NWC, wm2 = wid / NWC;
    const int half = lane >> 5, ln = lane & 31;
    const int w    = wm2 * 32 + ln;
    const int nwg  = gridDim.x;
    const int bid  = (blockIdx.x & 7) * (nwg >> 3) + (blockIdx.x >> 3);
    const int h    = bid % SD;
    const int d    = (bid / SD) % SD;
    const int b    = bid / (SD * SD);
    const int cout = wn * 32 + ln;

    int pz[9], py[9], pt[9], np = 0;
    for (int kd = 0; kd < 3; ++kd) {
        const int iz = d + kd - 1;
        if ((unsigned)iz >= (unsigned)SD) continue;
        for (int kh = 0; kh < 3; ++kh) {
            const int iy = h + kh - 1;
            if ((unsigned)iy >= (unsigned)SD) continue;
            pz[np] = iz; py[np] = iy; pt[np] = (kd * 3 + kh) * 3; ++np;
        }
    }

    f32x16 accA, accB;
#pragma unroll
    for (int i = 0; i < 16; ++i) { accA[i] = 0.f; accB[i] = 0.f; }

    for (int i = tid; i < CIN / 2; i += NT) {
        const int pv = (i < CIN / 4) ? 0 : (SD + 1);
        const int ch = (i % (CIN / 4)) * 4;
        const int bo = ((pv * CIN + ch) * 2) ^ ((pv & 7) << 4);
        const ushort4 z4 = make_ushort4(0, 0, 0, 0);
        *reinterpret_cast<ushort4*>((char*)&lh[0] + bo) = z4;
        *reinterpret_cast<ushort4*>((char*)&ll[0] + bo) = z4;
    }

    ushort4 rh[LP], rl2a[LP];
    auto loadrow = [&](int iz, int iy) {
        const size_t rb = ((size_t)((b * SD + iz) * SD + iy)) * SD * CIN;
#pragma unroll
        for (int j = 0; j < LP; ++j) {
            const int idx = (tid + j * NT) * 4;
            rh[j]   = *reinterpret_cast<const ushort4*>(xh + rb + idx);
            rl2a[j] = *reinterpret_cast<const ushort4*>(xl + rb + idx);
        }
    };
    auto writerow = [&]() {
#pragma unroll
        for (int j = 0; j < LP; ++j) {
            const int idx = (tid + j * NT) * 4;
            const int pv = idx / CIN + 1, ch = idx % CIN;
            const int bo = ((pv * CIN + ch) * 2) ^ ((pv & 7) << 4);
            *reinterpret_cast<ushort4*>((char*)&lh[0] + bo) = rh[j];
            *reinterpret_cast<ushort4*>((char*)&ll[0] + bo) = rl2a[j];
        }
    };

    loadrow(pz[0], py[0]);
    writerow();
    __syncthreads();
#pragma unroll 1
    for (int i = 0; i < np; ++i) {
        if (i + 1 < np) loadrow(pz[i + 1], py[i + 1]);
#pragma unroll
        for (int kw = 0; kw < 3; ++kw) {
            const int tap = pt[i] + kw;
            const int pv = w + kw;
#pragma unroll
            for (int ks = 0; ks < KS; ++ks) {
                const int bo = ((pv * CIN + half * 8 + ks * 16) * 2) ^ ((pv & 7) << 4);
                const s8b ah  = *reinterpret_cast<const s8b*>((const char*)&lh[0] + bo);
                const s8b al2 = *reinterpret_cast<const s8b*>((const char*)&ll[0] + bo);
                const size_t wb = ((size_t)((tap * KS + ks) * 2 + half) * COUT + cout) * 8;
                const s8b bh = *reinterpret_cast<const s8b*>(wh + wb);
                const s8b bl = *reinterpret_cast<const s8b*>(wl + wb);
                accA = __builtin_amdgcn_mfma_f32_32x32x16_bf16(ah, bh, accA, 0, 0, 0);
                accB = __builtin_amdgcn_mfma_f32_32x32x16_bf16(al2, bh, accB, 0, 0, 0);
                accB = __builtin_amdgcn_mfma_f32_32x32x16_bf16(ah, bl, accB, 0, 0, 0);
            }
        }
        if (i + 1 < np) {
            __syncthreads();
            writerow();
            __syncthreads();
        }
    }

    const size_t outrow = ((size_t)((b * SD + d) * SD + h)) * SD;
    const float bv = bias[cout];
    float sc = 0.f, mm = 0.f, bb2 = 0.f, aa = 0.f;
    if constexpr (EPI == 3) {
        sc = g[cout] * (1.0f / sqrtf(vr[cout] + 1e-3f));
        mm = mn[cout]; bb2 = be[cout]; aa = al[cout];
    }
    if constexpr (EPI == 2) aa = al[cout];
#pragma unroll
    for (int r = 0; r < 16; ++r) {
        const int rl3 = (r & 3) + 8 * (r >> 2) + 4 * half;
        const size_t oe = (outrow + wm2 * 32 + rl3) * COUT + cout;
        float y = accA[r] + accB[r] + bv;
        if constexpr (EPI == 0) y = fmaxf(y, 0.f);
        else if constexpr (EPI == 1) y = y / (1.f + expf(-y));
        else if constexpr (EPI == 2) y = y > 0.f ? y : aa * y;
        else {
            float t2 = (y - mm) * sc + bb2;
            t2 = t2 > 0.f ? t2 : aa * t2;
            float sv = b2f(skh[oe]) + b2f(skl[oe]);
            y = fmaxf(sv + t2, 0.f);
        }
        const bf16_t hh = f2b(y);
        oh[oe] = hh;
        ol[oe] = f2b(y - b2f(hh));
    }
}

// ---------------- convT stride-2 k=4 (du0, split-2, padded LDS) -------------
__global__ __launch_bounds__(256)
void convTm(const bf16_t* __restrict__ xh, const bf16_t* __restrict__ xl,
            const bf16_t* __restrict__ wh, const bf16_t* __restrict__ wl,
            const float* __restrict__ bias,
            bf16_t* __restrict__ oh, bf16_t* __restrict__ ol)
{
    constexpr int NT = 256, LP = (32 * 128) / (4 * NT);
    __shared__ bf16_t lh[34 * 128], ll[34 * 128];

    const int tid  = threadIdx.x;
    const int lane = tid & 63;
    const int wid  = tid >> 6;
    const int wn   = wid & 1, p = wid >> 1;
    const int half = lane >> 5, ln = lane & 31;
    const int nwg  = gridDim.x;
    const int bid  = (blockIdx.x & 7) * (nwg >> 3) + (blockIdx.x >> 3);
    const int ohh  = bid % 64;
    const int od   = (bid / 64) % 64;
    const int b    = bid / 4096;
    const int pd = od & 1, dz = od >> 1;
    const int ph = ohh & 1, hy = ohh >> 1;
    const int cout = wn * 32 + ln;

    int pz[4], py[4], pt[4], np = 0;
    for (int jd = 0; jd < 2; ++jd) {
        const int kd = pd + 2 * jd;
        const int iz = dz + pd - 1 + jd;
        if ((unsigned)iz >= 32u) continue;
        for (int jh = 0; jh < 2; ++jh) {
            const int kh = ph + 2 * jh;
            const int iy = hy + ph - 1 + jh;
            if ((unsigned)iy >= 32u) continue;
            pz[np] = iz; py[np] = iy; pt[np] = (kd * 4 + kh) * 4; ++np;
        }
    }

    f32x16 accA, accB;
#pragma unroll
    for (int i = 0; i < 16; ++i) { accA[i] = 0.0f; accB[i] = 0.0f; }

    for (int i = tid; i < 64; i += NT) {        // 2 pads x 128/4
        const int pv = (i < 32) ? 0 : 33;
        const int ch = (i % 32) * 4;
        const int bo = ((pv * 128 + ch) * 2) ^ ((pv & 7) << 4);
        const ushort4 z4 = make_ushort4(0, 0, 0, 0);
        *reinterpret_cast<ushort4*>((char*)&lh[0] + bo) = z4;
        *reinterpret_cast<ushort4*>((char*)&ll[0] + bo) = z4;
    }

    ushort4 rh[LP], rl2a[LP];
    auto loadrow = [&](int iz, int iy) {
        const size_t rb = ((size_t)((b * 32 + iz) * 32 + iy)) * 32 * 128;
#pragma unroll
        for (int j = 0; j < LP; ++j) {
            const int idx = (tid + j * NT) * 4;
            rh[j]   = *reinterpret_cast<const ushort4*>(xh + rb + idx);
            rl2a[j] = *reinterpret_cast<const ushort4*>(xl + rb + idx);
        }
    };
    auto writerow = [&]() {
#pragma unroll
        for (int j = 0; j < LP; ++j) {
            const int idx = (tid + j * NT) * 4;
            const int pv = idx / 128 + 1, ch = idx % 128;
            const int bo = ((pv * 128 + ch) * 2) ^ ((pv & 7) << 4);
            *reinterpret_cast<ushort4*>((char*)&lh[0] + bo) = rh[j];
            *reinterpret_cast<ushort4*>((char*)&ll[0] + bo) = rl2a[j];
        }
    };

    loadrow(pz[0], py[0]);
    writerow();
    __syncthreads();
#pragma unroll 1
    for (int i = 0; i < np; ++i) {
        if (i + 1 < np) loadrow(pz[i + 1], py[i + 1]);
#pragma unroll
        for (int jw = 0; jw < 2; ++jw) {
            const int kw = p + 2 * jw;
            const int tap = pt[i] + kw;
            const int pv = ln + p + jw;                 // padded 0..33
#pragma unroll
            for (int ks = 0; ks < 8; ++ks) {
                const int bo = ((pv * 128 + half * 8 + ks * 16) * 2) ^ ((pv & 7) << 4);
                const s8b a  = *reinterpret_cast<const s8b*>((const char*)&lh[0] + bo);
                const s8b a2 = *reinterpret_cast<const s8b*>((const char*)&ll[0] + bo);
                const size_t wb = ((size_t)((tap * 8 + ks) * 2 + half) * 64 + cout) * 8;
                const s8b bb = *reinterpret_cast<const s8b*>(wh + wb);
                const s8b b2 = *reinterpret_cast<const s8b*>(wl + wb);
                accA = __builtin_amdgcn_mfma_f32_32x32x16_bf16(a, bb, accA, 0, 0, 0);
                accB = __builtin_amdgcn_mfma_f32_32x32x16_bf16(a2, bb, accB, 0, 0, 0);
                accB = __builtin_amdgcn_mfma_f32_32x32x16_bf16(a, b2, accB, 0, 0, 0);
            }
        }
        if (i + 1 < np) {
            __syncthreads();
            writerow();
            __syncthreads();
        }
    }

    const float bv = bias[cout];
#pragma unroll
    for (int r = 0; r < 16; ++r) {
        const int rl3 = (r & 3) + 8 * (r >> 2) + 4 * half;
        const int ow = 2 * rl3 + p;
        const size_t oe = (((size_t)((b * 64 + od) * 64 + ohh)) * 64 + ow) * 64 + cout;
        const float y = fmaxf(accA[r] + accB[r] + bv, 0.f);
        const bf16_t hh = f2b(y);
        oh[oe] = hh;
        ol[oe] = f2b(y - b2f(hh));
    }
}

// ---------------- ec0 via MFMA: s2 k=4, CIN=1, K=64 taps --------------------
__global__ __launch_bounds__(128)
void conv_ec0m(const float* __restrict__ x,
               const bf16_t* __restrict__ wh, const bf16_t* __restrict__ wm,
               const bf16_t* __restrict__ wl,
               const float* __restrict__ bias, float* __restrict__ of)
{
    __shared__ bf16_t lh[16 * 132], lm[16 * 132], ll[16 * 132];

    const int tid  = threadIdx.x;
    const int lane = tid & 63;
    const int wm2  = tid >> 6;
    const int half = lane >> 5, ln = lane & 31;
    const int w    = wm2 * 32 + ln;
    const int nwg  = gridDim.x;
    const int bid  = (blockIdx.x & 7) * (nwg >> 3) + (blockIdx.x >> 3);
    const int h    = bid % 64;
    const int d    = (bid / 64) % 64;
    const int b    = bid / 4096;

    for (int i = tid; i < 16 * 132; i += 128) {
        const int row = i / 132, col = i % 132;
        const int kd = row >> 2, kh = row & 3;
        const int iz = 2 * d + kd - 1, iy = 2 * h + kh - 1;
        const int ix = col - 1;
        float v = 0.f;
        if ((unsigned)iz < 128u && (unsigned)iy < 128u &&
            (unsigned)ix < 128u && col < 130)
            v = x[(size_t)((b * 128 + iz) * 128 + iy) * 128 + ix];
        unsigned short hh, mm2, ll2;
        split3s(v, hh, mm2, ll2);
        lh[i] = hh; lm[i] = mm2; ll[i] = ll2;
    }
    __syncthreads();

    f32x16 accA[2], accB[2];
#pragma unroll
    for (int i = 0; i < 16; ++i) {
        accA[0][i] = 0.f; accA[1][i] = 0.f;
        accB[0][i] = 0.f; accB[1][i] = 0.f;
    }

#pragma unroll
    for (int ks = 0; ks < 4; ++ks) {
        const int row0 = ks * 4 + 2 * half;
        const int i0 = row0 * 132 + 2 * w;
        const int i1 = i0 + 132;
        s8b ah, am, al3;
        {
            uint* ap = (uint*)&ah;
            ap[0] = *(const uint*)&lh[i0]; ap[1] = *(const uint*)&lh[i0 + 2];
            ap[2] = *(const uint*)&lh[i1]; ap[3] = *(const uint*)&lh[i1 + 2];
        }
        {
            uint* ap = (uint*)&am;
            ap[0] = *(const uint*)&lm[i0]; ap[1] = *(const uint*)&lm[i0 + 2];
            ap[2] = *(const uint*)&lm[i1]; ap[3] = *(const uint*)&lm[i1 + 2];
        }
        {
            uint* ap = (uint*)&al3;
            ap[0] = *(const uint*)&ll[i0]; ap[1] = *(const uint*)&ll[i0 + 2];
            ap[2] = *(const uint*)&ll[i1]; ap[3] = *(const uint*)&ll[i1 + 2];
        }
        const size_t wb0 = ((size_t)(ks * 2 + half) * 64 + ln) * 8;
#pragma unroll
        for (int n2 = 0; n2 < 2; ++n2) {
            const size_t wb = wb0 + n2 * 256;
            const s8b bh = *reinterpret_cast<const s8b*>(wh + wb);
            const s8b bm = *reinterpret_cast<const s8b*>(wm + wb);
            const s8b bl = *reinterpret_cast<const s8b*>(wl + wb);
            accA[n2] = __builtin_amdgcn_mfma_f32_32x32x16_bf16(ah, bh, accA[n2], 0, 0, 0);
            accB[n2] = __builtin_amdgcn_mfma_f32_32x32x16_bf16(ah, bm, accB[n2], 0, 0, 0);
            accA[n2] = __builtin_amdgcn_mfma_f32_32x32x16_bf16(am, bh, accA[n2], 0, 0, 0);
            accB[n2] = __builtin_amdgcn_mfma_f32_32x32x16_bf16(am, bm, accB[n2], 0, 0, 0);
            accA[n2] = __builtin_amdgcn_mfma_f32_32x32x16_bf16(al3, bh, accA[n2], 0, 0, 0);
            accB[n2] = __builtin_amdgcn_mfma_f32_32x32x16_bf16(ah, bl, accB[n2], 0, 0, 0);
        }
    }

    const size_t outrow = ((size_t)((b * 64 + d) * 64 + h)) * 64;
#pragma unroll
    for (int n2 = 0; n2 < 2; ++n2) {
        const int cout = n2 * 32 + ln;
        const float bv = bias[cout];
#pragma unroll
        for (int r = 0; r < 16; ++r) {
            const int rl3 = (r & 3) + 8 * (r >> 2) + 4 * half;
            const size_t oe = (outrow + wm2 * 32 + rl3) * 64 + cout;
            of[oe] = fmaxf(accA[n2][r] + accB[n2][r] + bv, 0.f);
        }
    }
}

// ---------------- du1: convT s2 k=4, CIN=64, COUT=1 — wave-level ------------
__global__ __launch_bounds__(256)
void convT_du1w(const bf16_t* __restrict__ inh, const bf16_t* __restrict__ inl,
                const float* __restrict__ wt, const float* __restrict__ bias,
                float* __restrict__ out)
{
    const int lane = threadIdx.x & 63;
    const int wv   = blockIdx.x * 4 + (threadIdx.x >> 6);
    const size_t obase = (size_t)wv * 16;
    const int ow0 = (int)(obase % 128);
    size_t rem = obase / 128;
    const int ohh = (int)(rem % 128); rem /= 128;
    const int od  = (int)(rem % 128); rem /= 128;
    const int b   = (int)rem;
    const int pd = od & 1, dz = od >> 1;
    const int ph = ohh & 1, hy = ohh >> 1;
    const int wx0 = ow0 >> 1;

    float acc[16];
#pragma unroll
    for (int o = 0; o < 16; ++o) acc[o] = 0.f;

#pragma unroll
    for (int jd = 0; jd < 2; ++jd) {
        const int kd = pd + 2 * jd;
        const int iz = dz + pd - 1 + jd;
        if ((unsigned)iz >= 64u) continue;
#pragma unroll
        for (int jh = 0; jh < 2; ++jh) {
            const int kh = ph + 2 * jh;
            const int iy = hy + ph - 1 + jh;
            if ((unsigned)iy >= 64u) continue;
            const size_t rbase = ((size_t)((b * 64 + iz) * 64 + iy)) * 64;
            float wv4[4];
#pragma unroll
            for (int kw = 0; kw < 4; ++kw)
                wv4[kw] = wt[(size_t)((kd * 4 + kh) * 4 + kw) * 64 + lane];
            float v[10];
#pragma unroll
            for (int t = 0; t < 10; ++t) {
                const int ix = wx0 - 1 + t;
                if ((unsigned)ix < 64u) {
                    const size_t a = (rbase + ix) * 64 + lane;
                    v[t] = b2f(inh[a]) + b2f(inl[a]);
                } else {
                    v[t] = 0.f;
                }
            }
#pragma unroll
            for (int o = 0; o < 16; ++o) {
                const int pw = o & 1;
                const int t0 = (o >> 1) + pw;
                acc[o] = fmaf(v[t0],     wv4[pw],     acc[o]);
                acc[o] = fmaf(v[t0 + 1], wv4[pw + 2], acc[o]);
            }
        }
    }

    const float b0 = bias[0];
#pragma unroll
    for (int o = 0; o < 16; ++o) {
        float s = acc[o];
        s += __shfl_xor(s, 1);
        s += __shfl_xor(s, 2);
        s += __shfl_xor(s, 4);
        s += __shfl_xor(s, 8);
        s += __shfl_xor(s, 16);
        s += __shfl_xor(s, 32);
        if (lane == 0) out[obase + o] = s + b0;
    }
}

// --------------------------------- VQ ---------------------------------------
__global__ void zero512(float* __restrict__ p) { p[threadIdx.x] = 0.0f; }

__global__ void vq_cnorm(const float* __restrict__ cb, float* __restrict__ cnorm)
{
    const int k = blockIdx.x * 64 + threadIdx.x;
    float s = 0.0f;
    for (int ci = 0; ci < 64; ++ci) { const float c = cb[k * 64 + ci]; s = fmaf(c, c, s); }
    cnorm[k] = s;
}

// 1 thread per z (k loop wave-uniform => scalar cb loads), k unrolled x4
// with 4 independent dot chains (round-15, proven).
__global__ __launch_bounds__(256)
void vq_assign(const float* __restrict__ z, const float* __restrict__ cb,
               const float* __restrict__ cnorm, int* __restrict__ idx,
               float* __restrict__ hist, int N)
{
    const int n = blockIdx.x * 256 + threadIdx.x;
    const float4* zp = reinterpret_cast<const float4*>(z + (size_t)n * 64);
    float4 zv[16];
    float z2 = 0.0f;
#pragma unroll
    for (int i = 0; i < 16; ++i) {
        zv[i] = zp[i];
        z2 += zv[i].x * zv[i].x + zv[i].y * zv[i].y + zv[i].z * zv[i].z + zv[i].w * zv[i].w;
    }
    float best = 3.4e38f;
    int bi = 0;
#pragma unroll 1
    for (int k = 0; k < 512; k += 4) {
        float dot0 = 0.f, dot1 = 0.f, dot2 = 0.f, dot3 = 0.f;
        const float4* c0 = reinterpret_cast<const float4*>(cb + (size_t)(k + 0) * 64);
        const float4* c1 = reinterpret_cast<const float4*>(cb + (size_t)(k + 1) * 64);
        const float4* c2 = reinterpret_cast<const float4*>(cb + (size_t)(k + 2) * 64);
        const float4* c3 = reinterpret_cast<const float4*>(cb + (size_t)(k + 3) * 64);
#pragma unroll
        for (int i = 0; i < 16; ++i) {
            const float4 zi = zv[i];
            const float4 a0 = c0[i];
            const float4 a1 = c1[i];
            const float4 a2 = c2[i];
            const float4 a3 = c3[i];
            dot0 += zi.x * a0.x + zi.y * a0.y + zi.z * a0.z + zi.w * a0.w;
            dot1 += zi.x * a1.x + zi.y * a1.y + zi.z * a1.z + zi.w * a1.w;
            dot2 += zi.x * a2.x + zi.y * a2.y + zi.z * a2.z + zi.w * a2.w;
            dot3 += zi.x * a3.x + zi.y * a3.y + zi.z * a3.z + zi.w * a3.w;
        }
        const float d0 = z2 + cnorm[k + 0] - 2.0f * dot0;
        const float d1 = z2 + cnorm[k + 1] - 2.0f * dot1;
        const float d2 = z2 + cnorm[k + 2] - 2.0f * dot2;
        const float d3 = z2 + cnorm[k + 3] - 2.0f * dot3;
        if (d0 < best) { best = d0; bi = k + 0; }
        if (d1 < best) { best = d1; bi = k + 1; }
        if (d2 < best) { best = d2; bi = k + 2; }
        if (d3 < best) { best = d3; bi = k + 3; }
    }
    idx[n] = bi;
    atomicAdd(&hist[bi], 1.0f);
}

__global__ __launch_bounds__(256)
void vq_gather_split(const float* __restrict__ cb, const int* __restrict__ idx,
                     bf16_t* __restrict__ zh, bf16_t* __restrict__ zl)
{
    const int gid = blockIdx.x * 256 + threadIdx.x;
    const int n = gid >> 4, c4 = gid & 15;
    const int k = idx[n];
    const float4 c = reinterpret_cast<const float4*>(cb)[k * 16 + c4];
    ushort4 h, l;
    h.x = f2b(c.x); l.x = f2b(c.x - b2f(h.x));
    h.y = f2b(c.y); l.y = f2b(c.y - b2f(h.y));
    h.z = f2b(c.z); l.z = f2b(c.z - b2f(h.z));
    h.w = f2b(c.w); l.w = f2b(c.w - b2f(h.w));
    reinterpret_cast<ushort4*>(zh)[gid] = h;
    reinterpret_cast<ushort4*>(zl)[gid] = l;
}

__global__ __launch_bounds__(512)
void perplexity_k(const float* __restrict__ hist, float* __restrict__ out, float invN)
{
    __shared__ float red[512];
    const int t = threadIdx.x;
    const float p = hist[t] * invN;
    red[t] = p * logf(p + 1e-12f);
    __syncthreads();
    for (int s = 256; s > 0; s >>= 1) {
        if (t < s) red[t] += red[t + s];
        __syncthreads();
    }
    if (t == 0) out[0] = expf(-red[0]);
}

// ---------------------------------------------------------------------------
extern "C" void kernel_launch(void* const* d_in, const int* in_sizes, int n_in,
                              void* d_out, int out_size, void* d_ws, size_t ws_size,
                              hipStream_t stream)
{
    const float* x       = (const float*)d_in[0];
    const float* ec0_w   = (const float*)d_in[1];
    const float* ec0_b   = (const float*)d_in[2];
    const float* er0_c1w = (const float*)d_in[3];
    const float* er0_c1b = (const float*)d_in[4];
    const float* er0_c2w = (const float*)d_in[5];
    const float* er0_c2b = (const float*)d_in[6];
    const float* er0_g   = (const float*)d_in[7];
    const float* er0_be  = (const float*)d_in[8];
    const float* er0_m   = (const float*)d_in[9];
    const float* er0_v   = (const float*)d_in[10];
    const float* er0_a   = (const float*)d_in[11];
    const float* ec1_w   = (const float*)d_in[12];
    const float* ec1_b   = (const float*)d_in[13];
    const float* er1_c1w = (const float*)d_in[14];
    const float* er1_c1b = (const float*)d_in[15];
    const float* er1_c2w = (const float*)d_in[16];
    const float* er1_c2b = (const float*)d_in[17];
    const float* er1_g   = (const float*)d_in[18];
    const float* er1_be  = (const float*)d_in[19];
    const float* er1_m   = (const float*)d_in[20];
    const float* er1_v   = (const float*)d_in[21];
    const float* er1_a   = (const float*)d_in[22];
    const float* eo_w    = (const float*)d_in[23];
    const float* eo_b    = (const float*)d_in[24];
    const float* eo_a    = (const float*)d_in[25];
    const float* cb      = (const float*)d_in[26];
    const float* dc0_w   = (const float*)d_in[27];
    const float* dc0_b   = (const float*)d_in[28];
    const float* dc0_a   = (const float*)d_in[29];
    const float* dr0_c1w = (const float*)d_in[30];
    const float* dr0_c1b = (const float*)d_in[31];
    const float* dr0_c2w = (const float*)d_in[32];
    const float* dr0_c2b = (const float*)d_in[33];
    const float* dr0_g   = (const float*)d_in[34];
    const float* dr0_be  = (const float*)d_in[35];
    const float* dr0_m   = (const float*)d_in[36];
    const float* dr0_v   = (const float*)d_in[37];
    const float* dr0_a   = (const float*)d_in[38];
    const float* du0_w   = (const float*)d_in[39];
    const float* du0_b   = (const float*)d_in[40];
    const float* dr1_c1w = (const float*)d_in[41];
    const float* dr1_c1b = (const float*)d_in[42];
    const float* dr1_c2w = (const float*)d_in[43];
    const float* dr1_c2b = (const float*)d_in[44];
    const float* dr1_g   = (const float*)d_in[45];
    const float* dr1_be  = (const float*)d_in[46];
    const float* dr1_m   = (const float*)d_in[47];
    const float* dr1_v   = (const float*)d_in[48];
    const float* dr1_a   = (const float*)d_in[49];
    const float* du1_w   = (const float*)d_in[50];
    const float* du1_b   = (const float*)d_in[51];

    float* out = (float*)d_out;

    // ---- ws: A=[0,134MB) , H=[134MB,268MB) ----
    char* W = (char*)d_ws;
    float*  Af  = (float*)(W);
    float*  Hf  = (float*)(W + 134217728);
    float*  E1f = (float*)(W + 134217728);
    float*  R1f = (float*)(W + 134217728 + 33554432);
    float*  Zf  = (float*)(W);
    int*    IDX = (int*)  (W + 16777216);
    float*  CN  = (float*)(W + 17039360);
    float*  HS  = (float*)(W + 17041408);
    bf16_t* ZQh = (bf16_t*)(W + 33554432);
    bf16_t* ZQl = (bf16_t*)(W + 41943040);
    bf16_t* D0h = (bf16_t*)(W + 50331648);
    bf16_t* D0l = (bf16_t*)(W + 67108864);
    bf16_t* Gh  = (bf16_t*)(W + 83886080);
    bf16_t* Gl  = (bf16_t*)(W + 100663296);
    bf16_t* U0h = (bf16_t*)(W + 134217728);
    bf16_t* U0l = (bf16_t*)(W + 201326592);
    bf16_t* G1h = (bf16_t*)(W);
    bf16_t* G1l = (bf16_t*)(W + 67108864);

    // ---- weight arenas in d_out ----
    char* WB = (char*)d_out;
    bf16_t* e0c1h = (bf16_t*)(WB + 0);
    bf16_t* e0c1m = (bf16_t*)(WB + 221184);
    bf16_t* e0c1l = (bf16_t*)(WB + 442368);
    bf16_t* e0c2h = (bf16_t*)(WB + 663552);
    bf16_t* e0c2m = (bf16_t*)(WB + 884736);
    bf16_t* e0c2l = (bf16_t*)(WB + 1105920);
    bf16_t* ec1h  = (bf16_t*)(WB + 1327104);
    bf16_t* ec1m  = (bf16_t*)(WB + 2375680);
    bf16_t* ec1l  = (bf16_t*)(WB + 3424256);
    bf16_t* e1c1h = (bf16_t*)(WB + 4472832);
    bf16_t* e1c1m = (bf16_t*)(WB + 5357568);
    bf16_t* e1c1l = (bf16_t*)(WB + 6242304);
    bf16_t* e1c2h = (bf16_t*)(WB + 7127040);
    bf16_t* e1c2m = (bf16_t*)(WB + 8011776);
    bf16_t* e1c2l = (bf16_t*)(WB + 8896512);
    bf16_t* eoh   = (bf16_t*)(WB + 9781248);
    bf16_t* eom   = (bf16_t*)(WB + 10223616);
    bf16_t* eol   = (bf16_t*)(WB + 10665984);
    bf16_t* wec0h = (bf16_t*)(WB + 11108352);
    bf16_t* wec0m = (bf16_t*)(WB + 11116544);
    bf16_t* wec0l = (bf16_t*)(WB + 11124736);
    bf16_t* dc0h  = (bf16_t*)(WB + 0);
    bf16_t* dc0l  = (bf16_t*)(WB + 442368);
    bf16_t* d0c1h = (bf16_t*)(WB + 884736);
    bf16_t* d0c1l = (bf16_t*)(WB + 1769472);
    bf16_t* d0c2h = (bf16_t*)(WB + 2654208);
    bf16_t* d0c2l = (bf16_t*)(WB + 3538944);
    bf16_t* du0h  = (bf16_t*)(WB + 4423680);
    bf16_t* du0l  = (bf16_t*)(WB + 5472256);
    bf16_t* d1c1h = (bf16_t*)(WB + 6520832);
    bf16_t* d1c1l = (bf16_t*)(WB + 6742016);
    bf16_t* d1c2h = (bf16_t*)(WB + 6963200);
    bf16_t* d1c2l = (bf16_t*)(WB + 7184384);

    const float* fn = nullptr;
    const bf16_t* bn_ = nullptr;

    // ---- encoder weight prep (split-3, fragment-major) ----
    wprep3<<<16, 256, 0, stream>>>(ec0_w, wec0h, wec0m, wec0l, 64, 64, 4096);
    wprep3<<<432, 256, 0, stream>>>(er0_c1w, e0c1h, e0c1m, e0c1l, 64, 64, 110592);
    wprep3<<<432, 256, 0, stream>>>(er0_c2w, e0c2h, e0c2m, e0c2l, 64, 64, 110592);
    wprep3<<<2048, 256, 0, stream>>>(ec1_w, ec1h, ec1m, ec1l, 64, 128, 524288);
    wprep3<<<1728, 256, 0, stream>>>(er1_c1w, e1c1h, e1c1m, e1c1l, 128, 128, 442368);
    wprep3<<<1728, 256, 0, stream>>>(er1_c2w, e1c2h, e1c2m, e1c2l, 128, 128, 442368);
    wprep3<<<864, 256, 0, stream>>>(eo_w, eoh, eom, eol, 128, 64, 221184);

    // ---- encoder (fp32-class) ----
    conv_ec0m<<<8192, 128, 0, stream>>>(x, wec0h, wec0m, wec0l, ec0_b, Af);

    conv3e<64, 64, 64, 2, 1><<<8192, 256, 0, stream>>>(
        Af, e0c1h, e0c1m, e0c1l, er0_c1b, fn, fn, fn, fn, fn, fn, Hf);
    conv3e<64, 64, 64, 2, 3><<<8192, 256, 0, stream>>>(
        Hf, e0c2h, e0c2m, e0c2l, er0_c2b, er0_g, er0_be, er0_m, er0_v, er0_a, Af, Af);

    convs2e<<<2048, 256, 0, stream>>>(Af, ec1h, ec1m, ec1l, ec1_b, E1f);

    conv3e<128, 128, 32, 4, 1><<<2048, 256, 0, stream>>>(
        E1f, e1c1h, e1c1m, e1c1l, er1_c1b, fn, fn, fn, fn, fn, fn, R1f);
    conv3e<128, 128, 32, 4, 3><<<2048, 256, 0, stream>>>(
        R1f, e1c2h, e1c2m, e1c2l, er1_c2b, er1_g, er1_be, er1_m, er1_v, er1_a, E1f, E1f);

    conv3e<128, 64, 32, 2, 2><<<2048, 128, 0, stream>>>(
        E1f, eoh, eom, eol, eo_b, fn, fn, fn, fn, eo_a, fn, Zf);

    // ---- VQ (exact fp32, ILP assign) ----
    vq_cnorm<<<8, 64, 0, stream>>>(cb, CN);
    zero512<<<1, 512, 0, stream>>>(HS);
    vq_assign<<<256, 256, 0, stream>>>(Zf, cb, CN, IDX, HS, 65536);
    perplexity_k<<<1, 512, 0, stream>>>(HS, out + 4194304, 1.0f / 65536.0f);
    vq_gather_split<<<4096, 256, 0, stream>>>(cb, IDX, ZQh, ZQl);

    // ---- decoder weight prep (split-2, fragment-major, overwrites arena) ----
    wprep_split<<<864, 256, 0, stream>>>(dc0_w, dc0h, dc0l, 64, 128, 221184);
    wprep_split<<<1728, 256, 0, stream>>>(dr0_c1w, d0c1h, d0c1l, 128, 128, 442368);
    wprep_split<<<1728, 256, 0, stream>>>(dr0_c2w, d0c2h, d0c2l, 128, 128, 442368);
    wprep_split<<<2048, 256, 0, stream>>>(du0_w, du0h, du0l, 128, 64, 524288);
    wprep_split<<<432, 256, 0, stream>>>(dr1_c1w, d1c1h, d1c1l, 64, 64, 110592);
    wprep_split<<<432, 256, 0, stream>>>(dr1_c2w, d1c2h, d1c2l, 64, 64, 110592);

    // ---- decoder (split-2 bf16) ----
    conv3d<64, 128, 32, 4, 2><<<2048, 256, 0, stream>>>(
        ZQh, ZQl, dc0h, dc0l, dc0_b, fn, fn, fn, fn, dc0_a, bn_, bn_, D0h, D0l);
    conv3d<128, 128, 32, 4, 1><<<2048, 256, 0, stream>>>(
        D0h, D0l, d0c1h, d0c1l, dr0_c1b, fn, fn, fn, fn, fn, bn_, bn_, Gh, Gl);
    conv3d<128, 128, 32, 4, 3><<<2048, 256, 0, stream>>>(
        Gh, Gl, d0c2h, d0c2l, dr0_c2b, dr0_g, dr0_be, dr0_m, dr0_v, dr0_a,
        D0h, D0l, D0h, D0l);

    convTm<<<8192, 256, 0, stream>>>(D0h, D0l, du0h, du0l, du0_b, U0h, U0l);

    conv3d<64, 64, 64, 2, 1><<<8192, 256, 0, stream>>>(
        U0h, U0l, d1c1h, d1c1l, dr1_c1b, fn, fn, fn, fn, fn, bn_, bn_, G1h, G1l);
    conv3d<64, 64, 64, 2, 3><<<8192, 256, 0, stream>>>(
        G1h, G1l, d1c2h, d1c2l, dr1_c2b, dr1_g, dr1_be, dr1_m, dr1_v, dr1_a,
        U0h, U0l, U0h, U0l);

    convT_du1w<<<65536, 256, 0, stream>>>(U0h, U0l, du1_w, du1_b, out);
}

// Round 18
// 5127.053 us; speedup vs baseline: 1.1908x; 1.0098x over previous
//
#include <hip/hip_runtime.h>
#include <cstdint>

// ---------------------------------------------------------------------------
// VQVAE forward — MFMA implicit-GEMM convolutions, channels-last.
//
// Round-18 = round-17 + DOUBLE-BUFFERED LDS, ONE barrier per row-iter.
//   Writes at iter i go to buf[(i+1)&1]; reads from buf[i&1] (disjoint) =>
//   the read-side barrier is gone. Single end-of-iter barrier orders both
//   "writes visible next iter" and "reads done before overwrite (2 iters)".
//   Per-iter schedule: writerow(other) [vmcnt hidden: loads issued 1 iter
//   earlier] -> issue loadrow(i+2) -> pure-MFMA phase -> 1 barrier.
//   Attacks the 2-barrier m97-structure ceiling (MfmaUtil pinned at 47%,
//   ~26% cycles in barrier drains). Numerics bit-identical.
//   - Encoder: fp32 activations; EXACT 3-way bf16 split at LDS-stage time;
//     6-MFMA products => fp32-class => VQ argmin safe.
//   - Decoder: split-2 bf16 storage, 3-pass MFMA.
//   - vq_assign: uniform-k, 4 independent dot chains (round-15, proven).
// Retained: zero-padded LDS rows, 4-wave blocks (32 couts/wave), fragment-
// major weights, T1 XCD-chunked swizzle, LDS XOR swizzle, MFMA ec0,
// wave-level du1.
//
// C layout: col = lane&31, row = (reg&3) + 8*(reg>>2) + 4*(lane>>5)
// ---------------------------------------------------------------------------

typedef unsigned short bf16_t;
typedef __attribute__((ext_vector_type(8)))  short s8b;     // 8 x bf16 frag
typedef __attribute__((ext_vector_type(16))) float f32x16;  // 32x32 acc

__device__ __forceinline__ float b2f(bf16_t u) { return __uint_as_float((unsigned)u << 16); }
__device__ __forceinline__ bf16_t f2b(float f) {
    unsigned x = __float_as_uint(f);
    return (bf16_t)((x + 0x7FFFu + ((x >> 16) & 1u)) >> 16);
}

__device__ __forceinline__ void split3s(float v, unsigned short& h,
                                        unsigned short& m, unsigned short& l)
{
    const unsigned uv = __float_as_uint(v);
    const float fh = __uint_as_float(uv & 0xFFFF0000u);
    const float r1 = v - fh;
    const unsigned u1 = __float_as_uint(r1);
    const float fm = __uint_as_float(u1 & 0xFFFF0000u);
    const float r2 = r1 - fm;
    h = (unsigned short)(uv >> 16);
    m = (unsigned short)(u1 >> 16);
    l = (unsigned short)(__float_as_uint(r2) >> 16);
}

// ------------------------- weight prep ------------------------------------
// src [tap][ci][co] fp32 -> dst fragment-major [tap][ks][half][co][8k]
__device__ __forceinline__ int wdst(int tap, int ci_, int co_, int ci, int co)
{
    const int ks = ci_ >> 4, half = (ci_ >> 3) & 1, j = ci_ & 7;
    return (((tap * (ci >> 4) + ks) * 2 + half) * co + co_) * 8 + j;
}

__global__ __launch_bounds__(256)
void wprep3(const float* __restrict__ w, bf16_t* __restrict__ h,
            bf16_t* __restrict__ m, bf16_t* __restrict__ l,
            int ci, int co, int n)
{
    const int i = blockIdx.x * 256 + threadIdx.x;
    if (i >= n) return;
    const int co_ = i % co;
    const int ci_ = (i / co) % ci;
    const int tap = i / (co * ci);
    const int dst = wdst(tap, ci_, co_, ci, co);
    unsigned short hh, mm, ll2;
    split3s(w[i], hh, mm, ll2);
    h[dst] = hh; m[dst] = mm; l[dst] = ll2;
}

__global__ __launch_bounds__(256)
void wprep_split(const float* __restrict__ w, bf16_t* __restrict__ hi,
                 bf16_t* __restrict__ lo, int ci, int co, int n)
{
    const int i = blockIdx.x * 256 + threadIdx.x;
    if (i >= n) return;
    const int co_ = i % co;
    const int ci_ = (i / co) % ci;
    const int tap = i / (co * ci);
    const float v = w[i];
    const int dst = wdst(tap, ci_, co_, ci, co);
    const bf16_t h = f2b(v);
    hi[dst] = h;
    lo[dst] = f2b(v - b2f(h));
}

// ---------------- encoder 3x3x3 conv: fp32 in, dbuf LDS, split-3 ------------
// NWC = COUT/32 waves in N. EPI: 0=ReLU 1=swish 2=PReLU 3=BN+PReLU+skip+ReLU
template<int CIN, int COUT, int SD, int NWC, int EPI>
__global__ __launch_bounds__((SD / 32) * NWC * 64)
void conv3e(const float* __restrict__ xf,
            const bf16_t* __restrict__ wh, const bf16_t* __restrict__ wm,
            const bf16_t* __restrict__ wl,
            const float* __restrict__ bias,
            const float* __restrict__ g, const float* __restrict__ be,
            const float* __restrict__ mn, const float* __restrict__ vr,
            const float* __restrict__ al,
            const float* skf, float* __restrict__ of)
{
    constexpr int NT = (SD / 32) * NWC * 64;
    constexpr int LP = (SD * CIN) / (4 * NT);
    constexpr int KS = CIN / 16;
    constexpr int RB = (SD + 2) * CIN;
    __shared__ bf16_t lh[2][RB], lm[2][RB], ll[2][RB];

    const int tid  = threadIdx.x;
    const int lane = tid & 63;
    const int wid  = tid >> 6;
    const int wn   = wid % NWC, wm2 = wid / NWC;
    const int half = lane >> 5, ln = lane & 31;
    const int w    = wm2 * 32 + ln;
    const int nwg  = gridDim.x;
    const int bid  = (blockIdx.x & 7) * (nwg >> 3) + (blockIdx.x >> 3);
    const int h    = bid % SD;
    const int d    = (bid / SD) % SD;
    const int b    = bid / (SD * SD);
    const int cout = wn * 32 + ln;

    int pz[9], py[9], pt[9], np = 0;
    for (int kd = 0; kd < 3; ++kd) {
        const int iz = d + kd - 1;
        if ((unsigned)iz >= (unsigned)SD) continue;
        for (int kh = 0; kh < 3; ++kh) {
            const int iy = h + kh - 1;
            if ((unsigned)iy >= (unsigned)SD) continue;
            pz[np] = iz; py[np] = iy; pt[np] = (kd * 3 + kh) * 3; ++np;
        }
    }

    f32x16 accA, accB;
#pragma unroll
    for (int i = 0; i < 16; ++i) { accA[i] = 0.f; accB[i] = 0.f; }

    // zero pads (pv=0 and pv=SD+1) in BOTH buffers, once
    for (int i = tid; i < CIN; i += NT) {
        const int bf2 = i / (CIN / 2);
        const int rem = i % (CIN / 2);
        const int pv = (rem < CIN / 4) ? 0 : (SD + 1);
        const int ch = (rem % (CIN / 4)) * 4;
        const int bo = ((pv * CIN + ch) * 2) ^ ((pv & 7) << 4);
        const ushort4 z4 = make_ushort4(0, 0, 0, 0);
        *reinterpret_cast<ushort4*>((char*)&lh[bf2][0] + bo) = z4;
        *reinterpret_cast<ushort4*>((char*)&lm[bf2][0] + bo) = z4;
        *reinterpret_cast<ushort4*>((char*)&ll[bf2][0] + bo) = z4;
    }

    float4 rg[LP];
    auto loadrow = [&](int iz, int iy) {
        const float* src = xf + ((size_t)((b * SD + iz) * SD + iy)) * SD * CIN;
#pragma unroll
        for (int j = 0; j < LP; ++j)
            rg[j] = *reinterpret_cast<const float4*>(src + (size_t)(tid + j * NT) * 4);
    };
    auto writerow = [&](int bf2) {
#pragma unroll
        for (int j = 0; j < LP; ++j) {
            const int idx = (tid + j * NT) * 4;
            const int pv = idx / CIN + 1, ch = idx % CIN;
            ushort4 h4, m4, l4;
            split3s(rg[j].x, h4.x, m4.x, l4.x);
            split3s(rg[j].y, h4.y, m4.y, l4.y);
            split3s(rg[j].z, h4.z, m4.z, l4.z);
            split3s(rg[j].w, h4.w, m4.w, l4.w);
            const int bo = ((pv * CIN + ch) * 2) ^ ((pv & 7) << 4);
            *reinterpret_cast<ushort4*>((char*)&lh[bf2][0] + bo) = h4;
            *reinterpret_cast<ushort4*>((char*)&lm[bf2][0] + bo) = m4;
            *reinterpret_cast<ushort4*>((char*)&ll[bf2][0] + bo) = l4;
        }
    };

    loadrow(pz[0], py[0]);
    writerow(0);
    if (np > 1) loadrow(pz[1], py[1]);
    __syncthreads();
#pragma unroll 1
    for (int i = 0; i < np; ++i) {
        const int cur = i & 1;
        if (i + 1 < np) writerow((i + 1) & 1);          // vmcnt hidden (1 iter old)
        if (i + 2 < np) loadrow(pz[i + 2], py[i + 2]);  // issue early (T14)
#pragma unroll
        for (int kw = 0; kw < 3; ++kw) {
            const int tap = pt[i] + kw;
            const int pv = w + kw;
#pragma unroll
            for (int ks = 0; ks < KS; ++ks) {
                const int bo = ((pv * CIN + half * 8 + ks * 16) * 2) ^ ((pv & 7) << 4);
                const s8b ah  = *reinterpret_cast<const s8b*>((const char*)&lh[cur][0] + bo);
                const s8b am  = *reinterpret_cast<const s8b*>((const char*)&lm[cur][0] + bo);
                const s8b al3 = *reinterpret_cast<const s8b*>((const char*)&ll[cur][0] + bo);
                const size_t wb = ((size_t)((tap * KS + ks) * 2 + half) * COUT + cout) * 8;
                const s8b bh = *reinterpret_cast<const s8b*>(wh + wb);
                const s8b bm = *reinterpret_cast<const s8b*>(wm + wb);
                const s8b bl = *reinterpret_cast<const s8b*>(wl + wb);
                accA = __builtin_amdgcn_mfma_f32_32x32x16_bf16(ah, bh, accA, 0, 0, 0);
                accB = __builtin_amdgcn_mfma_f32_32x32x16_bf16(ah, bm, accB, 0, 0, 0);
                accA = __builtin_amdgcn_mfma_f32_32x32x16_bf16(am, bh, accA, 0, 0, 0);
                accB = __builtin_amdgcn_mfma_f32_32x32x16_bf16(am, bm, accB, 0, 0, 0);
                accA = __builtin_amdgcn_mfma_f32_32x32x16_bf16(al3, bh, accA, 0, 0, 0);
                accB = __builtin_amdgcn_mfma_f32_32x32x16_bf16(ah, bl, accB, 0, 0, 0);
            }
        }
        __syncthreads();              // single barrier per iter
    }

    const size_t outrow = ((size_t)((b * SD + d) * SD + h)) * SD;
    const float bv = bias[cout];
    float sc = 0.f, mm = 0.f, bb2 = 0.f, aa = 0.f;
    if constexpr (EPI == 3) {
        sc = g[cout] * (1.0f / sqrtf(vr[cout] + 1e-3f));
        mm = mn[cout]; bb2 = be[cout]; aa = al[cout];
    }
    if constexpr (EPI == 2) aa = al[cout];
#pragma unroll
    for (int r = 0; r < 16; ++r) {
        const int rl = (r & 3) + 8 * (r >> 2) + 4 * half;
        const size_t oe = (outrow + wm2 * 32 + rl) * COUT + cout;
        float y = accA[r] + accB[r] + bv;
        if constexpr (EPI == 0) y = fmaxf(y, 0.f);
        else if constexpr (EPI == 1) y = y / (1.f + expf(-y));
        else if constexpr (EPI == 2) y = y > 0.f ? y : aa * y;
        else {
            float t2 = (y - mm) * sc + bb2;
            t2 = t2 > 0.f ? t2 : aa * t2;
            y = fmaxf(skf[oe] + t2, 0.f);
        }
        of[oe] = y;
    }
}

// ---------------- ec1: stride-2 k=4, fp32 in, dbuf LDS, split-3 -------------
__global__ __launch_bounds__(256)
void convs2e(const float* __restrict__ xf,
             const bf16_t* __restrict__ wh, const bf16_t* __restrict__ wm,
             const bf16_t* __restrict__ wl,
             const float* __restrict__ bias, float* __restrict__ of)
{
    constexpr int NT = 256, LP = (64 * 64) / (4 * NT);
    __shared__ bf16_t lh[2][66 * 64], lm[2][66 * 64], ll[2][66 * 64];

    const int tid  = threadIdx.x;
    const int lane = tid & 63;
    const int wn   = tid >> 6;
    const int half = lane >> 5, ln = lane & 31;
    const int nwg  = gridDim.x;
    const int bid  = (blockIdx.x & 7) * (nwg >> 3) + (blockIdx.x >> 3);
    const int h    = bid % 32;
    const int d    = (bid / 32) % 32;
    const int b    = bid / 1024;
    const int cout = wn * 32 + ln;

    int pz[16], py[16], pt[16], np = 0;
    for (int kd = 0; kd < 4; ++kd) {
        const int iz = 2 * d + kd - 1;
        if ((unsigned)iz >= 64u) continue;
        for (int kh = 0; kh < 4; ++kh) {
            const int iy = 2 * h + kh - 1;
            if ((unsigned)iy >= 64u) continue;
            pz[np] = iz; py[np] = iy; pt[np] = (kd * 4 + kh) * 4; ++np;
        }
    }

    f32x16 accA, accB;
#pragma unroll
    for (int i = 0; i < 16; ++i) { accA[i] = 0.f; accB[i] = 0.f; }

    for (int i = tid; i < 64; i += NT) {
        const int bf2 = i / 32;
        const int rem = i % 32;
        const int pv = (rem < 16) ? 0 : 65;
        const int ch = (rem % 16) * 4;
        const int bo = ((pv * 64 + ch) * 2) ^ ((pv & 7) << 4);
        const ushort4 z4 = make_ushort4(0, 0, 0, 0);
        *reinterpret_cast<ushort4*>((char*)&lh[bf2][0] + bo) = z4;
        *reinterpret_cast<ushort4*>((char*)&lm[bf2][0] + bo) = z4;
        *reinterpret_cast<ushort4*>((char*)&ll[bf2][0] + bo) = z4;
    }

    float4 rg[LP];
    auto loadrow = [&](int iz, int iy) {
        const float* src = xf + ((size_t)((b * 64 + iz) * 64 + iy)) * 64 * 64;
#pragma unroll
        for (int j = 0; j < LP; ++j)
            rg[j] = *reinterpret_cast<const float4*>(src + (size_t)(tid + j * NT) * 4);
    };
    auto writerow = [&](int bf2) {
#pragma unroll
        for (int j = 0; j < LP; ++j) {
            const int idx = (tid + j * NT) * 4;
            const int pv = idx / 64 + 1, ch = idx % 64;
            ushort4 h4, m4, l4;
            split3s(rg[j].x, h4.x, m4.x, l4.x);
            split3s(rg[j].y, h4.y, m4.y, l4.y);
            split3s(rg[j].z, h4.z, m4.z, l4.z);
            split3s(rg[j].w, h4.w, m4.w, l4.w);
            const int bo = ((pv * 64 + ch) * 2) ^ ((pv & 7) << 4);
            *reinterpret_cast<ushort4*>((char*)&lh[bf2][0] + bo) = h4;
            *reinterpret_cast<ushort4*>((char*)&lm[bf2][0] + bo) = m4;
            *reinterpret_cast<ushort4*>((char*)&ll[bf2][0] + bo) = l4;
        }
    };

    loadrow(pz[0], py[0]);
    writerow(0);
    if (np > 1) loadrow(pz[1], py[1]);
    __syncthreads();
#pragma unroll 1
    for (int i = 0; i < np; ++i) {
        const int cur = i & 1;
        if (i + 1 < np) writerow((i + 1) & 1);
        if (i + 2 < np) loadrow(pz[i + 2], py[i + 2]);
#pragma unroll
        for (int kw = 0; kw < 4; ++kw) {
            const int tap = pt[i] + kw;
            const int pv = 2 * ln + kw;
#pragma unroll
            for (int ks = 0; ks < 4; ++ks) {
                const int bo = ((pv * 64 + half * 8 + ks * 16) * 2) ^ ((pv & 7) << 4);
                const s8b ah  = *reinterpret_cast<const s8b*>((const char*)&lh[cur][0] + bo);
                const s8b am  = *reinterpret_cast<const s8b*>((const char*)&lm[cur][0] + bo);
                const s8b al3 = *reinterpret_cast<const s8b*>((const char*)&ll[cur][0] + bo);
                const size_t wb = ((size_t)((tap * 4 + ks) * 2 + half) * 128 + cout) * 8;
                const s8b bh = *reinterpret_cast<const s8b*>(wh + wb);
                const s8b bm = *reinterpret_cast<const s8b*>(wm + wb);
                const s8b bl = *reinterpret_cast<const s8b*>(wl + wb);
                accA = __builtin_amdgcn_mfma_f32_32x32x16_bf16(ah, bh, accA, 0, 0, 0);
                accB = __builtin_amdgcn_mfma_f32_32x32x16_bf16(ah, bm, accB, 0, 0, 0);
                accA = __builtin_amdgcn_mfma_f32_32x32x16_bf16(am, bh, accA, 0, 0, 0);
                accB = __builtin_amdgcn_mfma_f32_32x32x16_bf16(am, bm, accB, 0, 0, 0);
                accA = __builtin_amdgcn_mfma_f32_32x32x16_bf16(al3, bh, accA, 0, 0, 0);
                accB = __builtin_amdgcn_mfma_f32_32x32x16_bf16(ah, bl, accB, 0, 0, 0);
            }
        }
        __syncthreads();
    }

    const size_t outrow = ((size_t)((b * 32 + d) * 32 + h)) * 32;
    const float bv = bias[cout];
#pragma unroll
    for (int r = 0; r < 16; ++r) {
        const int rl = (r & 3) + 8 * (r >> 2) + 4 * half;
        const size_t oe = (outrow + rl) * 128 + cout;
        of[oe] = fmaxf(accA[r] + accB[r] + bv, 0.f);
    }
}

// ---------------- decoder 3x3x3 conv: split-2 bf16, dbuf LDS ----------------
template<int CIN, int COUT, int SD, int NWC, int EPI>
__global__ __launch_bounds__((SD / 32) * NWC * 64)
void conv3d(const bf16_t* __restrict__ xh, const bf16_t* __restrict__ xl,
            const bf16_t* __restrict__ wh, const bf16_t* __restrict__ wl,
            const float* __restrict__ bias,
            const float* __restrict__ g, const float* __restrict__ be,
            const float* __restrict__ mn, const float* __restrict__ vr,
            const float* __restrict__ al,
            const bf16_t* skh, const bf16_t* skl,
            bf16_t* oh, bf16_t* ol)
{
    constexpr int NT = (SD / 32) * NWC * 64;
    constexpr int LP = (SD * CIN) / (4 * NT);
    constexpr int KS = CIN / 16;
    constexpr int RB = (SD + 2) * CIN;
    __shared__ bf16_t lh[2][RB], ll[2][RB];

    const int tid  = threadIdx.x;
    const int lane = tid & 63;
    const int wid  = tid >> 6;
    const int wn   = wid % NWC, wm2 = wid / NWC;
    const int half = lane >> 5, ln = lane & 31;
    const int w    = wm2 * 32 + ln;
    const int nwg  = gridDim.x;
    const int bid  = (blockIdx.x & 7) * (nwg >> 3) + (blockIdx.x >> 3);
    const int h    = bid % SD;
    const int d    = (bid / SD) % SD;
    const int b    = bid / (SD * SD);
    const int cout = wn * 32 + ln;

    int pz[9], py[9], pt[9], np = 0;
    for (int kd = 0; kd < 3; ++kd) {
        const int iz = d + kd - 1;
        if ((unsigned)iz >= (unsigned)SD) continue;
        for (int kh = 0; kh < 3; ++kh) {
            const int iy = h + kh - 1;
            if ((unsigned)iy >= (unsigned)SD) continue;
            pz[np] = iz; py[np] = iy; pt[np] = (kd * 3 + kh) * 3; ++np;
        }
    }

    f32x16 accA, accB;
#pragma unroll
    for (int i = 0; i < 16; ++i) { accA[i] = 0.f; accB[i] = 0.f; }

    for (int i = tid; i < CIN; i += NT) {
        const int bf2 = i / (CIN / 2);
        const int rem = i % (CIN / 2);
        const int pv = (rem < CIN / 4) ? 0 : (SD + 1);
        const int ch = (rem % (CIN / 4)) * 4;
        const int bo = ((pv * CIN + ch) * 2) ^ ((pv & 7) << 4);
        const ushort4 z4 = make_ushort4(0, 0, 0, 0);
        *reinterpret_cast<ushort4*>((char*)&lh[bf2][0] + bo) = z4;
        *reinterpret_cast<ushort4*>((char*)&ll[bf2][0] + bo) = z4;
    }

    ushort4 rh[LP], rl2a[LP];
    auto loadrow = [&](int iz, int iy) {
        const size_t rb = ((size_t)((b * SD + iz) * SD + iy)) * SD * CIN;
#pragma unroll
        for (int j = 0; j < LP; ++j) {
            const int idx = (tid + j * NT) * 4;
            rh[j]   = *reinterpret_cast<const ushort4*>(xh + rb + idx);
            rl2a[j] = *reinterpret_cast<const ushort4*>(xl + rb + idx);
        }
    };
    auto writerow = [&](int bf2) {
#pragma unroll
        for (int j = 0; j < LP; ++j) {
            const int idx = (tid + j * NT) * 4;
            const int pv = idx / CIN + 1, ch = idx % CIN;
            const int bo = ((pv * CIN + ch) * 2) ^ ((pv & 7) << 4);
            *reinterpret_cast<ushort4*>((char*)&lh[bf2][0] + bo) = rh[j];
            *reinterpret_cast<ushort4*>((char*)&ll[bf2][0] + bo) = rl2a[j];
        }
    };

    loadrow(pz[0], py[0]);
    writerow(0);
    if (np > 1) loadrow(pz[1], py[1]);
    __syncthreads();
#pragma unroll 1
    for (int i = 0; i < np; ++i) {
        const int cur = i & 1;
        if (i + 1 < np) writerow((i + 1) & 1);
        if (i + 2 < np) loadrow(pz[i + 2], py[i + 2]);
#pragma unroll
        for (int kw = 0; kw < 3; ++kw) {
            const int tap = pt[i] + kw;
            const int pv = w + kw;
#pragma unroll
            for (int ks = 0; ks < KS; ++ks) {
                const int bo = ((pv * CIN + half * 8 + ks * 16) * 2) ^ ((pv & 7) << 4);
                const s8b ah  = *reinterpret_cast<const s8b*>((const char*)&lh[cur][0] + bo);
                const s8b al2 = *reinterpret_cast<const s8b*>((const char*)&ll[cur][0] + bo);
                const size_t wb = ((size_t)((tap * KS + ks) * 2 + half) * COUT + cout) * 8;
                const s8b bh = *reinterpret_cast<const s8b*>(wh + wb);
                const s8b bl = *reinterpret_cast<const s8b*>(wl + wb);
                accA = __builtin_amdgcn_mfma_f32_32x32x16_bf16(ah, bh, accA, 0, 0, 0);
                accB = __builtin_amdgcn_mfma_f32_32x32x16_bf16(al2, bh, accB, 0, 0, 0);
                accB = __builtin_amdgcn_mfma_f32_32x32x16_bf16(ah, bl, accB, 0, 0, 0);
            }
        }
        __syncthreads();
    }

    const size_t outrow = ((size_t)((b * SD + d) * SD + h)) * SD;
    const float bv = bias[cout];
    float sc = 0.f, mm = 0.f, bb2 = 0.f, aa = 0.f;
    if constexpr (EPI == 3) {
        sc = g[cout] * (1.0f / sqrtf(vr[cout] + 1e-3f));
        mm = mn[cout]; bb2 = be[cout]; aa = al[cout];
    }
    if constexpr (EPI == 2) aa = al[cout];
#pragma unroll
    for (int r = 0; r < 16; ++r) {
        const int rl3 = (r & 3) + 8 * (r >> 2) + 4 * half;
        const size_t oe = (outrow + wm2 * 32 + rl3) * COUT + cout;
        float y = accA[r] + accB[r] + bv;
        if constexpr (EPI == 0) y = fmaxf(y, 0.f);
        else if constexpr (EPI == 1) y = y / (1.f + expf(-y));
        else if constexpr (EPI == 2) y = y > 0.f ? y : aa * y;
        else {
            float t2 = (y - mm) * sc + bb2;
            t2 = t2 > 0.f ? t2 : aa * t2;
            float sv = b2f(skh[oe]) + b2f(skl[oe]);
            y = fmaxf(sv + t2, 0.f);
        }
        const bf16_t hh = f2b(y);
        oh[oe] = hh;
        ol[oe] = f2b(y - b2f(hh));
    }
}

// ---------------- convT stride-2 k=4 (du0, split-2, dbuf LDS) ---------------
__global__ __launch_bounds__(256)
void convTm(const bf16_t* __restrict__ xh, const bf16_t* __restrict__ xl,
            const bf16_t* __restrict__ wh, const bf16_t* __restrict__ wl,
            const float* __restrict__ bias,
            bf16_t* __restrict__ oh, bf16_t* __restrict__ ol)
{
    constexpr int NT = 256, LP = (32 * 128) / (4 * NT);
    __shared__ bf16_t lh[2][34 * 128], ll[2][34 * 128];

    const int tid  = threadIdx.x;
    const int lane = tid & 63;
    const int wid  = tid >> 6;
    const int wn   = wid & 1, p = wid >> 1;
    const int half = lane >> 5, ln = lane & 31;
    const int nwg  = gridDim.x;
    const int bid  = (blockIdx.x & 7) * (nwg >> 3) + (blockIdx.x >> 3);
    const int ohh  = bid % 64;
    const int od   = (bid / 64) % 64;
    const int b    = bid / 4096;
    const int pd = od & 1, dz = od >> 1;
    const int ph = ohh & 1, hy = ohh >> 1;
    const int cout = wn * 32 + ln;

    int pz[4], py[4], pt[4], np = 0;
    for (int jd = 0; jd < 2; ++jd) {
        const int kd = pd + 2 * jd;
        const int iz = dz + pd - 1 + jd;
        if ((unsigned)iz >= 32u) continue;
        for (int jh = 0; jh < 2; ++jh) {
            const int kh = ph + 2 * jh;
            const int iy = hy + ph - 1 + jh;
            if ((unsigned)iy >= 32u) continue;
            pz[np] = iz; py[np] = iy; pt[np] = (kd * 4 + kh) * 4; ++np;
        }
    }

    f32x16 accA, accB;
#pragma unroll
    for (int i = 0; i < 16; ++i) { accA[i] = 0.0f; accB[i] = 0.0f; }

    for (int i = tid; i < 128; i += NT) {
        const int bf2 = i / 64;
        const int rem = i % 64;
        const int pv = (rem < 32) ? 0 : 33;
        const int ch = (rem % 32) * 4;
        const int bo = ((pv * 128 + ch) * 2) ^ ((pv & 7) << 4);
        const ushort4 z4 = make_ushort4(0, 0, 0, 0);
        *reinterpret_cast<ushort4*>((char*)&lh[bf2][0] + bo) = z4;
        *reinterpret_cast<ushort4*>((char*)&ll[bf2][0] + bo) = z4;
    }

    ushort4 rh[LP], rl2a[LP];
    auto loadrow = [&](int iz, int iy) {
        const size_t rb = ((size_t)((b * 32 + iz) * 32 + iy)) * 32 * 128;
#pragma unroll
        for (int j = 0; j < LP; ++j) {
            const int idx = (tid + j * NT) * 4;
            rh[j]   = *reinterpret_cast<const ushort4*>(xh + rb + idx);
            rl2a[j] = *reinterpret_cast<const ushort4*>(xl + rb + idx);
        }
    };
    auto writerow = [&](int bf2) {
#pragma unroll
        for (int j = 0; j < LP; ++j) {
            const int idx = (tid + j * NT) * 4;
            const int pv = idx / 128 + 1, ch = idx % 128;
            const int bo = ((pv * 128 + ch) * 2) ^ ((pv & 7) << 4);
            *reinterpret_cast<ushort4*>((char*)&lh[bf2][0] + bo) = rh[j];
            *reinterpret_cast<ushort4*>((char*)&ll[bf2][0] + bo) = rl2a[j];
        }
    };

    loadrow(pz[0], py[0]);
    writerow(0);
    if (np > 1) loadrow(pz[1], py[1]);
    __syncthreads();
#pragma unroll 1
    for (int i = 0; i < np; ++i) {
        const int cur = i & 1;
        if (i + 1 < np) writerow((i + 1) & 1);
        if (i + 2 < np) loadrow(pz[i + 2], py[i + 2]);
#pragma unroll
        for (int jw = 0; jw < 2; ++jw) {
            const int kw = p + 2 * jw;
            const int tap = pt[i] + kw;
            const int pv = ln + p + jw;                 // padded 0..33
#pragma unroll
            for (int ks = 0; ks < 8; ++ks) {
                const int bo = ((pv * 128 + half * 8 + ks * 16) * 2) ^ ((pv & 7) << 4);
                const s8b a  = *reinterpret_cast<const s8b*>((const char*)&lh[cur][0] + bo);
                const s8b a2 = *reinterpret_cast<const s8b*>((const char*)&ll[cur][0] + bo);
                const size_t wb = ((size_t)((tap * 8 + ks) * 2 + half) * 64 + cout) * 8;
                const s8b bb = *reinterpret_cast<const s8b*>(wh + wb);
                const s8b b2 = *reinterpret_cast<const s8b*>(wl + wb);
                accA = __builtin_amdgcn_mfma_f32_32x32x16_bf16(a, bb, accA, 0, 0, 0);
                accB = __builtin_amdgcn_mfma_f32_32x32x16_bf16(a2, bb, accB, 0, 0, 0);
                accB = __builtin_amdgcn_mfma_f32_32x32x16_bf16(a, b2, accB, 0, 0, 0);
            }
        }
        __syncthreads();
    }

    const float bv = bias[cout];
#pragma unroll
    for (int r = 0; r < 16; ++r) {
        const int rl3 = (r & 3) + 8 * (r >> 2) + 4 * half;
        const int ow = 2 * rl3 + p;
        const size_t oe = (((size_t)((b * 64 + od) * 64 + ohh)) * 64 + ow) * 64 + cout;
        const float y = fmaxf(accA[r] + accB[r] + bv, 0.f);
        const bf16_t hh = f2b(y);
        oh[oe] = hh;
        ol[oe] = f2b(y - b2f(hh));
    }
}

// ---------------- ec0 via MFMA: s2 k=4, CIN=1, K=64 taps --------------------
__global__ __launch_bounds__(128)
void conv_ec0m(const float* __restrict__ x,
               const bf16_t* __restrict__ wh, const bf16_t* __restrict__ wm,
               const bf16_t* __restrict__ wl,
               const float* __restrict__ bias, float* __restrict__ of)
{
    __shared__ bf16_t lh[16 * 132], lm[16 * 132], ll[16 * 132];

    const int tid  = threadIdx.x;
    const int lane = tid & 63;
    const int wm2  = tid >> 6;
    const int half = lane >> 5, ln = lane & 31;
    const int w    = wm2 * 32 + ln;
    const int nwg  = gridDim.x;
    const int bid  = (blockIdx.x & 7) * (nwg >> 3) + (blockIdx.x >> 3);
    const int h    = bid % 64;
    const int d    = (bid / 64) % 64;
    const int b    = bid / 4096;

    for (int i = tid; i < 16 * 132; i += 128) {
        const int row = i / 132, col = i % 132;
        const int kd = row >> 2, kh = row & 3;
        const int iz = 2 * d + kd - 1, iy = 2 * h + kh - 1;
        const int ix = col - 1;
        float v = 0.f;
        if ((unsigned)iz < 128u && (unsigned)iy < 128u &&
            (unsigned)ix < 128u && col < 130)
            v = x[(size_t)((b * 128 + iz) * 128 + iy) * 128 + ix];
        unsigned short hh, mm2, ll2;
        split3s(v, hh, mm2, ll2);
        lh[i] = hh; lm[i] = mm2; ll[i] = ll2;
    }
    __syncthreads();

    f32x16 accA[2], accB[2];
#pragma unroll
    for (int i = 0; i < 16; ++i) {
        accA[0][i] = 0.f; accA[1][i] = 0.f;
        accB[0][i] = 0.f; accB[1][i] = 0.f;
    }

#pragma unroll
    for (int ks = 0; ks < 4; ++ks) {
        const int row0 = ks * 4 + 2 * half;
        const int i0 = row0 * 132 + 2 * w;
        const int i1 = i0 + 132;
        s8b ah, am, al3;
        {
            uint* ap = (uint*)&ah;
            ap[0] = *(const uint*)&lh[i0]; ap[1] = *(const uint*)&lh[i0 + 2];
            ap[2] = *(const uint*)&lh[i1]; ap[3] = *(const uint*)&lh[i1 + 2];
        }
        {
            uint* ap = (uint*)&am;
            ap[0] = *(const uint*)&lm[i0]; ap[1] = *(const uint*)&lm[i0 + 2];
            ap[2] = *(const uint*)&lm[i1]; ap[3] = *(const uint*)&lm[i1 + 2];
        }
        {
            uint* ap = (uint*)&al3;
            ap[0] = *(const uint*)&ll[i0]; ap[1] = *(const uint*)&ll[i0 + 2];
            ap[2] = *(const uint*)&ll[i1]; ap[3] = *(const uint*)&ll[i1 + 2];
        }
        const size_t wb0 = ((size_t)(ks * 2 + half) * 64 + ln) * 8;
#pragma unroll
        for (int n2 = 0; n2 < 2; ++n2) {
            const size_t wb = wb0 + n2 * 256;
            const s8b bh = *reinterpret_cast<const s8b*>(wh + wb);
            const s8b bm = *reinterpret_cast<const s8b*>(wm + wb);
            const s8b bl = *reinterpret_cast<const s8b*>(wl + wb);
            accA[n2] = __builtin_amdgcn_mfma_f32_32x32x16_bf16(ah, bh, accA[n2], 0, 0, 0);
            accB[n2] = __builtin_amdgcn_mfma_f32_32x32x16_bf16(ah, bm, accB[n2], 0, 0, 0);
            accA[n2] = __builtin_amdgcn_mfma_f32_32x32x16_bf16(am, bh, accA[n2], 0, 0, 0);
            accB[n2] = __builtin_amdgcn_mfma_f32_32x32x16_bf16(am, bm, accB[n2], 0, 0, 0);
            accA[n2] = __builtin_amdgcn_mfma_f32_32x32x16_bf16(al3, bh, accA[n2], 0, 0, 0);
            accB[n2] = __builtin_amdgcn_mfma_f32_32x32x16_bf16(ah, bl, accB[n2], 0, 0, 0);
        }
    }

    const size_t outrow = ((size_t)((b * 64 + d) * 64 + h)) * 64;
#pragma unroll
    for (int n2 = 0; n2 < 2; ++n2) {
        const int cout = n2 * 32 + ln;
        const float bv = bias[cout];
#pragma unroll
        for (int r = 0; r < 16; ++r) {
            const int rl3 = (r & 3) + 8 * (r >> 2) + 4 * half;
            const size_t oe = (outrow + wm2 * 32 + rl3) * 64 + cout;
            of[oe] = fmaxf(accA[n2][r] + accB[n2][r] + bv, 0.f);
        }
    }
}

// ---------------- du1: convT s2 k=4, CIN=64, COUT=1 — wave-level ------------
__global__ __launch_bounds__(256)
void convT_du1w(const bf16_t* __restrict__ inh, const bf16_t* __restrict__ inl,
                const float* __restrict__ wt, const float* __restrict__ bias,
                float* __restrict__ out)
{
    const int lane = threadIdx.x & 63;
    const int wv   = blockIdx.x * 4 + (threadIdx.x >> 6);
    const size_t obase = (size_t)wv * 16;
    const int ow0 = (int)(obase % 128);
    size_t rem = obase / 128;
    const int ohh = (int)(rem % 128); rem /= 128;
    const int od  = (int)(rem % 128); rem /= 128;
    const int b   = (int)rem;
    const int pd = od & 1, dz = od >> 1;
    const int ph = ohh & 1, hy = ohh >> 1;
    const int wx0 = ow0 >> 1;

    float acc[16];
#pragma unroll
    for (int o = 0; o < 16; ++o) acc[o] = 0.f;

#pragma unroll
    for (int jd = 0; jd < 2; ++jd) {
        const int kd = pd + 2 * jd;
        const int iz = dz + pd - 1 + jd;
        if ((unsigned)iz >= 64u) continue;
#pragma unroll
        for (int jh = 0; jh < 2; ++jh) {
            const int kh = ph + 2 * jh;
            const int iy = hy + ph - 1 + jh;
            if ((unsigned)iy >= 64u) continue;
            const size_t rbase = ((size_t)((b * 64 + iz) * 64 + iy)) * 64;
            float wv4[4];
#pragma unroll
            for (int kw = 0; kw < 4; ++kw)
                wv4[kw] = wt[(size_t)((kd * 4 + kh) * 4 + kw) * 64 + lane];
            float v[10];
#pragma unroll
            for (int t = 0; t < 10; ++t) {
                const int ix = wx0 - 1 + t;
                if ((unsigned)ix < 64u) {
                    const size_t a = (rbase + ix) * 64 + lane;
                    v[t] = b2f(inh[a]) + b2f(inl[a]);
                } else {
                    v[t] = 0.f;
                }
            }
#pragma unroll
            for (int o = 0; o < 16; ++o) {
                const int pw = o & 1;
                const int t0 = (o >> 1) + pw;
                acc[o] = fmaf(v[t0],     wv4[pw],     acc[o]);
                acc[o] = fmaf(v[t0 + 1], wv4[pw + 2], acc[o]);
            }
        }
    }

    const float b0 = bias[0];
#pragma unroll
    for (int o = 0; o < 16; ++o) {
        float s = acc[o];
        s += __shfl_xor(s, 1);
        s += __shfl_xor(s, 2);
        s += __shfl_xor(s, 4);
        s += __shfl_xor(s, 8);
        s += __shfl_xor(s, 16);
        s += __shfl_xor(s, 32);
        if (lane == 0) out[obase + o] = s + b0;
    }
}

// --------------------------------- VQ ---------------------------------------
__global__ void zero512(float* __restrict__ p) { p[threadIdx.x] = 0.0f; }

__global__ void vq_cnorm(const float* __restrict__ cb, float* __restrict__ cnorm)
{
    const int k = blockIdx.x * 64 + threadIdx.x;
    float s = 0.0f;
    for (int ci = 0; ci < 64; ++ci) { const float c = cb[k * 64 + ci]; s = fmaf(c, c, s); }
    cnorm[k] = s;
}

// 1 thread per z (k loop wave-uniform => scalar cb loads), k unrolled x4
// with 4 independent dot chains (round-15, proven).
__global__ __launch_bounds__(256)
void vq_assign(const float* __restrict__ z, const float* __restrict__ cb,
               const float* __restrict__ cnorm, int* __restrict__ idx,
               float* __restrict__ hist, int N)
{
    const int n = blockIdx.x * 256 + threadIdx.x;
    const float4* zp = reinterpret_cast<const float4*>(z + (size_t)n * 64);
    float4 zv[16];
    float z2 = 0.0f;
#pragma unroll
    for (int i = 0; i < 16; ++i) {
        zv[i] = zp[i];
        z2 += zv[i].x * zv[i].x + zv[i].y * zv[i].y + zv[i].z * zv[i].z + zv[i].w * zv[i].w;
    }
    float best = 3.4e38f;
    int bi = 0;
#pragma unroll 1
    for (int k = 0; k < 512; k += 4) {
        float dot0 = 0.f, dot1 = 0.f, dot2 = 0.f, dot3 = 0.f;
        const float4* c0 = reinterpret_cast<const float4*>(cb + (size_t)(k + 0) * 64);
        const float4* c1 = reinterpret_cast<const float4*>(cb + (size_t)(k + 1) * 64);
        const float4* c2 = reinterpret_cast<const float4*>(cb + (size_t)(k + 2) * 64);
        const float4* c3 = reinterpret_cast<const float4*>(cb + (size_t)(k + 3) * 64);
#pragma unroll
        for (int i = 0; i < 16; ++i) {
            const float4 zi = zv[i];
            const float4 a0 = c0[i];
            const float4 a1 = c1[i];
            const float4 a2 = c2[i];
            const float4 a3 = c3[i];
            dot0 += zi.x * a0.x + zi.y * a0.y + zi.z * a0.z + zi.w * a0.w;
            dot1 += zi.x * a1.x + zi.y * a1.y + zi.z * a1.z + zi.w * a1.w;
            dot2 += zi.x * a2.x + zi.y * a2.y + zi.z * a2.z + zi.w * a2.w;
            dot3 += zi.x * a3.x + zi.y * a3.y + zi.z * a3.z + zi.w * a3.w;
        }
        const float d0 = z2 + cnorm[k + 0] - 2.0f * dot0;
        const float d1 = z2 + cnorm[k + 1] - 2.0f * dot1;
        const float d2 = z2 + cnorm[k + 2] - 2.0f * dot2;
        const float d3 = z2 + cnorm[k + 3] - 2.0f * dot3;
        if (d0 < best) { best = d0; bi = k + 0; }
        if (d1 < best) { best = d1; bi = k + 1; }
        if (d2 < best) { best = d2; bi = k + 2; }
        if (d3 < best) { best = d3; bi = k + 3; }
    }
    idx[n] = bi;
    atomicAdd(&hist[bi], 1.0f);
}

__global__ __launch_bounds__(256)
void vq_gather_split(const float* __restrict__ cb, const int* __restrict__ idx,
                     bf16_t* __restrict__ zh, bf16_t* __restrict__ zl)
{
    const int gid = blockIdx.x * 256 + threadIdx.x;
    const int n = gid >> 4, c4 = gid & 15;
    const int k = idx[n];
    const float4 c = reinterpret_cast<const float4*>(cb)[k * 16 + c4];
    ushort4 h, l;
    h.x = f2b(c.x); l.x = f2b(c.x - b2f(h.x));
    h.y = f2b(c.y); l.y = f2b(c.y - b2f(h.y));
    h.z = f2b(c.z); l.z = f2b(c.z - b2f(h.z));
    h.w = f2b(c.w); l.w = f2b(c.w - b2f(h.w));
    reinterpret_cast<ushort4*>(zh)[gid] = h;
    reinterpret_cast<ushort4*>(zl)[gid] = l;
}

__global__ __launch_bounds__(512)
void perplexity_k(const float* __restrict__ hist, float* __restrict__ out, float invN)
{
    __shared__ float red[512];
    const int t = threadIdx.x;
    const float p = hist[t] * invN;
    red[t] = p * logf(p + 1e-12f);
    __syncthreads();
    for (int s = 256; s > 0; s >>= 1) {
        if (t < s) red[t] += red[t + s];
        __syncthreads();
    }
    if (t == 0) out[0] = expf(-red[0]);
}

// ---------------------------------------------------------------------------
extern "C" void kernel_launch(void* const* d_in, const int* in_sizes, int n_in,
                              void* d_out, int out_size, void* d_ws, size_t ws_size,
                              hipStream_t stream)
{
    const float* x       = (const float*)d_in[0];
    const float* ec0_w   = (const float*)d_in[1];
    const float* ec0_b   = (const float*)d_in[2];
    const float* er0_c1w = (const float*)d_in[3];
    const float* er0_c1b = (const float*)d_in[4];
    const float* er0_c2w = (const float*)d_in[5];
    const float* er0_c2b = (const float*)d_in[6];
    const float* er0_g   = (const float*)d_in[7];
    const float* er0_be  = (const float*)d_in[8];
    const float* er0_m   = (const float*)d_in[9];
    const float* er0_v   = (const float*)d_in[10];
    const float* er0_a   = (const float*)d_in[11];
    const float* ec1_w   = (const float*)d_in[12];
    const float* ec1_b   = (const float*)d_in[13];
    const float* er1_c1w = (const float*)d_in[14];
    const float* er1_c1b = (const float*)d_in[15];
    const float* er1_c2w = (const float*)d_in[16];
    const float* er1_c2b = (const float*)d_in[17];
    const float* er1_g   = (const float*)d_in[18];
    const float* er1_be  = (const float*)d_in[19];
    const float* er1_m   = (const float*)d_in[20];
    const float* er1_v   = (const float*)d_in[21];
    const float* er1_a   = (const float*)d_in[22];
    const float* eo_w    = (const float*)d_in[23];
    const float* eo_b    = (const float*)d_in[24];
    const float* eo_a    = (const float*)d_in[25];
    const float* cb      = (const float*)d_in[26];
    const float* dc0_w   = (const float*)d_in[27];
    const float* dc0_b   = (const float*)d_in[28];
    const float* dc0_a   = (const float*)d_in[29];
    const float* dr0_c1w = (const float*)d_in[30];
    const float* dr0_c1b = (const float*)d_in[31];
    const float* dr0_c2w = (const float*)d_in[32];
    const float* dr0_c2b = (const float*)d_in[33];
    const float* dr0_g   = (const float*)d_in[34];
    const float* dr0_be  = (const float*)d_in[35];
    const float* dr0_m   = (const float*)d_in[36];
    const float* dr0_v   = (const float*)d_in[37];
    const float* dr0_a   = (const float*)d_in[38];
    const float* du0_w   = (const float*)d_in[39];
    const float* du0_b   = (const float*)d_in[40];
    const float* dr1_c1w = (const float*)d_in[41];
    const float* dr1_c1b = (const float*)d_in[42];
    const float* dr1_c2w = (const float*)d_in[43];
    const float* dr1_c2b = (const float*)d_in[44];
    const float* dr1_g   = (const float*)d_in[45];
    const float* dr1_be  = (const float*)d_in[46];
    const float* dr1_m   = (const float*)d_in[47];
    const float* dr1_v   = (const float*)d_in[48];
    const float* dr1_a   = (const float*)d_in[49];
    const float* du1_w   = (const float*)d_in[50];
    const float* du1_b   = (const float*)d_in[51];

    float* out = (float*)d_out;

    // ---- ws: A=[0,134MB) , H=[134MB,268MB) ----
    char* W = (char*)d_ws;
    float*  Af  = (float*)(W);
    float*  Hf  = (float*)(W + 134217728);
    float*  E1f = (float*)(W + 134217728);
    float*  R1f = (float*)(W + 134217728 + 33554432);
    float*  Zf  = (float*)(W);
    int*    IDX = (int*)  (W + 16777216);
    float*  CN  = (float*)(W + 17039360);
    float*  HS  = (float*)(W + 17041408);
    bf16_t* ZQh = (bf16_t*)(W + 33554432);
    bf16_t* ZQl = (bf16_t*)(W + 41943040);
    bf16_t* D0h = (bf16_t*)(W + 50331648);
    bf16_t* D0l = (bf16_t*)(W + 67108864);
    bf16_t* Gh  = (bf16_t*)(W + 83886080);
    bf16_t* Gl  = (bf16_t*)(W + 100663296);
    bf16_t* U0h = (bf16_t*)(W + 134217728);
    bf16_t* U0l = (bf16_t*)(W + 201326592);
    bf16_t* G1h = (bf16_t*)(W);
    bf16_t* G1l = (bf16_t*)(W + 67108864);

    // ---- weight arenas in d_out ----
    char* WB = (char*)d_out;
    bf16_t* e0c1h = (bf16_t*)(WB + 0);
    bf16_t* e0c1m = (bf16_t*)(WB + 221184);
    bf16_t* e0c1l = (bf16_t*)(WB + 442368);
    bf16_t* e0c2h = (bf16_t*)(WB + 663552);
    bf16_t* e0c2m = (bf16_t*)(WB + 884736);
    bf16_t* e0c2l = (bf16_t*)(WB + 1105920);
    bf16_t* ec1h  = (bf16_t*)(WB + 1327104);
    bf16_t* ec1m  = (bf16_t*)(WB + 2375680);
    bf16_t* ec1l  = (bf16_t*)(WB + 3424256);
    bf16_t* e1c1h = (bf16_t*)(WB + 4472832);
    bf16_t* e1c1m = (bf16_t*)(WB + 5357568);
    bf16_t* e1c1l = (bf16_t*)(WB + 6242304);
    bf16_t* e1c2h = (bf16_t*)(WB + 7127040);
    bf16_t* e1c2m = (bf16_t*)(WB + 8011776);
    bf16_t* e1c2l = (bf16_t*)(WB + 8896512);
    bf16_t* eoh   = (bf16_t*)(WB + 9781248);
    bf16_t* eom   = (bf16_t*)(WB + 10223616);
    bf16_t* eol   = (bf16_t*)(WB + 10665984);
    bf16_t* wec0h = (bf16_t*)(WB + 11108352);
    bf16_t* wec0m = (bf16_t*)(WB + 11116544);
    bf16_t* wec0l = (bf16_t*)(WB + 11124736);
    bf16_t* dc0h  = (bf16_t*)(WB + 0);
    bf16_t* dc0l  = (bf16_t*)(WB + 442368);
    bf16_t* d0c1h = (bf16_t*)(WB + 884736);
    bf16_t* d0c1l = (bf16_t*)(WB + 1769472);
    bf16_t* d0c2h = (bf16_t*)(WB + 2654208);
    bf16_t* d0c2l = (bf16_t*)(WB + 3538944);
    bf16_t* du0h  = (bf16_t*)(WB + 4423680);
    bf16_t* du0l  = (bf16_t*)(WB + 5472256);
    bf16_t* d1c1h = (bf16_t*)(WB + 6520832);
    bf16_t* d1c1l = (bf16_t*)(WB + 6742016);
    bf16_t* d1c2h = (bf16_t*)(WB + 6963200);
    bf16_t* d1c2l = (bf16_t*)(WB + 7184384);

    const float* fn = nullptr;
    const bf16_t* bn_ = nullptr;

    // ---- encoder weight prep (split-3, fragment-major) ----
    wprep3<<<16, 256, 0, stream>>>(ec0_w, wec0h, wec0m, wec0l, 64, 64, 4096);
    wprep3<<<432, 256, 0, stream>>>(er0_c1w, e0c1h, e0c1m, e0c1l, 64, 64, 110592);
    wprep3<<<432, 256, 0, stream>>>(er0_c2w, e0c2h, e0c2m, e0c2l, 64, 64, 110592);
    wprep3<<<2048, 256, 0, stream>>>(ec1_w, ec1h, ec1m, ec1l, 64, 128, 524288);
    wprep3<<<1728, 256, 0, stream>>>(er1_c1w, e1c1h, e1c1m, e1c1l, 128, 128, 442368);
    wprep3<<<1728, 256, 0, stream>>>(er1_c2w, e1c2h, e1c2m, e1c2l, 128, 128, 442368);
    wprep3<<<864, 256, 0, stream>>>(eo_w, eoh, eom, eol, 128, 64, 221184);

    // ---- encoder (fp32-class) ----
    conv_ec0m<<<8192, 128, 0, stream>>>(x, wec0h, wec0m, wec0l, ec0_b, Af);

    conv3e<64, 64, 64, 2, 1><<<8192, 256, 0, stream>>>(
        Af, e0c1h, e0c1m, e0c1l, er0_c1b, fn, fn, fn, fn, fn, fn, Hf);
    conv3e<64, 64, 64, 2, 3><<<8192, 256, 0, stream>>>(
        Hf, e0c2h, e0c2m, e0c2l, er0_c2b, er0_g, er0_be, er0_m, er0_v, er0_a, Af, Af);

    convs2e<<<2048, 256, 0, stream>>>(Af, ec1h, ec1m, ec1l, ec1_b, E1f);

    conv3e<128, 128, 32, 4, 1><<<2048, 256, 0, stream>>>(
        E1f, e1c1h, e1c1m, e1c1l, er1_c1b, fn, fn, fn, fn, fn, fn, R1f);
    conv3e<128, 128, 32, 4, 3><<<2048, 256, 0, stream>>>(
        R1f, e1c2h, e1c2m, e1c2l, er1_c2b, er1_g, er1_be, er1_m, er1_v, er1_a, E1f, E1f);

    conv3e<128, 64, 32, 2, 2><<<2048, 128, 0, stream>>>(
        E1f, eoh, eom, eol, eo_b, fn, fn, fn, fn, eo_a, fn, Zf);

    // ---- VQ (exact fp32, ILP assign) ----
    vq_cnorm<<<8, 64, 0, stream>>>(cb, CN);
    zero512<<<1, 512, 0, stream>>>(HS);
    vq_assign<<<256, 256, 0, stream>>>(Zf, cb, CN, IDX, HS, 65536);
    perplexity_k<<<1, 512, 0, stream>>>(HS, out + 4194304, 1.0f / 65536.0f);
    vq_gather_split<<<4096, 256, 0, stream>>>(cb, IDX, ZQh, ZQl);

    // ---- decoder weight prep (split-2, fragment-major, overwrites arena) ----
    wprep_split<<<864, 256, 0, stream>>>(dc0_w, dc0h, dc0l, 64, 128, 221184);
    wprep_split<<<1728, 256, 0, stream>>>(dr0_c1w, d0c1h, d0c1l, 128, 128, 442368);
    wprep_split<<<1728, 256, 0, stream>>>(dr0_c2w, d0c2h, d0c2l, 128, 128, 442368);
    wprep_split<<<2048, 256, 0, stream>>>(du0_w, du0h, du0l, 128, 64, 524288);
    wprep_split<<<432, 256, 0, stream>>>(dr1_c1w, d1c1h, d1c1l, 64, 64, 110592);
    wprep_split<<<432, 256, 0, stream>>>(dr1_c2w, d1c2h, d1c2l, 64, 64, 110592);

    // ---- decoder (split-2 bf16) ----
    conv3d<64, 128, 32, 4, 2><<<2048, 256, 0, stream>>>(
        ZQh, ZQl, dc0h, dc0l, dc0_b, fn, fn, fn, fn, dc0_a, bn_, bn_, D0h, D0l);
    conv3d<128, 128, 32, 4, 1><<<2048, 256, 0, stream>>>(
        D0h, D0l, d0c1h, d0c1l, dr0_c1b, fn, fn, fn, fn, fn, bn_, bn_, Gh, Gl);
    conv3d<128, 128, 32, 4, 3><<<2048, 256, 0, stream>>>(
        Gh, Gl, d0c2h, d0c2l, dr0_c2b, dr0_g, dr0_be, dr0_m, dr0_v, dr0_a,
        D0h, D0l, D0h, D0l);

    convTm<<<8192, 256, 0, stream>>>(D0h, D0l, du0h, du0l, du0_b, U0h, U0l);

    conv3d<64, 64, 64, 2, 1><<<8192, 256, 0, stream>>>(
        U0h, U0l, d1c1h, d1c1l, dr1_c1b, fn, fn, fn, fn, fn, bn_, bn_, G1h, G1l);
    conv3d<64, 64, 64, 2, 3><<<8192, 256, 0, stream>>>(
        G1h, G1l, d1c2h, d1c2l, dr1_c2b, dr1_g, dr1_be, dr1_m, dr1_v, dr1_a,
        U0h, U0l, U0h, U0l);

    convT_du1w<<<65536, 256, 0, stream>>>(U0h, U0l, du1_w, du1_b, out);
}